// Round 7
// baseline (8628.388 us; speedup 1.0000x reference)
//
#include <hip/hip_runtime.h>
#include <hip/hip_bf16.h>

#define B_ 32
#define T_ 512
#define L_ 128
#define INC_ 512
#define D_ 512
#define H_ 8
#define HD_ 64
#define NL_ 6
#define DFF_ 1024
#define V_ 8000

typedef __hip_bfloat16 bf16;

// C[M,N] = act(A[M,K] @ W[N,K]^T + bias[N]); all f32
template <int ACT>
__global__ __launch_bounds__(256) void gemm_bias(
    const float* __restrict__ A, const float* __restrict__ W,
    const float* __restrict__ bias, float* __restrict__ C,
    int M, int N, int K)
{
    __shared__ float As[16][65];
    __shared__ float Bs[16][65];
    const int bm = blockIdx.y * 64, bn = blockIdx.x * 64;
    const int t = threadIdx.x;
    const int tx = t & 15, ty = t >> 4;
    float acc[4][4] = {};
    for (int k0 = 0; k0 < K; k0 += 16) {
#pragma unroll
        for (int i = 0; i < 4; ++i) {
            int row = ty + 16 * i;
            As[tx][row] = A[(size_t)(bm + row) * K + (k0 + tx)];
            Bs[tx][row] = W[(size_t)(bn + row) * K + (k0 + tx)];
        }
        __syncthreads();
#pragma unroll
        for (int kk = 0; kk < 16; ++kk) {
            float a[4], b[4];
#pragma unroll
            for (int i = 0; i < 4; ++i) a[i] = As[kk][ty * 4 + i];
#pragma unroll
            for (int j = 0; j < 4; ++j) b[j] = Bs[kk][tx * 4 + j];
#pragma unroll
            for (int i = 0; i < 4; ++i)
#pragma unroll
                for (int j = 0; j < 4; ++j)
                    acc[i][j] += a[i] * b[j];
        }
        __syncthreads();
    }
#pragma unroll
    for (int j = 0; j < 4; ++j) {
        float bj = bias[bn + tx * 4 + j];
#pragma unroll
        for (int i = 0; i < 4; ++i) {
            float v = acc[i][j] + bj;
            if (ACT == 1) v = 0.5f * v * (1.0f + erff(v * 0.70710678118654752f));
            C[(size_t)(bm + ty * 4 + i) * N + (bn + tx * 4 + j)] = v;
        }
    }
}

__global__ void rope_tables_kernel(float* __restrict__ cosT, float* __restrict__ sinT)
{
    int gid = blockIdx.x * blockDim.x + threadIdx.x;
    if (gid >= L_ * 32) return;
    int l = gid >> 5, i = gid & 31;
    float inv = powf(10000.0f, -(float)(2 * i) / (float)HD_);
    float ang = (float)l * inv;
    cosT[gid] = cosf(ang);
    sinT[gid] = sinf(ang);
}

__global__ void embed_kernel(const int* __restrict__ targets, const float* __restrict__ emb,
                             float* __restrict__ tgt)
{
    int gid = blockIdx.x * blockDim.x + threadIdx.x;
    if (gid >= B_ * L_ * D_) return;
    int d = gid & (D_ - 1);
    int r = gid >> 9;  // b*L + l
    int tok = targets[r];
    tgt[gid] = emb[(size_t)tok * D_ + d] * 22.62741699796952f;  // sqrt(512)
}

__global__ void pad_kernel(const float* __restrict__ mem, int* __restrict__ pad)
{
    int gid = blockIdx.x * blockDim.x + threadIdx.x;
    if (gid >= B_ * T_) return;
    const float* p = mem + (size_t)gid * D_;
    float s = 0.f;
    for (int d = 0; d < D_; ++d) s += fabsf(p[d]);
    pad[gid] = (s == 0.0f) ? 1 : 0;
}

__global__ void rope_apply_kernel(float* __restrict__ q, float* __restrict__ k,
                                  const float* __restrict__ cosT, const float* __restrict__ sinT)
{
    int gid = blockIdx.x * blockDim.x + threadIdx.x;
    if (gid >= B_ * L_ * H_ * 32) return;
    int i = gid & 31;
    int h = (gid >> 5) & (H_ - 1);
    int l = (gid >> 8) & (L_ - 1);
    int b = gid >> 15;
    float c = cosT[l * 32 + i], s = sinT[l * 32 + i];
    size_t base = ((size_t)b * L_ + l) * D_ + h * HD_;
    float x1 = q[base + i], x2 = q[base + i + 32];
    q[base + i] = x1 * c - x2 * s;
    q[base + i + 32] = x2 * c + x1 * s;
    float y1 = k[base + i], y2 = k[base + i + 32];
    k[base + i] = y1 * c - y2 * s;
    k[base + i + 32] = y2 * c + y1 * s;
}

// one block per (b,h,l): causal softmax(q.k*scale) @ v
__global__ __launch_bounds__(128) void self_attn_kernel(
    const float* __restrict__ q, const float* __restrict__ k,
    const float* __restrict__ v, float* __restrict__ out)
{
    const int idx = blockIdx.x;
    const int l = idx & (L_ - 1);
    const int h = (idx >> 7) & (H_ - 1);
    const int b = idx >> 10;
    const int t = threadIdx.x;
    __shared__ float qs[HD_];
    __shared__ float pr[L_];
    __shared__ float rbuf[128];
    size_t qoff = ((size_t)b * L_ + l) * D_ + h * HD_;
    if (t < HD_) qs[t] = q[qoff + t];
    __syncthreads();
    float s = -INFINITY;
    if (t <= l) {
        const float* kp = k + ((size_t)b * L_ + t) * D_ + h * HD_;
        float acc = 0.f;
        for (int d = 0; d < HD_; ++d) acc += qs[d] * kp[d];
        s = acc * 0.125f;
    }
    rbuf[t] = s;
    __syncthreads();
    for (int off = 64; off > 0; off >>= 1) { if (t < off) rbuf[t] = fmaxf(rbuf[t], rbuf[t + off]); __syncthreads(); }
    float m = rbuf[0];
    __syncthreads();
    float e = (t <= l) ? expf(s - m) : 0.f;
    pr[t] = e;
    rbuf[t] = e;
    __syncthreads();
    for (int off = 64; off > 0; off >>= 1) { if (t < off) rbuf[t] += rbuf[t + off]; __syncthreads(); }
    float inv = 1.0f / rbuf[0];
    if (t < HD_) {
        float o = 0.f;
        const float* vp = v + (size_t)b * L_ * D_ + h * HD_ + t;
        for (int j = 0; j <= l; ++j) o += pr[j] * vp[(size_t)j * D_];
        out[qoff + t] = o * inv;
    }
}

// one block per (b,h,l): softmax over T keys with pad mask, @ V2
__global__ __launch_bounds__(512) void cross_attn_kernel(
    const float* __restrict__ q, const float* __restrict__ K2,
    const float* __restrict__ V2, const int* __restrict__ pad,
    float* __restrict__ out)
{
    const int idx = blockIdx.x;
    const int l = idx & (L_ - 1);
    const int h = (idx >> 7) & (H_ - 1);
    const int b = idx >> 10;
    const int t = threadIdx.x;
    __shared__ float qs[HD_];
    __shared__ float pr[T_];
    __shared__ float rbuf[512];
    __shared__ float obuf[8][HD_];
    size_t qoff = ((size_t)b * L_ + l) * D_ + h * HD_;
    if (t < HD_) qs[t] = q[qoff + t];
    __syncthreads();
    float s;
    {
        const float* kp = K2 + ((size_t)b * T_ + t) * D_ + h * HD_;
        float acc = 0.f;
        for (int d = 0; d < HD_; ++d) acc += qs[d] * kp[d];
        s = pad[b * T_ + t] ? -INFINITY : acc * 0.125f;
    }
    rbuf[t] = s;
    __syncthreads();
    for (int off = 256; off > 0; off >>= 1) { if (t < off) rbuf[t] = fmaxf(rbuf[t], rbuf[t + off]); __syncthreads(); }
    float m = rbuf[0];
    __syncthreads();
    float e = expf(s - m);
    pr[t] = e;
    rbuf[t] = e;
    __syncthreads();
    for (int off = 256; off > 0; off >>= 1) { if (t < off) rbuf[t] += rbuf[t + off]; __syncthreads(); }
    float inv = 1.0f / rbuf[0];
    const int d = t & 63, c = t >> 6;
    float o = 0.f;
    const float* vp = V2 + ((size_t)b * T_ + c * 64) * D_ + h * HD_ + d;
    for (int j = 0; j < 64; ++j) o += pr[c * 64 + j] * vp[(size_t)j * D_];
    obuf[c][d] = o;
    __syncthreads();
    if (t < HD_) {
        float acc = 0.f;
#pragma unroll
        for (int cc = 0; cc < 8; ++cc) acc += obuf[cc][t];
        out[qoff + t] = acc * inv;
    }
}

// tgt = LN(tgt + delta) * g + b, in place. one block per row.
__global__ __launch_bounds__(128) void ln_residual_kernel(
    float* __restrict__ tgt, const float* __restrict__ delta,
    const float* __restrict__ g, const float* __restrict__ bb)
{
    const int row = blockIdx.x;
    const int t = threadIdx.x;
    __shared__ float xs[D_];
    __shared__ float rbuf[128];
    size_t base = (size_t)row * D_;
    float lsum = 0.f;
    for (int d = t; d < D_; d += 128) {
        float x = tgt[base + d] + delta[base + d];
        xs[d] = x;
        lsum += x;
    }
    rbuf[t] = lsum;
    __syncthreads();
    for (int off = 64; off > 0; off >>= 1) { if (t < off) rbuf[t] += rbuf[t + off]; __syncthreads(); }
    float mean = rbuf[0] * (1.0f / D_);
    __syncthreads();
    float lv = 0.f;
    for (int d = t; d < D_; d += 128) { float dd = xs[d] - mean; lv += dd * dd; }
    rbuf[t] = lv;
    __syncthreads();
    for (int off = 64; off > 0; off >>= 1) { if (t < off) rbuf[t] += rbuf[t + off]; __syncthreads(); }
    float inv = 1.0f / sqrtf(rbuf[0] * (1.0f / D_) + 1e-5f);
    for (int d = t; d < D_; d += 128)
        tgt[base + d] = (xs[d] - mean) * inv * g[d] + bb[d];
}

__global__ void copyf_kernel(const float* __restrict__ in, float* __restrict__ out, int n)
{
    int gid = blockIdx.x * blockDim.x + threadIdx.x;
    if (gid < n) out[gid] = in[gid];
}

__global__ void fillf_kernel(float* p, float v, size_t n)
{
    size_t gid = (size_t)blockIdx.x * 256 + threadIdx.x;
    if (gid < n) p[gid] = v;
}

extern "C" void kernel_launch(void* const* d_in, const int* in_sizes, int n_in,
                              void* d_out, int out_size, void* d_ws, size_t ws_size,
                              hipStream_t stream)
{
    const float* enc    = (const float*)d_in[0];
    const int*   tg     = (const int*)d_in[1];
    const float* emb    = (const float*)d_in[2];
    const float* inp_w  = (const float*)d_in[3];
    const float* inp_b  = (const float*)d_in[4];
    const float* out_w  = (const float*)d_in[5];
    const float* out_b  = (const float*)d_in[6];
    const float* qw     = (const float*)d_in[7];
    const float* qb     = (const float*)d_in[8];
    const float* kw     = (const float*)d_in[9];
    const float* kb     = (const float*)d_in[10];
    const float* vw     = (const float*)d_in[11];
    const float* vb     = (const float*)d_in[12];
    const float* ow     = (const float*)d_in[13];
    const float* ob     = (const float*)d_in[14];
    const float* mha_w  = (const float*)d_in[15];
    const float* mha_b  = (const float*)d_in[16];
    const float* mha_ow = (const float*)d_in[17];
    const float* mha_ob = (const float*)d_in[18];
    const float* w1     = (const float*)d_in[19];
    const float* b1     = (const float*)d_in[20];
    const float* w2     = (const float*)d_in[21];
    const float* b2     = (const float*)d_in[22];
    const float* ln1g   = (const float*)d_in[23];
    const float* ln1b   = (const float*)d_in[24];
    const float* ln2g   = (const float*)d_in[25];
    const float* ln2b   = (const float*)d_in[26];
    const float* ln3g   = (const float*)d_in[27];
    const float* ln3b   = (const float*)d_in[28];

    const int BL = B_ * L_;        // 4096
    const int BT = B_ * T_;        // 16384
    const size_t N_LOGITS = (size_t)BL * V_;  // 32,768,000

    // --- d_ws (75.7 MB): K2/V2 f32 + tgt f32 + RoPE tables + pad mask ---
    const size_t WS_NEEDED =
        (size_t)2 * BT * D_ * sizeof(float) + (size_t)BL * D_ * sizeof(float)
        + (size_t)2 * L_ * 32 * sizeof(float) + (size_t)BT * sizeof(int);
    if (ws_size < WS_NEEDED) {
        fillf_kernel<<<((size_t)out_size + 255) / 256, 256, 0, stream>>>((float*)d_out, 0.f, (size_t)out_size);
        return;
    }
    float* f_K2  = (float*)d_ws;
    float* f_V2  = f_K2 + (size_t)BT * D_;
    float* f_tgt = f_V2 + (size_t)BT * D_;
    float* f_cos = f_tgt + (size_t)BL * D_;
    float* f_sin = f_cos + (size_t)L_ * 32;
    int*   f_pad = (int*)(f_sin + (size_t)L_ * 32);

    // --- d_out (f32, 139.5 MB) doubles as layer-loop scratch (58.7 MB peak, dead
    //     before the final logits/tgt writes) ---
    float* f_q   = (float*)d_out;
    float* f_k   = f_q  + (size_t)BL * D_;
    float* f_v   = f_k  + (size_t)BL * D_;
    float* f_t1  = f_v  + (size_t)BL * D_;
    float* f_t2  = f_t1 + (size_t)BL * D_;
    float* f_ffh = f_t2 + (size_t)BL * D_;
    float* f_mem = f_q;  // prologue-only alias: BT*D floats = q..t1 exactly

    rope_tables_kernel<<<(L_ * 32 + 255) / 256, 256, 0, stream>>>(f_cos, f_sin);
    embed_kernel<<<(BL * D_ + 255) / 256, 256, 0, stream>>>(tg, emb, f_tgt);

    // memory = enc @ inp_w^T + inp_b   (loop-invariant, hoisted)
    gemm_bias<0><<<dim3(D_ / 64, BT / 64), 256, 0, stream>>>(enc, inp_w, inp_b, f_mem, BT, D_, INC_);
    pad_kernel<<<(BT + 255) / 256, 256, 0, stream>>>(f_mem, f_pad);
    // cross K,V (loop-invariant): mha_w rows [D,2D) and [2D,3D)
    gemm_bias<0><<<dim3(D_ / 64, BT / 64), 256, 0, stream>>>(f_mem, mha_w + (size_t)D_ * D_, mha_b + D_, f_K2, BT, D_, D_);
    gemm_bias<0><<<dim3(D_ / 64, BT / 64), 256, 0, stream>>>(f_mem, mha_w + (size_t)2 * D_ * D_, mha_b + 2 * D_, f_V2, BT, D_, D_);

    for (int layer = 0; layer < NL_; ++layer) {
        // --- self attention ---
        gemm_bias<0><<<dim3(D_ / 64, BL / 64), 256, 0, stream>>>(f_tgt, qw, qb, f_q, BL, D_, D_);
        gemm_bias<0><<<dim3(D_ / 64, BL / 64), 256, 0, stream>>>(f_tgt, kw, kb, f_k, BL, D_, D_);
        gemm_bias<0><<<dim3(D_ / 64, BL / 64), 256, 0, stream>>>(f_tgt, vw, vb, f_v, BL, D_, D_);
        rope_apply_kernel<<<(B_ * L_ * H_ * 32 + 255) / 256, 256, 0, stream>>>(f_q, f_k, f_cos, f_sin);
        self_attn_kernel<<<B_ * H_ * L_, 128, 0, stream>>>(f_q, f_k, f_v, f_t1);
        gemm_bias<0><<<dim3(D_ / 64, BL / 64), 256, 0, stream>>>(f_t1, ow, ob, f_t2, BL, D_, D_);
        ln_residual_kernel<<<BL, 128, 0, stream>>>(f_tgt, f_t2, ln1g, ln1b);
        // --- cross attention ---
        gemm_bias<0><<<dim3(D_ / 64, BL / 64), 256, 0, stream>>>(f_tgt, mha_w, mha_b, f_q, BL, D_, D_);
        cross_attn_kernel<<<B_ * H_ * L_, 512, 0, stream>>>(f_q, f_K2, f_V2, f_pad, f_t1);
        gemm_bias<0><<<dim3(D_ / 64, BL / 64), 256, 0, stream>>>(f_t1, mha_ow, mha_ob, f_t2, BL, D_, D_);
        ln_residual_kernel<<<BL, 128, 0, stream>>>(f_tgt, f_t2, ln2g, ln2b);
        // --- FFN ---
        gemm_bias<1><<<dim3(DFF_ / 64, BL / 64), 256, 0, stream>>>(f_tgt, w1, b1, f_ffh, BL, DFF_, D_);
        gemm_bias<0><<<dim3(D_ / 64, BL / 64), 256, 0, stream>>>(f_ffh, w2, b2, f_t2, BL, D_, DFF_);
        ln_residual_kernel<<<BL, 128, 0, stream>>>(f_tgt, f_t2, ln3g, ln3b);
    }

    // scratch in d_out is dead from here on; outputs are FLOAT32
    float* o_logits = (float*)d_out;
    float* o_tgt = o_logits + N_LOGITS;
    gemm_bias<0><<<dim3(V_ / 64, BL / 64), 256, 0, stream>>>(f_tgt, out_w, out_b, o_logits, BL, V_, D_);
    copyf_kernel<<<(BL * D_ + 255) / 256, 256, 0, stream>>>(f_tgt, o_tgt, BL * D_);
}

// Round 8
// 5948.192 us; speedup vs baseline: 1.4506x; 1.4506x over previous
//
#include <hip/hip_runtime.h>
#include <hip/hip_bf16.h>

#define B_ 32
#define T_ 512
#define L_ 128
#define INC_ 512
#define D_ 512
#define H_ 8
#define HD_ 64
#define NL_ 6
#define DFF_ 1024
#define V_ 8000
#define LDSK 40  // padded LDS row stride (bf16 units) to break bank conflicts

typedef __bf16 bfr;
typedef __attribute__((ext_vector_type(8))) __bf16 bf16x8;
typedef __attribute__((ext_vector_type(4))) float f32x4;

// split f32 -> bf16 hi + lo planes
__global__ void split_convert_kernel(const float* __restrict__ src,
                                     bfr* __restrict__ hi, bfr* __restrict__ lo, int n)
{
    int g = blockIdx.x * 256 + threadIdx.x;
    if (g >= n) return;
    float x = src[g];
    bfr h = (bfr)x;
    hi[g] = h;
    lo[g] = (bfr)(x - (float)h);
}

// C[M,N] = act(A[M,K] @ W[N,K]^T + bias); A f32 (split in-kernel), W pre-split bf16 planes.
// Split product: A*W ~= Ah*Wh + Ah*Wl + Al*Wh  (lo*lo dropped, ~1.6e-5 relative)
// Tile 128x64, 4 waves (2M x 2N), each wave 64x32 = 4x2 MFMA 16x16x32 frags.
template <int ACT>
__global__ __launch_bounds__(256) void gemm_split(
    const float* __restrict__ A, const bfr* __restrict__ Whi, const bfr* __restrict__ Wlo,
    const float* __restrict__ bias, float* __restrict__ C, int M, int N, int K)
{
    __shared__ bfr Ah_s[128 * LDSK];
    __shared__ bfr Al_s[128 * LDSK];
    __shared__ bfr Wh_s[64 * LDSK];
    __shared__ bfr Wl_s[64 * LDSK];
    const int t = threadIdx.x;
    const int bm = blockIdx.y * 128, bn = blockIdx.x * 64;
    const int w = t >> 6, lane = t & 63;
    const int wm = w >> 1, wn = w & 1;
    const int fr = lane & 15, kq = lane >> 4;  // frag row, k-quarter
    const int ar = t >> 1, ah = (t & 1) * 16;  // A-stage: row, k-offset (16 f32 per thread)
    const int wr = t >> 2, wk = (t & 3) * 8;   // W-stage: row, k-offset (8 bf16 per thread)

    f32x4 acc[4][2] = {};

    for (int k0 = 0; k0 < K; k0 += 32) {
        // ---- stage A: load 16 f32, split to hi/lo bf16 ----
        {
            const float* ap = A + (size_t)(bm + ar) * K + (k0 + ah);
            float4 v0 = ((const float4*)ap)[0];
            float4 v1 = ((const float4*)ap)[1];
            float4 v2 = ((const float4*)ap)[2];
            float4 v3 = ((const float4*)ap)[3];
            float xs[16] = {v0.x, v0.y, v0.z, v0.w, v1.x, v1.y, v1.z, v1.w,
                            v2.x, v2.y, v2.z, v2.w, v3.x, v3.y, v3.z, v3.w};
            bf16x8 h0, h1, l0, l1;
#pragma unroll
            for (int i = 0; i < 8; ++i) {
                bfr hh = (bfr)xs[i];
                h0[i] = hh; l0[i] = (bfr)(xs[i] - (float)hh);
            }
#pragma unroll
            for (int i = 0; i < 8; ++i) {
                bfr hh = (bfr)xs[8 + i];
                h1[i] = hh; l1[i] = (bfr)(xs[8 + i] - (float)hh);
            }
            *(bf16x8*)(Ah_s + ar * LDSK + ah) = h0;
            *(bf16x8*)(Ah_s + ar * LDSK + ah + 8) = h1;
            *(bf16x8*)(Al_s + ar * LDSK + ah) = l0;
            *(bf16x8*)(Al_s + ar * LDSK + ah + 8) = l1;
        }
        // ---- stage W planes (already bf16) ----
        {
            bf16x8 wh = *(const bf16x8*)(Whi + (size_t)(bn + wr) * K + (k0 + wk));
            bf16x8 wl = *(const bf16x8*)(Wlo + (size_t)(bn + wr) * K + (k0 + wk));
            *(bf16x8*)(Wh_s + wr * LDSK + wk) = wh;
            *(bf16x8*)(Wl_s + wr * LDSK + wk) = wl;
        }
        __syncthreads();
        // ---- MFMA ----
        bf16x8 Afh[4], Afl[4], Wfh[2], Wfl[2];
#pragma unroll
        for (int i = 0; i < 4; ++i) {
            int r = wm * 64 + i * 16 + fr;
            Afh[i] = *(const bf16x8*)(Ah_s + r * LDSK + kq * 8);
            Afl[i] = *(const bf16x8*)(Al_s + r * LDSK + kq * 8);
        }
#pragma unroll
        for (int j = 0; j < 2; ++j) {
            int r = wn * 32 + j * 16 + fr;
            Wfh[j] = *(const bf16x8*)(Wh_s + r * LDSK + kq * 8);
            Wfl[j] = *(const bf16x8*)(Wl_s + r * LDSK + kq * 8);
        }
#pragma unroll
        for (int i = 0; i < 4; ++i)
#pragma unroll
            for (int j = 0; j < 2; ++j) {
                acc[i][j] = __builtin_amdgcn_mfma_f32_16x16x32_bf16(Afh[i], Wfh[j], acc[i][j], 0, 0, 0);
                acc[i][j] = __builtin_amdgcn_mfma_f32_16x16x32_bf16(Afh[i], Wfl[j], acc[i][j], 0, 0, 0);
                acc[i][j] = __builtin_amdgcn_mfma_f32_16x16x32_bf16(Afl[i], Wfh[j], acc[i][j], 0, 0, 0);
            }
        __syncthreads();
    }
    // ---- epilogue: bias (+GELU), f32 store. C row=(lane>>4)*4+reg, col=lane&15 ----
#pragma unroll
    for (int i = 0; i < 4; ++i) {
        int row0 = bm + wm * 64 + i * 16 + (lane >> 4) * 4;
#pragma unroll
        for (int j = 0; j < 2; ++j) {
            int col = bn + wn * 32 + j * 16 + fr;
            float bj = bias[col];
#pragma unroll
            for (int r = 0; r < 4; ++r) {
                float v = acc[i][j][r] + bj;
                if (ACT == 1) v = 0.5f * v * (1.0f + erff(v * 0.70710678118654752f));
                C[(size_t)(row0 + r) * N + col] = v;
            }
        }
    }
}

__global__ void rope_tables_kernel(float* __restrict__ cosT, float* __restrict__ sinT)
{
    int gid = blockIdx.x * blockDim.x + threadIdx.x;
    if (gid >= L_ * 32) return;
    int l = gid >> 5, i = gid & 31;
    float inv = powf(10000.0f, -(float)(2 * i) / (float)HD_);
    float ang = (float)l * inv;
    cosT[gid] = cosf(ang);
    sinT[gid] = sinf(ang);
}

__global__ void embed_kernel(const int* __restrict__ targets, const float* __restrict__ emb,
                             float* __restrict__ tgt)
{
    int gid = blockIdx.x * blockDim.x + threadIdx.x;
    if (gid >= B_ * L_ * D_) return;
    int d = gid & (D_ - 1);
    int r = gid >> 9;
    int tok = targets[r];
    tgt[gid] = emb[(size_t)tok * D_ + d] * 22.62741699796952f;
}

__global__ void pad_kernel(const float* __restrict__ mem, int* __restrict__ pad)
{
    int gid = blockIdx.x * blockDim.x + threadIdx.x;
    if (gid >= B_ * T_) return;
    const float* p = mem + (size_t)gid * D_;
    float s = 0.f;
    for (int d = 0; d < D_; ++d) s += fabsf(p[d]);
    pad[gid] = (s == 0.0f) ? 1 : 0;
}

__global__ void rope_apply_kernel(float* __restrict__ q, float* __restrict__ k,
                                  const float* __restrict__ cosT, const float* __restrict__ sinT)
{
    int gid = blockIdx.x * blockDim.x + threadIdx.x;
    if (gid >= B_ * L_ * H_ * 32) return;
    int i = gid & 31;
    int h = (gid >> 5) & (H_ - 1);
    int l = (gid >> 8) & (L_ - 1);
    int b = gid >> 15;
    float c = cosT[l * 32 + i], s = sinT[l * 32 + i];
    size_t base = ((size_t)b * L_ + l) * D_ + h * HD_;
    float x1 = q[base + i], x2 = q[base + i + 32];
    q[base + i] = x1 * c - x2 * s;
    q[base + i + 32] = x2 * c + x1 * s;
    float y1 = k[base + i], y2 = k[base + i + 32];
    k[base + i] = y1 * c - y2 * s;
    k[base + i + 32] = y2 * c + y1 * s;
}

__global__ __launch_bounds__(128) void self_attn_kernel(
    const float* __restrict__ q, const float* __restrict__ k,
    const float* __restrict__ v, float* __restrict__ out)
{
    const int idx = blockIdx.x;
    const int l = idx & (L_ - 1);
    const int h = (idx >> 7) & (H_ - 1);
    const int b = idx >> 10;
    const int t = threadIdx.x;
    __shared__ float qs[HD_];
    __shared__ float pr[L_];
    __shared__ float rbuf[128];
    size_t qoff = ((size_t)b * L_ + l) * D_ + h * HD_;
    if (t < HD_) qs[t] = q[qoff + t];
    __syncthreads();
    float s = -INFINITY;
    if (t <= l) {
        const float* kp = k + ((size_t)b * L_ + t) * D_ + h * HD_;
        float acc = 0.f;
        for (int d = 0; d < HD_; ++d) acc += qs[d] * kp[d];
        s = acc * 0.125f;
    }
    rbuf[t] = s;
    __syncthreads();
    for (int off = 64; off > 0; off >>= 1) { if (t < off) rbuf[t] = fmaxf(rbuf[t], rbuf[t + off]); __syncthreads(); }
    float m = rbuf[0];
    __syncthreads();
    float e = (t <= l) ? expf(s - m) : 0.f;
    pr[t] = e;
    rbuf[t] = e;
    __syncthreads();
    for (int off = 64; off > 0; off >>= 1) { if (t < off) rbuf[t] += rbuf[t + off]; __syncthreads(); }
    float inv = 1.0f / rbuf[0];
    if (t < HD_) {
        float o = 0.f;
        const float* vp = v + (size_t)b * L_ * D_ + h * HD_ + t;
        for (int j = 0; j <= l; ++j) o += pr[j] * vp[(size_t)j * D_];
        out[qoff + t] = o * inv;
    }
}

__global__ __launch_bounds__(512) void cross_attn_kernel(
    const float* __restrict__ q, const float* __restrict__ K2,
    const float* __restrict__ V2, const int* __restrict__ pad,
    float* __restrict__ out)
{
    const int idx = blockIdx.x;
    const int l = idx & (L_ - 1);
    const int h = (idx >> 7) & (H_ - 1);
    const int b = idx >> 10;
    const int t = threadIdx.x;
    __shared__ float qs[HD_];
    __shared__ float pr[T_];
    __shared__ float rbuf[512];
    __shared__ float obuf[8][HD_];
    size_t qoff = ((size_t)b * L_ + l) * D_ + h * HD_;
    if (t < HD_) qs[t] = q[qoff + t];
    __syncthreads();
    float s;
    {
        const float* kp = K2 + ((size_t)b * T_ + t) * D_ + h * HD_;
        float acc = 0.f;
        for (int d = 0; d < HD_; ++d) acc += qs[d] * kp[d];
        s = pad[b * T_ + t] ? -INFINITY : acc * 0.125f;
    }
    rbuf[t] = s;
    __syncthreads();
    for (int off = 256; off > 0; off >>= 1) { if (t < off) rbuf[t] = fmaxf(rbuf[t], rbuf[t + off]); __syncthreads(); }
    float m = rbuf[0];
    __syncthreads();
    float e = expf(s - m);
    pr[t] = e;
    rbuf[t] = e;
    __syncthreads();
    for (int off = 256; off > 0; off >>= 1) { if (t < off) rbuf[t] += rbuf[t + off]; __syncthreads(); }
    float inv = 1.0f / rbuf[0];
    const int d = t & 63, c = t >> 6;
    float o = 0.f;
    const float* vp = V2 + ((size_t)b * T_ + c * 64) * D_ + h * HD_ + d;
    for (int j = 0; j < 64; ++j) o += pr[c * 64 + j] * vp[(size_t)j * D_];
    obuf[c][d] = o;
    __syncthreads();
    if (t < HD_) {
        float acc = 0.f;
#pragma unroll
        for (int cc = 0; cc < 8; ++cc) acc += obuf[cc][t];
        out[qoff + t] = acc * inv;
    }
}

__global__ __launch_bounds__(128) void ln_residual_kernel(
    float* __restrict__ tgt, const float* __restrict__ delta,
    const float* __restrict__ g, const float* __restrict__ bb)
{
    const int row = blockIdx.x;
    const int t = threadIdx.x;
    __shared__ float xs[D_];
    __shared__ float rbuf[128];
    size_t base = (size_t)row * D_;
    float lsum = 0.f;
    for (int d = t; d < D_; d += 128) {
        float x = tgt[base + d] + delta[base + d];
        xs[d] = x;
        lsum += x;
    }
    rbuf[t] = lsum;
    __syncthreads();
    for (int off = 64; off > 0; off >>= 1) { if (t < off) rbuf[t] += rbuf[t + off]; __syncthreads(); }
    float mean = rbuf[0] * (1.0f / D_);
    __syncthreads();
    float lv = 0.f;
    for (int d = t; d < D_; d += 128) { float dd = xs[d] - mean; lv += dd * dd; }
    rbuf[t] = lv;
    __syncthreads();
    for (int off = 64; off > 0; off >>= 1) { if (t < off) rbuf[t] += rbuf[t + off]; __syncthreads(); }
    float inv = 1.0f / sqrtf(rbuf[0] * (1.0f / D_) + 1e-5f);
    for (int d = t; d < D_; d += 128)
        tgt[base + d] = (xs[d] - mean) * inv * g[d] + bb[d];
}

__global__ void copyf_kernel(const float* __restrict__ in, float* __restrict__ out, int n)
{
    int gid = blockIdx.x * blockDim.x + threadIdx.x;
    if (gid < n) out[gid] = in[gid];
}

__global__ void fillf_kernel(float* p, float v, size_t n)
{
    size_t gid = (size_t)blockIdx.x * 256 + threadIdx.x;
    if (gid < n) p[gid] = v;
}

extern "C" void kernel_launch(void* const* d_in, const int* in_sizes, int n_in,
                              void* d_out, int out_size, void* d_ws, size_t ws_size,
                              hipStream_t stream)
{
    const float* enc    = (const float*)d_in[0];
    const int*   tg     = (const int*)d_in[1];
    const float* emb    = (const float*)d_in[2];
    const float* inp_w  = (const float*)d_in[3];
    const float* inp_b  = (const float*)d_in[4];
    const float* out_w  = (const float*)d_in[5];
    const float* out_b  = (const float*)d_in[6];
    const float* qw     = (const float*)d_in[7];
    const float* qb     = (const float*)d_in[8];
    const float* kw     = (const float*)d_in[9];
    const float* kb     = (const float*)d_in[10];
    const float* vw     = (const float*)d_in[11];
    const float* vb     = (const float*)d_in[12];
    const float* ow     = (const float*)d_in[13];
    const float* ob     = (const float*)d_in[14];
    const float* mha_w  = (const float*)d_in[15];
    const float* mha_b  = (const float*)d_in[16];
    const float* mha_ow = (const float*)d_in[17];
    const float* mha_ob = (const float*)d_in[18];
    const float* w1     = (const float*)d_in[19];
    const float* b1     = (const float*)d_in[20];
    const float* w2     = (const float*)d_in[21];
    const float* b2     = (const float*)d_in[22];
    const float* ln1g   = (const float*)d_in[23];
    const float* ln1b   = (const float*)d_in[24];
    const float* ln2g   = (const float*)d_in[25];
    const float* ln2b   = (const float*)d_in[26];
    const float* ln3g   = (const float*)d_in[27];
    const float* ln3b   = (const float*)d_in[28];

    const int BL = B_ * L_;        // 4096
    const int BT = B_ * T_;        // 16384
    const size_t N_LOGITS = (size_t)BL * V_;

    // --- d_ws (92 MB): K2/V2 f32 + tgt + tables + pad + out_w bf16 planes ---
    const size_t WS_NEEDED =
        (size_t)2 * BT * D_ * sizeof(float) + (size_t)BL * D_ * sizeof(float)
        + (size_t)2 * L_ * 32 * sizeof(float) + (size_t)BT * sizeof(int)
        + (size_t)2 * V_ * D_ * sizeof(bfr);
    if (ws_size < WS_NEEDED) {
        fillf_kernel<<<((size_t)out_size + 255) / 256, 256, 0, stream>>>((float*)d_out, 0.f, (size_t)out_size);
        return;
    }
    float* f_K2  = (float*)d_ws;
    float* f_V2  = f_K2 + (size_t)BT * D_;
    float* f_tgt = f_V2 + (size_t)BT * D_;
    float* f_cos = f_tgt + (size_t)BL * D_;
    float* f_sin = f_cos + (size_t)L_ * 32;
    int*   f_pad = (int*)(f_sin + (size_t)L_ * 32);
    bfr*   ow_hi = (bfr*)(f_pad + BT);
    bfr*   ow_lo = ow_hi + (size_t)V_ * D_;

    // --- d_out doubles as scratch: f32 buffers then weight bf16 planes ---
    float* f_q   = (float*)d_out;
    float* f_k   = f_q  + (size_t)BL * D_;
    float* f_v   = f_k  + (size_t)BL * D_;
    float* f_t1  = f_v  + (size_t)BL * D_;
    float* f_t2  = f_t1 + (size_t)BL * D_;
    float* f_ffh = f_t2 + (size_t)BL * D_;
    float* f_mem = f_q;  // prologue-only alias (BT*D = q..t1 exactly)
    bfr* wp = (bfr*)(f_ffh + (size_t)BL * DFF_);
    const int SZ_D2 = D_ * D_;          // 262144
    bfr* inp_hi = wp;                wp += SZ_D2;
    bfr* inp_lo = wp;                wp += SZ_D2;
    bfr* mha_hi = wp;                wp += 3 * SZ_D2;
    bfr* mha_lo = wp;                wp += 3 * SZ_D2;
    bfr* q_hi   = wp;                wp += SZ_D2;
    bfr* q_lo   = wp;                wp += SZ_D2;
    bfr* k_hi   = wp;                wp += SZ_D2;
    bfr* k_lo   = wp;                wp += SZ_D2;
    bfr* v_hi   = wp;                wp += SZ_D2;
    bfr* v_lo   = wp;                wp += SZ_D2;
    bfr* o_hi   = wp;                wp += SZ_D2;
    bfr* o_lo   = wp;                wp += SZ_D2;
    bfr* mo_hi  = wp;                wp += SZ_D2;
    bfr* mo_lo  = wp;                wp += SZ_D2;
    bfr* w1_hi  = wp;                wp += DFF_ * D_;
    bfr* w1_lo  = wp;                wp += DFF_ * D_;
    bfr* w2_hi  = wp;                wp += D_ * DFF_;
    bfr* w2_lo  = wp;                wp += D_ * DFF_;

    // --- weight splits (once per launch) ---
    split_convert_kernel<<<(SZ_D2 + 255) / 256, 256, 0, stream>>>(inp_w, inp_hi, inp_lo, SZ_D2);
    split_convert_kernel<<<(3 * SZ_D2 + 255) / 256, 256, 0, stream>>>(mha_w, mha_hi, mha_lo, 3 * SZ_D2);
    split_convert_kernel<<<(SZ_D2 + 255) / 256, 256, 0, stream>>>(qw, q_hi, q_lo, SZ_D2);
    split_convert_kernel<<<(SZ_D2 + 255) / 256, 256, 0, stream>>>(kw, k_hi, k_lo, SZ_D2);
    split_convert_kernel<<<(SZ_D2 + 255) / 256, 256, 0, stream>>>(vw, v_hi, v_lo, SZ_D2);
    split_convert_kernel<<<(SZ_D2 + 255) / 256, 256, 0, stream>>>(ow, o_hi, o_lo, SZ_D2);
    split_convert_kernel<<<(SZ_D2 + 255) / 256, 256, 0, stream>>>(mha_ow, mo_hi, mo_lo, SZ_D2);
    split_convert_kernel<<<(DFF_ * D_ + 255) / 256, 256, 0, stream>>>(w1, w1_hi, w1_lo, DFF_ * D_);
    split_convert_kernel<<<(D_ * DFF_ + 255) / 256, 256, 0, stream>>>(w2, w2_hi, w2_lo, D_ * DFF_);
    split_convert_kernel<<<(V_ * D_ + 255) / 256, 256, 0, stream>>>(out_w, ow_hi, ow_lo, V_ * D_);

    rope_tables_kernel<<<(L_ * 32 + 255) / 256, 256, 0, stream>>>(f_cos, f_sin);
    embed_kernel<<<(BL * D_ + 255) / 256, 256, 0, stream>>>(tg, emb, f_tgt);

    // prologue: memory, pad mask, cross K2/V2 (loop-invariant)
    gemm_split<0><<<dim3(D_ / 64, BT / 128), 256, 0, stream>>>(enc, inp_hi, inp_lo, inp_b, f_mem, BT, D_, INC_);
    pad_kernel<<<(BT + 255) / 256, 256, 0, stream>>>(f_mem, f_pad);
    gemm_split<0><<<dim3(D_ / 64, BT / 128), 256, 0, stream>>>(f_mem, mha_hi + (size_t)D_ * D_, mha_lo + (size_t)D_ * D_, mha_b + D_, f_K2, BT, D_, D_);
    gemm_split<0><<<dim3(D_ / 64, BT / 128), 256, 0, stream>>>(f_mem, mha_hi + (size_t)2 * D_ * D_, mha_lo + (size_t)2 * D_ * D_, mha_b + 2 * D_, f_V2, BT, D_, D_);

    for (int layer = 0; layer < NL_; ++layer) {
        // self attention
        gemm_split<0><<<dim3(D_ / 64, BL / 128), 256, 0, stream>>>(f_tgt, q_hi, q_lo, qb, f_q, BL, D_, D_);
        gemm_split<0><<<dim3(D_ / 64, BL / 128), 256, 0, stream>>>(f_tgt, k_hi, k_lo, kb, f_k, BL, D_, D_);
        gemm_split<0><<<dim3(D_ / 64, BL / 128), 256, 0, stream>>>(f_tgt, v_hi, v_lo, vb, f_v, BL, D_, D_);
        rope_apply_kernel<<<(B_ * L_ * H_ * 32 + 255) / 256, 256, 0, stream>>>(f_q, f_k, f_cos, f_sin);
        self_attn_kernel<<<B_ * H_ * L_, 128, 0, stream>>>(f_q, f_k, f_v, f_t1);
        gemm_split<0><<<dim3(D_ / 64, BL / 128), 256, 0, stream>>>(f_t1, o_hi, o_lo, ob, f_t2, BL, D_, D_);
        ln_residual_kernel<<<BL, 128, 0, stream>>>(f_tgt, f_t2, ln1g, ln1b);
        // cross attention
        gemm_split<0><<<dim3(D_ / 64, BL / 128), 256, 0, stream>>>(f_tgt, mha_hi, mha_lo, mha_b, f_q, BL, D_, D_);
        cross_attn_kernel<<<B_ * H_ * L_, 512, 0, stream>>>(f_q, f_K2, f_V2, f_pad, f_t1);
        gemm_split<0><<<dim3(D_ / 64, BL / 128), 256, 0, stream>>>(f_t1, mo_hi, mo_lo, mha_ob, f_t2, BL, D_, D_);
        ln_residual_kernel<<<BL, 128, 0, stream>>>(f_tgt, f_t2, ln2g, ln2b);
        // FFN
        gemm_split<1><<<dim3(DFF_ / 64, BL / 128), 256, 0, stream>>>(f_tgt, w1_hi, w1_lo, b1, f_ffh, BL, DFF_, D_);
        gemm_split<0><<<dim3(D_ / 64, BL / 128), 256, 0, stream>>>(f_ffh, w2_hi, w2_lo, b2, f_t2, BL, D_, DFF_);
        ln_residual_kernel<<<BL, 128, 0, stream>>>(f_tgt, f_t2, ln3g, ln3b);
    }

    // scratch (incl. d_out weight planes) dead from here; outputs f32
    float* o_logits = (float*)d_out;
    float* o_tgt = o_logits + N_LOGITS;
    gemm_split<0><<<dim3(V_ / 64, BL / 128), 256, 0, stream>>>(f_tgt, ow_hi, ow_lo, out_b, o_logits, BL, V_, D_);
    copyf_kernel<<<(BL * D_ + 255) / 256, 256, 0, stream>>>(f_tgt, o_tgt, BL * D_);
}

// Round 9
// 2004.491 us; speedup vs baseline: 4.3045x; 2.9674x over previous
//
#include <hip/hip_runtime.h>
#include <hip/hip_bf16.h>

#define B_ 32
#define T_ 512
#define L_ 128
#define INC_ 512
#define D_ 512
#define H_ 8
#define HD_ 64
#define NL_ 6
#define DFF_ 1024
#define V_ 8000
#define LDSK 40  // gemm LDS row stride (bf16)
#define AST 72   // attn LDS row stride (bf16), 16B-aligned

typedef __bf16 bfr;
typedef __attribute__((ext_vector_type(8))) __bf16 bf16x8;
typedef __attribute__((ext_vector_type(4))) float f32x4;

// split f32 -> bf16 hi + lo planes
__global__ void split_convert_kernel(const float* __restrict__ src,
                                     bfr* __restrict__ hi, bfr* __restrict__ lo, int n)
{
    int g = blockIdx.x * 256 + threadIdx.x;
    if (g >= n) return;
    float x = src[g];
    bfr h = (bfr)x;
    hi[g] = h;
    lo[g] = (bfr)(x - (float)h);
}

// C[M,N] = act(A[M,K] @ W[N,K]^T + bias); A f32 (split in-kernel), W pre-split bf16 planes.
template <int ACT>
__global__ __launch_bounds__(256) void gemm_split(
    const float* __restrict__ A, const bfr* __restrict__ Whi, const bfr* __restrict__ Wlo,
    const float* __restrict__ bias, float* __restrict__ C, int M, int N, int K)
{
    __shared__ bfr Ah_s[128 * LDSK];
    __shared__ bfr Al_s[128 * LDSK];
    __shared__ bfr Wh_s[64 * LDSK];
    __shared__ bfr Wl_s[64 * LDSK];
    const int t = threadIdx.x;
    const int bm = blockIdx.y * 128, bn = blockIdx.x * 64;
    const int w = t >> 6, lane = t & 63;
    const int wm = w >> 1, wn = w & 1;
    const int fr = lane & 15, kq = lane >> 4;
    const int ar = t >> 1, ah = (t & 1) * 16;
    const int wr = t >> 2, wk = (t & 3) * 8;

    f32x4 acc[4][2] = {};

    for (int k0 = 0; k0 < K; k0 += 32) {
        {
            const float* ap = A + (size_t)(bm + ar) * K + (k0 + ah);
            float4 v0 = ((const float4*)ap)[0];
            float4 v1 = ((const float4*)ap)[1];
            float4 v2 = ((const float4*)ap)[2];
            float4 v3 = ((const float4*)ap)[3];
            float xs[16] = {v0.x, v0.y, v0.z, v0.w, v1.x, v1.y, v1.z, v1.w,
                            v2.x, v2.y, v2.z, v2.w, v3.x, v3.y, v3.z, v3.w};
            bf16x8 h0, h1, l0, l1;
#pragma unroll
            for (int i = 0; i < 8; ++i) {
                bfr hh = (bfr)xs[i];
                h0[i] = hh; l0[i] = (bfr)(xs[i] - (float)hh);
            }
#pragma unroll
            for (int i = 0; i < 8; ++i) {
                bfr hh = (bfr)xs[8 + i];
                h1[i] = hh; l1[i] = (bfr)(xs[8 + i] - (float)hh);
            }
            *(bf16x8*)(Ah_s + ar * LDSK + ah) = h0;
            *(bf16x8*)(Ah_s + ar * LDSK + ah + 8) = h1;
            *(bf16x8*)(Al_s + ar * LDSK + ah) = l0;
            *(bf16x8*)(Al_s + ar * LDSK + ah + 8) = l1;
        }
        {
            bf16x8 wh = *(const bf16x8*)(Whi + (size_t)(bn + wr) * K + (k0 + wk));
            bf16x8 wl = *(const bf16x8*)(Wlo + (size_t)(bn + wr) * K + (k0 + wk));
            *(bf16x8*)(Wh_s + wr * LDSK + wk) = wh;
            *(bf16x8*)(Wl_s + wr * LDSK + wk) = wl;
        }
        __syncthreads();
        bf16x8 Afh[4], Afl[4], Wfh[2], Wfl[2];
#pragma unroll
        for (int i = 0; i < 4; ++i) {
            int r = wm * 64 + i * 16 + fr;
            Afh[i] = *(const bf16x8*)(Ah_s + r * LDSK + kq * 8);
            Afl[i] = *(const bf16x8*)(Al_s + r * LDSK + kq * 8);
        }
#pragma unroll
        for (int j = 0; j < 2; ++j) {
            int r = wn * 32 + j * 16 + fr;
            Wfh[j] = *(const bf16x8*)(Wh_s + r * LDSK + kq * 8);
            Wfl[j] = *(const bf16x8*)(Wl_s + r * LDSK + kq * 8);
        }
#pragma unroll
        for (int i = 0; i < 4; ++i)
#pragma unroll
            for (int j = 0; j < 2; ++j) {
                acc[i][j] = __builtin_amdgcn_mfma_f32_16x16x32_bf16(Afh[i], Wfh[j], acc[i][j], 0, 0, 0);
                acc[i][j] = __builtin_amdgcn_mfma_f32_16x16x32_bf16(Afh[i], Wfl[j], acc[i][j], 0, 0, 0);
                acc[i][j] = __builtin_amdgcn_mfma_f32_16x16x32_bf16(Afl[i], Wfh[j], acc[i][j], 0, 0, 0);
            }
        __syncthreads();
    }
#pragma unroll
    for (int i = 0; i < 4; ++i) {
        int row0 = bm + wm * 64 + i * 16 + (lane >> 4) * 4;
#pragma unroll
        for (int j = 0; j < 2; ++j) {
            int col = bn + wn * 32 + j * 16 + fr;
            float bj = bias[col];
#pragma unroll
            for (int r = 0; r < 4; ++r) {
                float v = acc[i][j][r] + bj;
                if (ACT == 1) v = 0.5f * v * (1.0f + erff(v * 0.70710678118654752f));
                C[(size_t)(row0 + r) * N + col] = v;
            }
        }
    }
}

// Fused flash attention. Block = (b, h, q-tile of 64 rows); 4 waves x 16 q rows each.
// Layouts: Q/O rows (b*L + q)*D + h*64 + d; K/V rows (b*TK + t)*D + h*64 + d.
// CAUSAL: causal mask (TK=L); else pad-key mask via pad[b*TK + t].
template <int TK, int CAUSAL>
__global__ __launch_bounds__(256) void attn_kernel(
    const float* __restrict__ Qg, const float* __restrict__ Kg,
    const float* __restrict__ Vg, const int* __restrict__ pad,
    float* __restrict__ Og)
{
    __shared__ bfr Qs[64 * AST];
    __shared__ bfr Ks[64 * AST];
    __shared__ bfr VTs[64 * AST];
    __shared__ bfr Ps[64 * AST];
    const int bidx = blockIdx.x;
    const int qt = bidx & 1, bh = bidx >> 1;
    const int h = bh & 7, b = bh >> 3;
    const int t = threadIdx.x;
    const int w = t >> 6, lane = t & 63;
    const int l4 = lane & 15, hi4 = lane >> 4;
    const int q0 = qt * 64;
    const int srow = t >> 2, sd0 = (t & 3) * 16;  // staging: row, d-offset (16 elems)

    // stage Q tile (64x64) as bf16
    {
        const float* qp = Qg + (size_t)(b * L_ + q0 + srow) * D_ + h * HD_ + sd0;
        bf16x8 v0, v1;
#pragma unroll
        for (int i = 0; i < 8; ++i) v0[i] = (bfr)qp[i];
#pragma unroll
        for (int i = 0; i < 8; ++i) v1[i] = (bfr)qp[8 + i];
        *(bf16x8*)(Qs + srow * AST + sd0) = v0;
        *(bf16x8*)(Qs + srow * AST + sd0 + 8) = v1;
    }

    f32x4 o_acc[4] = {};
    float m_run[4], l_run[4];
#pragma unroll
    for (int r = 0; r < 4; ++r) { m_run[r] = -1e30f; l_run[r] = 0.f; }

    const int NT = CAUSAL ? (qt + 1) : (TK / 64);
    for (int kt = 0; kt < NT; ++kt) {
        __syncthreads();  // prior-iter LDS reads done (also covers Q stage on iter 0)
        {
            const float* kp = Kg + (size_t)(b * TK + kt * 64 + srow) * D_ + h * HD_ + sd0;
            bf16x8 v0, v1;
#pragma unroll
            for (int i = 0; i < 8; ++i) v0[i] = (bfr)kp[i];
#pragma unroll
            for (int i = 0; i < 8; ++i) v1[i] = (bfr)kp[8 + i];
            *(bf16x8*)(Ks + srow * AST + sd0) = v0;
            *(bf16x8*)(Ks + srow * AST + sd0 + 8) = v1;
            const float* vp = Vg + (size_t)(b * TK + kt * 64 + srow) * D_ + h * HD_ + sd0;
#pragma unroll
            for (int i = 0; i < 16; ++i) VTs[(sd0 + i) * AST + srow] = (bfr)vp[i];
        }
        __syncthreads();

        // S = Q K^T (wave rows w*16..+15, tile cols 0..63)
        f32x4 s[4] = {};
#pragma unroll
        for (int kk = 0; kk < 64; kk += 32) {
            bf16x8 a = *(const bf16x8*)(Qs + (w * 16 + l4) * AST + kk + hi4 * 8);
#pragma unroll
            for (int n = 0; n < 4; ++n) {
                bf16x8 bb = *(const bf16x8*)(Ks + (n * 16 + l4) * AST + kk + hi4 * 8);
                s[n] = __builtin_amdgcn_mfma_f32_16x16x32_bf16(a, bb, s[n], 0, 0, 0);
            }
        }
        float madd[4];
        if (!CAUSAL) {
#pragma unroll
            for (int n = 0; n < 4; ++n)
                madd[n] = pad[b * TK + kt * 64 + n * 16 + l4] ? -1e30f : 0.f;
        }
        // online softmax per row r (row = q0 + w*16 + hi4*4 + r; col = kt*64 + n*16 + l4)
#pragma unroll
        for (int r = 0; r < 4; ++r) {
            int qrow = q0 + w * 16 + hi4 * 4 + r;
            float sv[4];
#pragma unroll
            for (int n = 0; n < 4; ++n) {
                float x = s[n][r] * 0.125f;
                if (CAUSAL) {
                    int col = kt * 64 + n * 16 + l4;
                    if (col > qrow) x = -1e30f;
                } else x += madd[n];
                sv[n] = x;
            }
            float mx = fmaxf(fmaxf(sv[0], sv[1]), fmaxf(sv[2], sv[3]));
#pragma unroll
            for (int off = 1; off < 16; off <<= 1) mx = fmaxf(mx, __shfl_xor(mx, off));
            float mnew = fmaxf(m_run[r], mx);
            float alpha = expf(m_run[r] - mnew);
            float pv[4], psum = 0.f;
#pragma unroll
            for (int n = 0; n < 4; ++n) { pv[n] = expf(sv[n] - mnew); psum += pv[n]; }
#pragma unroll
            for (int off = 1; off < 16; off <<= 1) psum += __shfl_xor(psum, off);
            l_run[r] = l_run[r] * alpha + psum;
            m_run[r] = mnew;
#pragma unroll
            for (int n = 0; n < 4; ++n) o_acc[n][r] *= alpha;
#pragma unroll
            for (int n = 0; n < 4; ++n)
                Ps[(w * 16 + hi4 * 4 + r) * AST + n * 16 + l4] = (bfr)pv[n];
        }
        // O += P V   (A = P rows q, B = VT rows d; same-wave LDS ops are in-order)
#pragma unroll
        for (int kk = 0; kk < 64; kk += 32) {
            bf16x8 pa = *(const bf16x8*)(Ps + (w * 16 + l4) * AST + kk + hi4 * 8);
#pragma unroll
            for (int n = 0; n < 4; ++n) {
                bf16x8 vb = *(const bf16x8*)(VTs + (n * 16 + l4) * AST + kk + hi4 * 8);
                o_acc[n] = __builtin_amdgcn_mfma_f32_16x16x32_bf16(pa, vb, o_acc[n], 0, 0, 0);
            }
        }
    }
#pragma unroll
    for (int r = 0; r < 4; ++r) {
        float inv = 1.0f / l_run[r];
        int qrow = q0 + w * 16 + hi4 * 4 + r;
#pragma unroll
        for (int n = 0; n < 4; ++n)
            Og[(size_t)(b * L_ + qrow) * D_ + h * HD_ + n * 16 + l4] = o_acc[n][r] * inv;
    }
}

__global__ void rope_tables_kernel(float* __restrict__ cosT, float* __restrict__ sinT)
{
    int gid = blockIdx.x * blockDim.x + threadIdx.x;
    if (gid >= L_ * 32) return;
    int l = gid >> 5, i = gid & 31;
    float inv = powf(10000.0f, -(float)(2 * i) / (float)HD_);
    float ang = (float)l * inv;
    cosT[gid] = cosf(ang);
    sinT[gid] = sinf(ang);
}

__global__ void embed_kernel(const int* __restrict__ targets, const float* __restrict__ emb,
                             float* __restrict__ tgt)
{
    int gid = blockIdx.x * blockDim.x + threadIdx.x;
    if (gid >= B_ * L_ * D_) return;
    int d = gid & (D_ - 1);
    int r = gid >> 9;
    int tok = targets[r];
    tgt[gid] = emb[(size_t)tok * D_ + d] * 22.62741699796952f;
}

__global__ void pad_kernel(const float* __restrict__ mem, int* __restrict__ pad)
{
    int gid = blockIdx.x * blockDim.x + threadIdx.x;
    if (gid >= B_ * T_) return;
    const float* p = mem + (size_t)gid * D_;
    float s = 0.f;
    for (int d = 0; d < D_; ++d) s += fabsf(p[d]);
    pad[gid] = (s == 0.0f) ? 1 : 0;
}

__global__ void rope_apply_kernel(float* __restrict__ q, float* __restrict__ k,
                                  const float* __restrict__ cosT, const float* __restrict__ sinT)
{
    int gid = blockIdx.x * blockDim.x + threadIdx.x;
    if (gid >= B_ * L_ * H_ * 32) return;
    int i = gid & 31;
    int h = (gid >> 5) & (H_ - 1);
    int l = (gid >> 8) & (L_ - 1);
    int b = gid >> 15;
    float c = cosT[l * 32 + i], s = sinT[l * 32 + i];
    size_t base = ((size_t)b * L_ + l) * D_ + h * HD_;
    float x1 = q[base + i], x2 = q[base + i + 32];
    q[base + i] = x1 * c - x2 * s;
    q[base + i + 32] = x2 * c + x1 * s;
    float y1 = k[base + i], y2 = k[base + i + 32];
    k[base + i] = y1 * c - y2 * s;
    k[base + i + 32] = y2 * c + y1 * s;
}

__global__ __launch_bounds__(128) void ln_residual_kernel(
    float* __restrict__ tgt, const float* __restrict__ delta,
    const float* __restrict__ g, const float* __restrict__ bb)
{
    const int row = blockIdx.x;
    const int t = threadIdx.x;
    __shared__ float xs[D_];
    __shared__ float rbuf[128];
    size_t base = (size_t)row * D_;
    float lsum = 0.f;
    for (int d = t; d < D_; d += 128) {
        float x = tgt[base + d] + delta[base + d];
        xs[d] = x;
        lsum += x;
    }
    rbuf[t] = lsum;
    __syncthreads();
    for (int off = 64; off > 0; off >>= 1) { if (t < off) rbuf[t] += rbuf[t + off]; __syncthreads(); }
    float mean = rbuf[0] * (1.0f / D_);
    __syncthreads();
    float lv = 0.f;
    for (int d = t; d < D_; d += 128) { float dd = xs[d] - mean; lv += dd * dd; }
    rbuf[t] = lv;
    __syncthreads();
    for (int off = 64; off > 0; off >>= 1) { if (t < off) rbuf[t] += rbuf[t + off]; __syncthreads(); }
    float inv = 1.0f / sqrtf(rbuf[0] * (1.0f / D_) + 1e-5f);
    for (int d = t; d < D_; d += 128)
        tgt[base + d] = (xs[d] - mean) * inv * g[d] + bb[d];
}

__global__ void copyf_kernel(const float* __restrict__ in, float* __restrict__ out, int n)
{
    int gid = blockIdx.x * blockDim.x + threadIdx.x;
    if (gid < n) out[gid] = in[gid];
}

__global__ void fillf_kernel(float* p, float v, size_t n)
{
    size_t gid = (size_t)blockIdx.x * 256 + threadIdx.x;
    if (gid < n) p[gid] = v;
}

extern "C" void kernel_launch(void* const* d_in, const int* in_sizes, int n_in,
                              void* d_out, int out_size, void* d_ws, size_t ws_size,
                              hipStream_t stream)
{
    const float* enc    = (const float*)d_in[0];
    const int*   tg     = (const int*)d_in[1];
    const float* emb    = (const float*)d_in[2];
    const float* inp_w  = (const float*)d_in[3];
    const float* inp_b  = (const float*)d_in[4];
    const float* out_w  = (const float*)d_in[5];
    const float* out_b  = (const float*)d_in[6];
    const float* qw     = (const float*)d_in[7];
    const float* qb     = (const float*)d_in[8];
    const float* kw     = (const float*)d_in[9];
    const float* kb     = (const float*)d_in[10];
    const float* vw     = (const float*)d_in[11];
    const float* vb     = (const float*)d_in[12];
    const float* ow     = (const float*)d_in[13];
    const float* ob     = (const float*)d_in[14];
    const float* mha_w  = (const float*)d_in[15];
    const float* mha_b  = (const float*)d_in[16];
    const float* mha_ow = (const float*)d_in[17];
    const float* mha_ob = (const float*)d_in[18];
    const float* w1     = (const float*)d_in[19];
    const float* b1     = (const float*)d_in[20];
    const float* w2     = (const float*)d_in[21];
    const float* b2     = (const float*)d_in[22];
    const float* ln1g   = (const float*)d_in[23];
    const float* ln1b   = (const float*)d_in[24];
    const float* ln2g   = (const float*)d_in[25];
    const float* ln2b   = (const float*)d_in[26];
    const float* ln3g   = (const float*)d_in[27];
    const float* ln3b   = (const float*)d_in[28];

    const int BL = B_ * L_;        // 4096
    const int BT = B_ * T_;        // 16384
    const size_t N_LOGITS = (size_t)BL * V_;

    const size_t WS_NEEDED =
        (size_t)2 * BT * D_ * sizeof(float) + (size_t)BL * D_ * sizeof(float)
        + (size_t)2 * L_ * 32 * sizeof(float) + (size_t)BT * sizeof(int)
        + (size_t)2 * V_ * D_ * sizeof(bfr);
    if (ws_size < WS_NEEDED) {
        fillf_kernel<<<((size_t)out_size + 255) / 256, 256, 0, stream>>>((float*)d_out, 0.f, (size_t)out_size);
        return;
    }
    float* f_K2  = (float*)d_ws;
    float* f_V2  = f_K2 + (size_t)BT * D_;
    float* f_tgt = f_V2 + (size_t)BT * D_;
    float* f_cos = f_tgt + (size_t)BL * D_;
    float* f_sin = f_cos + (size_t)L_ * 32;
    int*   f_pad = (int*)(f_sin + (size_t)L_ * 32);
    bfr*   ow_hi = (bfr*)(f_pad + BT);
    bfr*   ow_lo = ow_hi + (size_t)V_ * D_;

    float* f_q   = (float*)d_out;
    float* f_k   = f_q  + (size_t)BL * D_;
    float* f_v   = f_k  + (size_t)BL * D_;
    float* f_t1  = f_v  + (size_t)BL * D_;
    float* f_t2  = f_t1 + (size_t)BL * D_;
    float* f_ffh = f_t2 + (size_t)BL * D_;
    float* f_mem = f_q;
    bfr* wp = (bfr*)(f_ffh + (size_t)BL * DFF_);
    const int SZ_D2 = D_ * D_;
    bfr* inp_hi = wp;                wp += SZ_D2;
    bfr* inp_lo = wp;                wp += SZ_D2;
    bfr* mha_hi = wp;                wp += 3 * SZ_D2;
    bfr* mha_lo = wp;                wp += 3 * SZ_D2;
    bfr* q_hi   = wp;                wp += SZ_D2;
    bfr* q_lo   = wp;                wp += SZ_D2;
    bfr* k_hi   = wp;                wp += SZ_D2;
    bfr* k_lo   = wp;                wp += SZ_D2;
    bfr* v_hi   = wp;                wp += SZ_D2;
    bfr* v_lo   = wp;                wp += SZ_D2;
    bfr* o_hi   = wp;                wp += SZ_D2;
    bfr* o_lo   = wp;                wp += SZ_D2;
    bfr* mo_hi  = wp;                wp += SZ_D2;
    bfr* mo_lo  = wp;                wp += SZ_D2;
    bfr* w1_hi  = wp;                wp += DFF_ * D_;
    bfr* w1_lo  = wp;                wp += DFF_ * D_;
    bfr* w2_hi  = wp;                wp += D_ * DFF_;
    bfr* w2_lo  = wp;                wp += D_ * DFF_;

    split_convert_kernel<<<(SZ_D2 + 255) / 256, 256, 0, stream>>>(inp_w, inp_hi, inp_lo, SZ_D2);
    split_convert_kernel<<<(3 * SZ_D2 + 255) / 256, 256, 0, stream>>>(mha_w, mha_hi, mha_lo, 3 * SZ_D2);
    split_convert_kernel<<<(SZ_D2 + 255) / 256, 256, 0, stream>>>(qw, q_hi, q_lo, SZ_D2);
    split_convert_kernel<<<(SZ_D2 + 255) / 256, 256, 0, stream>>>(kw, k_hi, k_lo, SZ_D2);
    split_convert_kernel<<<(SZ_D2 + 255) / 256, 256, 0, stream>>>(vw, v_hi, v_lo, SZ_D2);
    split_convert_kernel<<<(SZ_D2 + 255) / 256, 256, 0, stream>>>(ow, o_hi, o_lo, SZ_D2);
    split_convert_kernel<<<(SZ_D2 + 255) / 256, 256, 0, stream>>>(mha_ow, mo_hi, mo_lo, SZ_D2);
    split_convert_kernel<<<(DFF_ * D_ + 255) / 256, 256, 0, stream>>>(w1, w1_hi, w1_lo, DFF_ * D_);
    split_convert_kernel<<<(D_ * DFF_ + 255) / 256, 256, 0, stream>>>(w2, w2_hi, w2_lo, D_ * DFF_);
    split_convert_kernel<<<(V_ * D_ + 255) / 256, 256, 0, stream>>>(out_w, ow_hi, ow_lo, V_ * D_);

    rope_tables_kernel<<<(L_ * 32 + 255) / 256, 256, 0, stream>>>(f_cos, f_sin);
    embed_kernel<<<(BL * D_ + 255) / 256, 256, 0, stream>>>(tg, emb, f_tgt);

    gemm_split<0><<<dim3(D_ / 64, BT / 128), 256, 0, stream>>>(enc, inp_hi, inp_lo, inp_b, f_mem, BT, D_, INC_);
    pad_kernel<<<(BT + 255) / 256, 256, 0, stream>>>(f_mem, f_pad);
    gemm_split<0><<<dim3(D_ / 64, BT / 128), 256, 0, stream>>>(f_mem, mha_hi + (size_t)D_ * D_, mha_lo + (size_t)D_ * D_, mha_b + D_, f_K2, BT, D_, D_);
    gemm_split<0><<<dim3(D_ / 64, BT / 128), 256, 0, stream>>>(f_mem, mha_hi + (size_t)2 * D_ * D_, mha_lo + (size_t)2 * D_ * D_, mha_b + 2 * D_, f_V2, BT, D_, D_);

    for (int layer = 0; layer < NL_; ++layer) {
        // self attention
        gemm_split<0><<<dim3(D_ / 64, BL / 128), 256, 0, stream>>>(f_tgt, q_hi, q_lo, qb, f_q, BL, D_, D_);
        gemm_split<0><<<dim3(D_ / 64, BL / 128), 256, 0, stream>>>(f_tgt, k_hi, k_lo, kb, f_k, BL, D_, D_);
        gemm_split<0><<<dim3(D_ / 64, BL / 128), 256, 0, stream>>>(f_tgt, v_hi, v_lo, vb, f_v, BL, D_, D_);
        rope_apply_kernel<<<(B_ * L_ * H_ * 32 + 255) / 256, 256, 0, stream>>>(f_q, f_k, f_cos, f_sin);
        attn_kernel<L_, 1><<<B_ * H_ * 2, 256, 0, stream>>>(f_q, f_k, f_v, nullptr, f_t1);
        gemm_split<0><<<dim3(D_ / 64, BL / 128), 256, 0, stream>>>(f_t1, o_hi, o_lo, ob, f_t2, BL, D_, D_);
        ln_residual_kernel<<<BL, 128, 0, stream>>>(f_tgt, f_t2, ln1g, ln1b);
        // cross attention
        gemm_split<0><<<dim3(D_ / 64, BL / 128), 256, 0, stream>>>(f_tgt, mha_hi, mha_lo, mha_b, f_q, BL, D_, D_);
        attn_kernel<T_, 0><<<B_ * H_ * 2, 256, 0, stream>>>(f_q, f_K2, f_V2, f_pad, f_t1);
        gemm_split<0><<<dim3(D_ / 64, BL / 128), 256, 0, stream>>>(f_t1, mo_hi, mo_lo, mha_ob, f_t2, BL, D_, D_);
        ln_residual_kernel<<<BL, 128, 0, stream>>>(f_tgt, f_t2, ln2g, ln2b);
        // FFN
        gemm_split<1><<<dim3(DFF_ / 64, BL / 128), 256, 0, stream>>>(f_tgt, w1_hi, w1_lo, b1, f_ffh, BL, DFF_, D_);
        gemm_split<0><<<dim3(D_ / 64, BL / 128), 256, 0, stream>>>(f_ffh, w2_hi, w2_lo, b2, f_t2, BL, D_, DFF_);
        ln_residual_kernel<<<BL, 128, 0, stream>>>(f_tgt, f_t2, ln3g, ln3b);
    }

    float* o_logits = (float*)d_out;
    float* o_tgt = o_logits + N_LOGITS;
    gemm_split<0><<<dim3(V_ / 64, BL / 128), 256, 0, stream>>>(f_tgt, ow_hi, ow_lo, out_b, o_logits, BL, V_, D_);
    copyf_kernel<<<(BL * D_ + 255) / 256, 256, 0, stream>>>(f_tgt, o_tgt, BL * D_);
}

// Round 10
// 1713.929 us; speedup vs baseline: 5.0343x; 1.1695x over previous
//
#include <hip/hip_runtime.h>
#include <hip/hip_bf16.h>

#define B_ 32
#define T_ 512
#define L_ 128
#define INC_ 512
#define D_ 512
#define H_ 8
#define HD_ 64
#define NL_ 6
#define DFF_ 1024
#define V_ 8000
#define LDSK 40  // gemm LDS row stride (bf16)
#define AST 72   // attn LDS row stride (bf16)

typedef __bf16 bfr;
typedef __attribute__((ext_vector_type(8))) __bf16 bf16x8;
typedef __attribute__((ext_vector_type(4))) float f32x4;

// split f32 -> bf16 hi + lo planes
__global__ void split_convert_kernel(const float* __restrict__ src,
                                     bfr* __restrict__ hi, bfr* __restrict__ lo, int n)
{
    int g = blockIdx.x * 256 + threadIdx.x;
    if (g >= n) return;
    float x = src[g];
    bfr h = (bfr)x;
    hi[g] = h;
    lo[g] = (bfr)(x - (float)h);
}

// ---- GEMM, A = f32 (in-kernel split). Prologue only. OUT: 0=f32, 1=bf16 ----
template <int OUT>
__global__ __launch_bounds__(256) void gemm_split(
    const float* __restrict__ A, const bfr* __restrict__ Whi, const bfr* __restrict__ Wlo,
    const float* __restrict__ bias, float* __restrict__ Cf, bfr* __restrict__ Cb,
    int M, int N, int K)
{
    __shared__ bfr Ah_s[128 * LDSK];
    __shared__ bfr Al_s[128 * LDSK];
    __shared__ bfr Wh_s[64 * LDSK];
    __shared__ bfr Wl_s[64 * LDSK];
    const int t = threadIdx.x;
    const int bm = blockIdx.y * 128, bn = blockIdx.x * 64;
    const int w = t >> 6, lane = t & 63;
    const int wm = w >> 1, wn = w & 1;
    const int fr = lane & 15, kq = lane >> 4;
    const int ar = t >> 1, ah = (t & 1) * 16;
    const int wr = t >> 2, wk = (t & 3) * 8;

    f32x4 acc[4][2] = {};

    for (int k0 = 0; k0 < K; k0 += 32) {
        {
            const float* ap = A + (size_t)(bm + ar) * K + (k0 + ah);
            float4 v0 = ((const float4*)ap)[0];
            float4 v1 = ((const float4*)ap)[1];
            float4 v2 = ((const float4*)ap)[2];
            float4 v3 = ((const float4*)ap)[3];
            float xs[16] = {v0.x, v0.y, v0.z, v0.w, v1.x, v1.y, v1.z, v1.w,
                            v2.x, v2.y, v2.z, v2.w, v3.x, v3.y, v3.z, v3.w};
            bf16x8 h0, h1, l0, l1;
#pragma unroll
            for (int i = 0; i < 8; ++i) {
                bfr hh = (bfr)xs[i];
                h0[i] = hh; l0[i] = (bfr)(xs[i] - (float)hh);
            }
#pragma unroll
            for (int i = 0; i < 8; ++i) {
                bfr hh = (bfr)xs[8 + i];
                h1[i] = hh; l1[i] = (bfr)(xs[8 + i] - (float)hh);
            }
            *(bf16x8*)(Ah_s + ar * LDSK + ah) = h0;
            *(bf16x8*)(Ah_s + ar * LDSK + ah + 8) = h1;
            *(bf16x8*)(Al_s + ar * LDSK + ah) = l0;
            *(bf16x8*)(Al_s + ar * LDSK + ah + 8) = l1;
        }
        {
            bf16x8 wh = *(const bf16x8*)(Whi + (size_t)(bn + wr) * K + (k0 + wk));
            bf16x8 wl = *(const bf16x8*)(Wlo + (size_t)(bn + wr) * K + (k0 + wk));
            *(bf16x8*)(Wh_s + wr * LDSK + wk) = wh;
            *(bf16x8*)(Wl_s + wr * LDSK + wk) = wl;
        }
        __syncthreads();
        bf16x8 Afh[4], Afl[4], Wfh[2], Wfl[2];
#pragma unroll
        for (int i = 0; i < 4; ++i) {
            int r = wm * 64 + i * 16 + fr;
            Afh[i] = *(const bf16x8*)(Ah_s + r * LDSK + kq * 8);
            Afl[i] = *(const bf16x8*)(Al_s + r * LDSK + kq * 8);
        }
#pragma unroll
        for (int j = 0; j < 2; ++j) {
            int r = wn * 32 + j * 16 + fr;
            Wfh[j] = *(const bf16x8*)(Wh_s + r * LDSK + kq * 8);
            Wfl[j] = *(const bf16x8*)(Wl_s + r * LDSK + kq * 8);
        }
#pragma unroll
        for (int i = 0; i < 4; ++i)
#pragma unroll
            for (int j = 0; j < 2; ++j) {
                acc[i][j] = __builtin_amdgcn_mfma_f32_16x16x32_bf16(Afh[i], Wfh[j], acc[i][j], 0, 0, 0);
                acc[i][j] = __builtin_amdgcn_mfma_f32_16x16x32_bf16(Afh[i], Wfl[j], acc[i][j], 0, 0, 0);
                acc[i][j] = __builtin_amdgcn_mfma_f32_16x16x32_bf16(Afl[i], Wfh[j], acc[i][j], 0, 0, 0);
            }
        __syncthreads();
    }
#pragma unroll
    for (int i = 0; i < 4; ++i) {
        int row0 = bm + wm * 64 + i * 16 + (lane >> 4) * 4;
#pragma unroll
        for (int j = 0; j < 2; ++j) {
            int col = bn + wn * 32 + j * 16 + fr;
            float bj = bias[col];
#pragma unroll
            for (int r = 0; r < 4; ++r) {
                float v = acc[i][j][r] + bj;
                if (OUT == 0) Cf[(size_t)(row0 + r) * N + col] = v;
                else Cb[(size_t)(row0 + r) * N + col] = (bfr)v;
            }
        }
    }
}

// ---- GEMM, A pre-split bf16 planes. OUT: 0=f32, 1=bf16, 2=split planes ----
template <int ACT, int OUT>
__global__ __launch_bounds__(256) void gemm_ps(
    const bfr* __restrict__ Ahi, const bfr* __restrict__ Alo,
    const bfr* __restrict__ Whi, const bfr* __restrict__ Wlo,
    const float* __restrict__ bias, float* __restrict__ Cf,
    bfr* __restrict__ Chi, bfr* __restrict__ Clo, int M, int N, int K)
{
    __shared__ bfr Ah_s[128 * LDSK];
    __shared__ bfr Al_s[128 * LDSK];
    __shared__ bfr Wh_s[64 * LDSK];
    __shared__ bfr Wl_s[64 * LDSK];
    const int t = threadIdx.x;
    const int bm = blockIdx.y * 128, bn = blockIdx.x * 64;
    const int w = t >> 6, lane = t & 63;
    const int wm = w >> 1, wn = w & 1;
    const int fr = lane & 15, kq = lane >> 4;
    const int ar = t >> 1, ah = (t & 1) * 16;
    const int wr = t >> 2, wk = (t & 3) * 8;

    f32x4 acc[4][2] = {};

    for (int k0 = 0; k0 < K; k0 += 32) {
        {
            const bfr* ap = Ahi + (size_t)(bm + ar) * K + (k0 + ah);
            const bfr* al = Alo + (size_t)(bm + ar) * K + (k0 + ah);
            *(bf16x8*)(Ah_s + ar * LDSK + ah) = *(const bf16x8*)ap;
            *(bf16x8*)(Ah_s + ar * LDSK + ah + 8) = *(const bf16x8*)(ap + 8);
            *(bf16x8*)(Al_s + ar * LDSK + ah) = *(const bf16x8*)al;
            *(bf16x8*)(Al_s + ar * LDSK + ah + 8) = *(const bf16x8*)(al + 8);
        }
        {
            *(bf16x8*)(Wh_s + wr * LDSK + wk) = *(const bf16x8*)(Whi + (size_t)(bn + wr) * K + (k0 + wk));
            *(bf16x8*)(Wl_s + wr * LDSK + wk) = *(const bf16x8*)(Wlo + (size_t)(bn + wr) * K + (k0 + wk));
        }
        __syncthreads();
        bf16x8 Afh[4], Afl[4], Wfh[2], Wfl[2];
#pragma unroll
        for (int i = 0; i < 4; ++i) {
            int r = wm * 64 + i * 16 + fr;
            Afh[i] = *(const bf16x8*)(Ah_s + r * LDSK + kq * 8);
            Afl[i] = *(const bf16x8*)(Al_s + r * LDSK + kq * 8);
        }
#pragma unroll
        for (int j = 0; j < 2; ++j) {
            int r = wn * 32 + j * 16 + fr;
            Wfh[j] = *(const bf16x8*)(Wh_s + r * LDSK + kq * 8);
            Wfl[j] = *(const bf16x8*)(Wl_s + r * LDSK + kq * 8);
        }
#pragma unroll
        for (int i = 0; i < 4; ++i)
#pragma unroll
            for (int j = 0; j < 2; ++j) {
                acc[i][j] = __builtin_amdgcn_mfma_f32_16x16x32_bf16(Afh[i], Wfh[j], acc[i][j], 0, 0, 0);
                acc[i][j] = __builtin_amdgcn_mfma_f32_16x16x32_bf16(Afh[i], Wfl[j], acc[i][j], 0, 0, 0);
                acc[i][j] = __builtin_amdgcn_mfma_f32_16x16x32_bf16(Afl[i], Wfh[j], acc[i][j], 0, 0, 0);
            }
        __syncthreads();
    }
#pragma unroll
    for (int i = 0; i < 4; ++i) {
        int row0 = bm + wm * 64 + i * 16 + (lane >> 4) * 4;
#pragma unroll
        for (int j = 0; j < 2; ++j) {
            int col = bn + wn * 32 + j * 16 + fr;
            float bj = bias[col];
#pragma unroll
            for (int r = 0; r < 4; ++r) {
                float v = acc[i][j][r] + bj;
                if (ACT == 1) v = 0.5f * v * (1.0f + erff(v * 0.70710678118654752f));
                size_t idx = (size_t)(row0 + r) * N + col;
                if (OUT == 0) Cf[idx] = v;
                else if (OUT == 1) Chi[idx] = (bfr)v;
                else {
                    bfr hh = (bfr)v;
                    Chi[idx] = hh;
                    Clo[idx] = (bfr)(v - (float)hh);
                }
            }
        }
    }
}

// ---- fused flash attention, bf16 inputs; RoPE folded in when CAUSAL ----
// Block = (b, h, 64-row q-tile); 4 waves x 16 q rows.
template <int TK, int CAUSAL>
__global__ __launch_bounds__(256) void attn_kernel(
    const bfr* __restrict__ Qg, int qstr,
    const bfr* __restrict__ Kg, const bfr* __restrict__ Vg, int kvstr,
    const int* __restrict__ pad,
    const float* __restrict__ cosT, const float* __restrict__ sinT,
    bfr* __restrict__ Ohi, bfr* __restrict__ Olo)
{
    __shared__ bfr Qs[64 * AST];
    __shared__ bfr Ks[64 * AST];
    __shared__ bfr VTs[64 * AST];
    __shared__ bfr Ps[64 * AST];
    const int bidx = blockIdx.x;
    const int qt = bidx & 1, bh = bidx >> 1;
    const int h = bh & 7, b = bh >> 3;
    const int t = threadIdx.x;
    const int w = t >> 6, lane = t & 63;
    const int l4 = lane & 15, hi4 = lane >> 4;
    const int q0 = qt * 64;
    const int srow = t >> 2, ht = t & 3;

    // stage Q (rope if CAUSAL)
    if (CAUSAL) {
        int qrow = q0 + srow;
        const bfr* qp = Qg + (size_t)(b * L_ + qrow) * qstr + h * HD_ + ht * 8;
        bf16x8 a = *(const bf16x8*)qp;
        bf16x8 bb = *(const bf16x8*)(qp + 32);
        bf16x8 o1, o2;
#pragma unroll
        for (int j = 0; j < 8; ++j) {
            float c = cosT[qrow * 32 + ht * 8 + j], s = sinT[qrow * 32 + ht * 8 + j];
            float x1 = (float)a[j], x2 = (float)bb[j];
            o1[j] = (bfr)(x1 * c - x2 * s);
            o2[j] = (bfr)(x2 * c + x1 * s);
        }
        *(bf16x8*)(Qs + srow * AST + ht * 8) = o1;
        *(bf16x8*)(Qs + srow * AST + ht * 8 + 32) = o2;
    } else {
        const bfr* qp = Qg + (size_t)(b * L_ + q0 + srow) * qstr + h * HD_ + ht * 16;
        *(bf16x8*)(Qs + srow * AST + ht * 16) = *(const bf16x8*)qp;
        *(bf16x8*)(Qs + srow * AST + ht * 16 + 8) = *(const bf16x8*)(qp + 8);
    }

    f32x4 o_acc[4] = {};
    float m_run[4], l_run[4];
#pragma unroll
    for (int r = 0; r < 4; ++r) { m_run[r] = -1e30f; l_run[r] = 0.f; }

    const int NT = CAUSAL ? (qt + 1) : (TK / 64);
    for (int kt = 0; kt < NT; ++kt) {
        __syncthreads();  // prior LDS reads done (covers Q stage on iter 0)
        if (CAUSAL) {
            int krow = kt * 64 + srow;
            const bfr* kp = Kg + (size_t)(b * TK + krow) * kvstr + h * HD_ + ht * 8;
            bf16x8 a = *(const bf16x8*)kp;
            bf16x8 bb = *(const bf16x8*)(kp + 32);
            bf16x8 o1, o2;
#pragma unroll
            for (int j = 0; j < 8; ++j) {
                float c = cosT[krow * 32 + ht * 8 + j], s = sinT[krow * 32 + ht * 8 + j];
                float x1 = (float)a[j], x2 = (float)bb[j];
                o1[j] = (bfr)(x1 * c - x2 * s);
                o2[j] = (bfr)(x2 * c + x1 * s);
            }
            *(bf16x8*)(Ks + srow * AST + ht * 8) = o1;
            *(bf16x8*)(Ks + srow * AST + ht * 8 + 32) = o2;
        } else {
            const bfr* kp = Kg + (size_t)(b * TK + kt * 64 + srow) * kvstr + h * HD_ + ht * 16;
            *(bf16x8*)(Ks + srow * AST + ht * 16) = *(const bf16x8*)kp;
            *(bf16x8*)(Ks + srow * AST + ht * 16 + 8) = *(const bf16x8*)(kp + 8);
        }
        {
            const bfr* vp = Vg + (size_t)(b * TK + kt * 64 + srow) * kvstr + h * HD_ + ht * 16;
            bf16x8 v0 = *(const bf16x8*)vp;
            bf16x8 v1 = *(const bf16x8*)(vp + 8);
#pragma unroll
            for (int i = 0; i < 8; ++i) VTs[(ht * 16 + i) * AST + srow] = v0[i];
#pragma unroll
            for (int i = 0; i < 8; ++i) VTs[(ht * 16 + 8 + i) * AST + srow] = v1[i];
        }
        __syncthreads();

        f32x4 s[4] = {};
#pragma unroll
        for (int kk = 0; kk < 64; kk += 32) {
            bf16x8 a = *(const bf16x8*)(Qs + (w * 16 + l4) * AST + kk + hi4 * 8);
#pragma unroll
            for (int n = 0; n < 4; ++n) {
                bf16x8 bb = *(const bf16x8*)(Ks + (n * 16 + l4) * AST + kk + hi4 * 8);
                s[n] = __builtin_amdgcn_mfma_f32_16x16x32_bf16(a, bb, s[n], 0, 0, 0);
            }
        }
        float madd[4];
        if (!CAUSAL) {
#pragma unroll
            for (int n = 0; n < 4; ++n)
                madd[n] = pad[b * TK + kt * 64 + n * 16 + l4] ? -1e30f : 0.f;
        }
#pragma unroll
        for (int r = 0; r < 4; ++r) {
            int qrow = q0 + w * 16 + hi4 * 4 + r;
            float sv[4];
#pragma unroll
            for (int n = 0; n < 4; ++n) {
                float x = s[n][r] * 0.125f;
                if (CAUSAL) {
                    int col = kt * 64 + n * 16 + l4;
                    if (col > qrow) x = -1e30f;
                } else x += madd[n];
                sv[n] = x;
            }
            float mx = fmaxf(fmaxf(sv[0], sv[1]), fmaxf(sv[2], sv[3]));
#pragma unroll
            for (int off = 1; off < 16; off <<= 1) mx = fmaxf(mx, __shfl_xor(mx, off));
            float mnew = fmaxf(m_run[r], mx);
            float alpha = expf(m_run[r] - mnew);
            float pv[4], psum = 0.f;
#pragma unroll
            for (int n = 0; n < 4; ++n) { pv[n] = expf(sv[n] - mnew); psum += pv[n]; }
#pragma unroll
            for (int off = 1; off < 16; off <<= 1) psum += __shfl_xor(psum, off);
            l_run[r] = l_run[r] * alpha + psum;
            m_run[r] = mnew;
#pragma unroll
            for (int n = 0; n < 4; ++n) o_acc[n][r] *= alpha;
#pragma unroll
            for (int n = 0; n < 4; ++n)
                Ps[(w * 16 + hi4 * 4 + r) * AST + n * 16 + l4] = (bfr)pv[n];
        }
#pragma unroll
        for (int kk = 0; kk < 64; kk += 32) {
            bf16x8 pa = *(const bf16x8*)(Ps + (w * 16 + l4) * AST + kk + hi4 * 8);
#pragma unroll
            for (int n = 0; n < 4; ++n) {
                bf16x8 vb = *(const bf16x8*)(VTs + (n * 16 + l4) * AST + kk + hi4 * 8);
                o_acc[n] = __builtin_amdgcn_mfma_f32_16x16x32_bf16(pa, vb, o_acc[n], 0, 0, 0);
            }
        }
    }
#pragma unroll
    for (int r = 0; r < 4; ++r) {
        float inv = 1.0f / l_run[r];
        int qrow = q0 + w * 16 + hi4 * 4 + r;
#pragma unroll
        for (int n = 0; n < 4; ++n) {
            float v = o_acc[n][r] * inv;
            size_t idx = (size_t)(b * L_ + qrow) * D_ + h * HD_ + n * 16 + l4;
            bfr hh = (bfr)v;
            Ohi[idx] = hh;
            Olo[idx] = (bfr)(v - (float)hh);
        }
    }
}

__global__ void rope_tables_kernel(float* __restrict__ cosT, float* __restrict__ sinT)
{
    int gid = blockIdx.x * blockDim.x + threadIdx.x;
    if (gid >= L_ * 32) return;
    int l = gid >> 5, i = gid & 31;
    float inv = powf(10000.0f, -(float)(2 * i) / (float)HD_);
    float ang = (float)l * inv;
    cosT[gid] = cosf(ang);
    sinT[gid] = sinf(ang);
}

__global__ void embed_kernel(const int* __restrict__ targets, const float* __restrict__ emb,
                             float* __restrict__ tgt, bfr* __restrict__ thi, bfr* __restrict__ tlo)
{
    int gid = blockIdx.x * blockDim.x + threadIdx.x;
    if (gid >= B_ * L_ * D_) return;
    int d = gid & (D_ - 1);
    int r = gid >> 9;
    int tok = targets[r];
    float x = emb[(size_t)tok * D_ + d] * 22.62741699796952f;
    tgt[gid] = x;
    bfr hh = (bfr)x;
    thi[gid] = hh;
    tlo[gid] = (bfr)(x - (float)hh);
}

__global__ void pad_kernel(const float* __restrict__ mem, int* __restrict__ pad)
{
    int gid = blockIdx.x * blockDim.x + threadIdx.x;
    if (gid >= B_ * T_) return;
    const float* p = mem + (size_t)gid * D_;
    float s = 0.f;
    for (int d = 0; d < D_; ++d) s += fabsf(p[d]);
    pad[gid] = (s == 0.0f) ? 1 : 0;
}

// tgt = LN(tgt + delta); writes f32 + split planes
__global__ __launch_bounds__(128) void ln_residual_kernel(
    float* __restrict__ tgt, const float* __restrict__ delta,
    const float* __restrict__ g, const float* __restrict__ bb,
    bfr* __restrict__ thi, bfr* __restrict__ tlo)
{
    const int row = blockIdx.x;
    const int t = threadIdx.x;
    __shared__ float xs[D_];
    __shared__ float rbuf[128];
    size_t base = (size_t)row * D_;
    float lsum = 0.f;
    for (int d = t; d < D_; d += 128) {
        float x = tgt[base + d] + delta[base + d];
        xs[d] = x;
        lsum += x;
    }
    rbuf[t] = lsum;
    __syncthreads();
    for (int off = 64; off > 0; off >>= 1) { if (t < off) rbuf[t] += rbuf[t + off]; __syncthreads(); }
    float mean = rbuf[0] * (1.0f / D_);
    __syncthreads();
    float lv = 0.f;
    for (int d = t; d < D_; d += 128) { float dd = xs[d] - mean; lv += dd * dd; }
    rbuf[t] = lv;
    __syncthreads();
    for (int off = 64; off > 0; off >>= 1) { if (t < off) rbuf[t] += rbuf[t + off]; __syncthreads(); }
    float inv = 1.0f / sqrtf(rbuf[0] * (1.0f / D_) + 1e-5f);
    for (int d = t; d < D_; d += 128) {
        float y = (xs[d] - mean) * inv * g[d] + bb[d];
        tgt[base + d] = y;
        bfr hh = (bfr)y;
        thi[base + d] = hh;
        tlo[base + d] = (bfr)(y - (float)hh);
    }
}

__global__ void copyf_kernel(const float* __restrict__ in, float* __restrict__ out, int n)
{
    int gid = blockIdx.x * blockDim.x + threadIdx.x;
    if (gid < n) out[gid] = in[gid];
}

__global__ void fillf_kernel(float* p, float v, size_t n)
{
    size_t gid = (size_t)blockIdx.x * 256 + threadIdx.x;
    if (gid < n) p[gid] = v;
}

extern "C" void kernel_launch(void* const* d_in, const int* in_sizes, int n_in,
                              void* d_out, int out_size, void* d_ws, size_t ws_size,
                              hipStream_t stream)
{
    const float* enc    = (const float*)d_in[0];
    const int*   tg     = (const int*)d_in[1];
    const float* emb    = (const float*)d_in[2];
    const float* inp_w  = (const float*)d_in[3];
    const float* inp_b  = (const float*)d_in[4];
    const float* out_w  = (const float*)d_in[5];
    const float* out_b  = (const float*)d_in[6];
    const float* qw     = (const float*)d_in[7];
    const float* qb     = (const float*)d_in[8];
    const float* kw     = (const float*)d_in[9];
    const float* kb     = (const float*)d_in[10];
    const float* vw     = (const float*)d_in[11];
    const float* vb     = (const float*)d_in[12];
    const float* ow     = (const float*)d_in[13];
    const float* ob     = (const float*)d_in[14];
    const float* mha_w  = (const float*)d_in[15];
    const float* mha_b  = (const float*)d_in[16];
    const float* mha_ow = (const float*)d_in[17];
    const float* mha_ob = (const float*)d_in[18];
    const float* w1     = (const float*)d_in[19];
    const float* b1     = (const float*)d_in[20];
    const float* w2     = (const float*)d_in[21];
    const float* b2     = (const float*)d_in[22];
    const float* ln1g   = (const float*)d_in[23];
    const float* ln1b   = (const float*)d_in[24];
    const float* ln2g   = (const float*)d_in[25];
    const float* ln2b   = (const float*)d_in[26];
    const float* ln3g   = (const float*)d_in[27];
    const float* ln3b   = (const float*)d_in[28];

    const int BL = B_ * L_;        // 4096
    const int BT = B_ * T_;        // 16384
    const size_t N_LOGITS = (size_t)BL * V_;
    const int D2 = D_ * D_;        // 262144

    // --- d_ws (~67 MB): K2/V2 bf16, tgt f32 + planes, tables, pad, out_w planes ---
    const size_t WS_NEEDED =
        (size_t)2 * BT * D_ * sizeof(bfr) + (size_t)BL * D_ * sizeof(float)
        + (size_t)2 * BL * D_ * sizeof(bfr)
        + (size_t)2 * L_ * 32 * sizeof(float) + (size_t)BT * sizeof(int)
        + (size_t)2 * V_ * D_ * sizeof(bfr);
    if (ws_size < WS_NEEDED) {
        fillf_kernel<<<((size_t)out_size + 255) / 256, 256, 0, stream>>>((float*)d_out, 0.f, (size_t)out_size);
        return;
    }
    bfr*   f_K2b = (bfr*)d_ws;
    bfr*   f_V2b = f_K2b + (size_t)BT * D_;
    float* f_tgt = (float*)(f_V2b + (size_t)BT * D_);
    bfr*   tgt_hi = (bfr*)(f_tgt + (size_t)BL * D_);
    bfr*   tgt_lo = tgt_hi + (size_t)BL * D_;
    float* f_cos = (float*)(tgt_lo + (size_t)BL * D_);
    float* f_sin = f_cos + (size_t)L_ * 32;
    int*   f_pad = (int*)(f_sin + (size_t)L_ * 32);
    bfr*   ow_hi = (bfr*)(f_pad + BT);
    bfr*   ow_lo = ow_hi + (size_t)V_ * D_;

    // --- d_out: weight planes (13 MB) + layer buffers (~50 MB); all dead before logits ---
    bfr* wp = (bfr*)d_out;
    bfr* qkvw_hi = wp;  wp += 3 * D2;
    bfr* qkvw_lo = wp;  wp += 3 * D2;
    bfr* inp_hi  = wp;  wp += D2;
    bfr* inp_lo  = wp;  wp += D2;
    bfr* mha_hi  = wp;  wp += 3 * D2;
    bfr* mha_lo  = wp;  wp += 3 * D2;
    bfr* o_hi    = wp;  wp += D2;
    bfr* o_lo    = wp;  wp += D2;
    bfr* mo_hi   = wp;  wp += D2;
    bfr* mo_lo   = wp;  wp += D2;
    bfr* w1_hi   = wp;  wp += DFF_ * D_;
    bfr* w1_lo   = wp;  wp += DFF_ * D_;
    bfr* w2_hi   = wp;  wp += D_ * DFF_;
    bfr* w2_lo   = wp;  wp += D_ * DFF_;
    float* f_qkvb = (float*)wp;                 // [1536]
    float* lr    = f_qkvb + 3 * D_;             // layer region start
    float* f_t2  = lr;
    bfr*   qkv   = (bfr*)(f_t2 + (size_t)BL * D_);        // [BL,1536]
    bfr*   qcr   = qkv + (size_t)BL * 3 * D_;             // [BL,512]
    bfr*   t1_hi = qcr + (size_t)BL * D_;
    bfr*   t1_lo = t1_hi + (size_t)BL * D_;
    bfr*   ffh_hi = t1_lo + (size_t)BL * D_;              // [BL,1024]
    bfr*   ffh_lo = ffh_hi + (size_t)BL * DFF_;
    float* f_mem = lr;  // prologue-only alias (BT*D f32 = 33.5MB fits layer region)

    // weight splits (once per launch)
    split_convert_kernel<<<(D2 + 255) / 256, 256, 0, stream>>>(qw, qkvw_hi, qkvw_lo, D2);
    split_convert_kernel<<<(D2 + 255) / 256, 256, 0, stream>>>(kw, qkvw_hi + D2, qkvw_lo + D2, D2);
    split_convert_kernel<<<(D2 + 255) / 256, 256, 0, stream>>>(vw, qkvw_hi + 2 * D2, qkvw_lo + 2 * D2, D2);
    split_convert_kernel<<<(D2 + 255) / 256, 256, 0, stream>>>(inp_w, inp_hi, inp_lo, D2);
    split_convert_kernel<<<(3 * D2 + 255) / 256, 256, 0, stream>>>(mha_w, mha_hi, mha_lo, 3 * D2);
    split_convert_kernel<<<(D2 + 255) / 256, 256, 0, stream>>>(ow, o_hi, o_lo, D2);
    split_convert_kernel<<<(D2 + 255) / 256, 256, 0, stream>>>(mha_ow, mo_hi, mo_lo, D2);
    split_convert_kernel<<<(DFF_ * D_ + 255) / 256, 256, 0, stream>>>(w1, w1_hi, w1_lo, DFF_ * D_);
    split_convert_kernel<<<(D_ * DFF_ + 255) / 256, 256, 0, stream>>>(w2, w2_hi, w2_lo, D_ * DFF_);
    split_convert_kernel<<<(V_ * D_ + 255) / 256, 256, 0, stream>>>(out_w, ow_hi, ow_lo, V_ * D_);
    copyf_kernel<<<2, 256, 0, stream>>>(qb, f_qkvb, D_);
    copyf_kernel<<<2, 256, 0, stream>>>(kb, f_qkvb + D_, D_);
    copyf_kernel<<<2, 256, 0, stream>>>(vb, f_qkvb + 2 * D_, D_);

    rope_tables_kernel<<<(L_ * 32 + 255) / 256, 256, 0, stream>>>(f_cos, f_sin);
    embed_kernel<<<(BL * D_ + 255) / 256, 256, 0, stream>>>(tg, emb, f_tgt, tgt_hi, tgt_lo);

    // prologue: memory (f32), pad, K2/V2 (bf16), loop-invariant
    gemm_split<0><<<dim3(D_ / 64, BT / 128), 256, 0, stream>>>(enc, inp_hi, inp_lo, inp_b, f_mem, nullptr, BT, D_, INC_);
    pad_kernel<<<(BT + 255) / 256, 256, 0, stream>>>(f_mem, f_pad);
    gemm_split<1><<<dim3(D_ / 64, BT / 128), 256, 0, stream>>>(f_mem, mha_hi + (size_t)D2, mha_lo + (size_t)D2, mha_b + D_, nullptr, f_K2b, BT, D_, D_);
    gemm_split<1><<<dim3(D_ / 64, BT / 128), 256, 0, stream>>>(f_mem, mha_hi + (size_t)2 * D2, mha_lo + (size_t)2 * D2, mha_b + 2 * D_, nullptr, f_V2b, BT, D_, D_);

    for (int layer = 0; layer < NL_; ++layer) {
        // self attention: fused QKV gemm -> bf16 [BL,1536]; rope inside attn
        gemm_ps<0, 1><<<dim3(3 * D_ / 64, BL / 128), 256, 0, stream>>>(tgt_hi, tgt_lo, qkvw_hi, qkvw_lo, f_qkvb, nullptr, qkv, nullptr, BL, 3 * D_, D_);
        attn_kernel<L_, 1><<<B_ * H_ * 2, 256, 0, stream>>>(qkv, 3 * D_, qkv + D_, qkv + 2 * D_, 3 * D_, nullptr, f_cos, f_sin, t1_hi, t1_lo);
        gemm_ps<0, 0><<<dim3(D_ / 64, BL / 128), 256, 0, stream>>>(t1_hi, t1_lo, o_hi, o_lo, ob, f_t2, nullptr, nullptr, BL, D_, D_);
        ln_residual_kernel<<<BL, 128, 0, stream>>>(f_tgt, f_t2, ln1g, ln1b, tgt_hi, tgt_lo);
        // cross attention
        gemm_ps<0, 1><<<dim3(D_ / 64, BL / 128), 256, 0, stream>>>(tgt_hi, tgt_lo, mha_hi, mha_lo, mha_b, nullptr, qcr, nullptr, BL, D_, D_);
        attn_kernel<T_, 0><<<B_ * H_ * 2, 256, 0, stream>>>(qcr, D_, f_K2b, f_V2b, D_, f_pad, nullptr, nullptr, t1_hi, t1_lo);
        gemm_ps<0, 0><<<dim3(D_ / 64, BL / 128), 256, 0, stream>>>(t1_hi, t1_lo, mo_hi, mo_lo, mha_ob, f_t2, nullptr, nullptr, BL, D_, D_);
        ln_residual_kernel<<<BL, 128, 0, stream>>>(f_tgt, f_t2, ln2g, ln2b, tgt_hi, tgt_lo);
        // FFN
        gemm_ps<1, 2><<<dim3(DFF_ / 64, BL / 128), 256, 0, stream>>>(tgt_hi, tgt_lo, w1_hi, w1_lo, b1, nullptr, ffh_hi, ffh_lo, BL, DFF_, D_);
        gemm_ps<0, 0><<<dim3(D_ / 64, BL / 128), 256, 0, stream>>>(ffh_hi, ffh_lo, w2_hi, w2_lo, b2, f_t2, nullptr, nullptr, BL, D_, DFF_);
        ln_residual_kernel<<<BL, 128, 0, stream>>>(f_tgt, f_t2, ln3g, ln3b, tgt_hi, tgt_lo);
    }

    // all d_out scratch dead; outputs f32 (A planes + out_w planes live in ws)
    float* o_logits = (float*)d_out;
    float* o_tgt = o_logits + N_LOGITS;
    gemm_ps<0, 0><<<dim3(V_ / 64, BL / 128), 256, 0, stream>>>(tgt_hi, tgt_lo, ow_hi, ow_lo, out_b, o_logits, nullptr, nullptr, BL, V_, D_);
    copyf_kernel<<<(BL * D_ + 255) / 256, 256, 0, stream>>>(f_tgt, o_tgt, BL * D_);
}

// Round 11
// 1498.542 us; speedup vs baseline: 5.7579x; 1.1437x over previous
//
#include <hip/hip_runtime.h>
#include <hip/hip_bf16.h>

#define B_ 32
#define T_ 512
#define L_ 128
#define INC_ 512
#define D_ 512
#define H_ 8
#define HD_ 64
#define NL_ 6
#define DFF_ 1024
#define V_ 8000
#define LDSK 40  // gemm LDS row stride (bf16)
#define AST 72   // attn LDS row stride (bf16)

typedef __bf16 bfr;
typedef __attribute__((ext_vector_type(8))) __bf16 bf16x8;
typedef __attribute__((ext_vector_type(4))) float f32x4;

// split f32 -> bf16 hi + lo planes
__global__ void split_convert_kernel(const float* __restrict__ src,
                                     bfr* __restrict__ hi, bfr* __restrict__ lo, int n)
{
    int g = blockIdx.x * 256 + threadIdx.x;
    if (g >= n) return;
    float x = src[g];
    bfr h = (bfr)x;
    hi[g] = h;
    lo[g] = (bfr)(x - (float)h);
}

// bijective XCD-chunk remap (m204) + GROUP_M tile raster -> (pm, pn)
__device__ __forceinline__ void tile_map(int bid, int nbm, int nbn, int& pm, int& pn)
{
    int nwg = nbm * nbn;
    int q = nwg >> 3, r = nwg & 7;
    int xcd = bid & 7, idx = bid >> 3;
    int wgid = (xcd < r ? xcd * (q + 1) : r * (q + 1) + (xcd - r) * q) + idx;
    const int GROUP = 8;
    int per_group = GROUP * nbn;
    int gid = wgid / per_group;
    int first = gid * GROUP;
    int gsz = min(nbm - first, GROUP);
    int rem = wgid - gid * per_group;
    pm = first + rem % gsz;
    pn = rem / gsz;
}

// ---- GEMM, A = f32 (in-kernel split). Prologue only. OUT: 0=f32, 1=bf16 ----
template <int OUT>
__global__ __launch_bounds__(256) void gemm_split(
    const float* __restrict__ A, const bfr* __restrict__ Whi, const bfr* __restrict__ Wlo,
    const float* __restrict__ bias, float* __restrict__ Cf, bfr* __restrict__ Cb,
    int M, int N, int K)
{
    __shared__ bfr Ah_s[128 * LDSK];
    __shared__ bfr Al_s[128 * LDSK];
    __shared__ bfr Wh_s[64 * LDSK];
    __shared__ bfr Wl_s[64 * LDSK];
    const int t = threadIdx.x;
    const int bm = blockIdx.y * 128, bn = blockIdx.x * 64;
    const int w = t >> 6, lane = t & 63;
    const int wm = w >> 1, wn = w & 1;
    const int fr = lane & 15, kq = lane >> 4;
    const int ar = t >> 1, ah = (t & 1) * 16;
    const int wr = t >> 2, wk = (t & 3) * 8;

    f32x4 acc[4][2] = {};

    for (int k0 = 0; k0 < K; k0 += 32) {
        {
            const float* ap = A + (size_t)(bm + ar) * K + (k0 + ah);
            float4 v0 = ((const float4*)ap)[0];
            float4 v1 = ((const float4*)ap)[1];
            float4 v2 = ((const float4*)ap)[2];
            float4 v3 = ((const float4*)ap)[3];
            float xs[16] = {v0.x, v0.y, v0.z, v0.w, v1.x, v1.y, v1.z, v1.w,
                            v2.x, v2.y, v2.z, v2.w, v3.x, v3.y, v3.z, v3.w};
            bf16x8 h0, h1, l0, l1;
#pragma unroll
            for (int i = 0; i < 8; ++i) {
                bfr hh = (bfr)xs[i];
                h0[i] = hh; l0[i] = (bfr)(xs[i] - (float)hh);
            }
#pragma unroll
            for (int i = 0; i < 8; ++i) {
                bfr hh = (bfr)xs[8 + i];
                h1[i] = hh; l1[i] = (bfr)(xs[8 + i] - (float)hh);
            }
            *(bf16x8*)(Ah_s + ar * LDSK + ah) = h0;
            *(bf16x8*)(Ah_s + ar * LDSK + ah + 8) = h1;
            *(bf16x8*)(Al_s + ar * LDSK + ah) = l0;
            *(bf16x8*)(Al_s + ar * LDSK + ah + 8) = l1;
        }
        {
            bf16x8 wh = *(const bf16x8*)(Whi + (size_t)(bn + wr) * K + (k0 + wk));
            bf16x8 wl = *(const bf16x8*)(Wlo + (size_t)(bn + wr) * K + (k0 + wk));
            *(bf16x8*)(Wh_s + wr * LDSK + wk) = wh;
            *(bf16x8*)(Wl_s + wr * LDSK + wk) = wl;
        }
        __syncthreads();
        bf16x8 Afh[4], Afl[4], Wfh[2], Wfl[2];
#pragma unroll
        for (int i = 0; i < 4; ++i) {
            int r = wm * 64 + i * 16 + fr;
            Afh[i] = *(const bf16x8*)(Ah_s + r * LDSK + kq * 8);
            Afl[i] = *(const bf16x8*)(Al_s + r * LDSK + kq * 8);
        }
#pragma unroll
        for (int j = 0; j < 2; ++j) {
            int r = wn * 32 + j * 16 + fr;
            Wfh[j] = *(const bf16x8*)(Wh_s + r * LDSK + kq * 8);
            Wfl[j] = *(const bf16x8*)(Wl_s + r * LDSK + kq * 8);
        }
#pragma unroll
        for (int i = 0; i < 4; ++i)
#pragma unroll
            for (int j = 0; j < 2; ++j) {
                acc[i][j] = __builtin_amdgcn_mfma_f32_16x16x32_bf16(Afh[i], Wfh[j], acc[i][j], 0, 0, 0);
                acc[i][j] = __builtin_amdgcn_mfma_f32_16x16x32_bf16(Afh[i], Wfl[j], acc[i][j], 0, 0, 0);
                acc[i][j] = __builtin_amdgcn_mfma_f32_16x16x32_bf16(Afl[i], Wfh[j], acc[i][j], 0, 0, 0);
            }
        __syncthreads();
    }
#pragma unroll
    for (int i = 0; i < 4; ++i) {
        int row0 = bm + wm * 64 + i * 16 + (lane >> 4) * 4;
#pragma unroll
        for (int j = 0; j < 2; ++j) {
            int col = bn + wn * 32 + j * 16 + fr;
            float bj = bias[col];
#pragma unroll
            for (int r = 0; r < 4; ++r) {
                float v = acc[i][j][r] + bj;
                if (OUT == 0) Cf[(size_t)(row0 + r) * N + col] = v;
                else Cb[(size_t)(row0 + r) * N + col] = (bfr)v;
            }
        }
    }
}

// ---- GEMM, A pre-split planes. BM in {64,128}; BN=64; 1D grid + swizzle ----
// OUT: 0=f32, 1=bf16, 2=split planes
template <int ACT, int OUT, int BM>
__global__ __launch_bounds__(256, 2) void gemm_ps(
    const bfr* __restrict__ Ahi, const bfr* __restrict__ Alo,
    const bfr* __restrict__ Whi, const bfr* __restrict__ Wlo,
    const float* __restrict__ bias, float* __restrict__ Cf,
    bfr* __restrict__ Chi, bfr* __restrict__ Clo, int M, int N, int K)
{
    constexpr int MF = BM / 32;  // A frags per wave
    __shared__ bfr Ah_s[BM * LDSK];
    __shared__ bfr Al_s[BM * LDSK];
    __shared__ bfr Wh_s[64 * LDSK];
    __shared__ bfr Wl_s[64 * LDSK];
    const int t = threadIdx.x;
    int pm, pn;
    tile_map(blockIdx.x, M / BM, N / 64, pm, pn);
    const int bm = pm * BM, bn = pn * 64;
    const int w = t >> 6, lane = t & 63;
    const int wm = w >> 1, wn = w & 1;
    const int fr = lane & 15, kq = lane >> 4;
    const int wr = t >> 2, wk = (t & 3) * 8;

    f32x4 acc[MF][2] = {};

    for (int k0 = 0; k0 < K; k0 += 32) {
        if constexpr (BM == 128) {
            const int ar = t >> 1, ah = (t & 1) * 16;
            const bfr* ap = Ahi + (size_t)(bm + ar) * K + (k0 + ah);
            const bfr* al = Alo + (size_t)(bm + ar) * K + (k0 + ah);
            *(bf16x8*)(Ah_s + ar * LDSK + ah) = *(const bf16x8*)ap;
            *(bf16x8*)(Ah_s + ar * LDSK + ah + 8) = *(const bf16x8*)(ap + 8);
            *(bf16x8*)(Al_s + ar * LDSK + ah) = *(const bf16x8*)al;
            *(bf16x8*)(Al_s + ar * LDSK + ah + 8) = *(const bf16x8*)(al + 8);
        } else {
            const int ar = t >> 2, ah = (t & 3) * 8;
            *(bf16x8*)(Ah_s + ar * LDSK + ah) = *(const bf16x8*)(Ahi + (size_t)(bm + ar) * K + (k0 + ah));
            *(bf16x8*)(Al_s + ar * LDSK + ah) = *(const bf16x8*)(Alo + (size_t)(bm + ar) * K + (k0 + ah));
        }
        {
            *(bf16x8*)(Wh_s + wr * LDSK + wk) = *(const bf16x8*)(Whi + (size_t)(bn + wr) * K + (k0 + wk));
            *(bf16x8*)(Wl_s + wr * LDSK + wk) = *(const bf16x8*)(Wlo + (size_t)(bn + wr) * K + (k0 + wk));
        }
        __syncthreads();
        bf16x8 Afh[MF], Afl[MF], Wfh[2], Wfl[2];
#pragma unroll
        for (int i = 0; i < MF; ++i) {
            int r = wm * (BM / 2) + i * 16 + fr;
            Afh[i] = *(const bf16x8*)(Ah_s + r * LDSK + kq * 8);
            Afl[i] = *(const bf16x8*)(Al_s + r * LDSK + kq * 8);
        }
#pragma unroll
        for (int j = 0; j < 2; ++j) {
            int r = wn * 32 + j * 16 + fr;
            Wfh[j] = *(const bf16x8*)(Wh_s + r * LDSK + kq * 8);
            Wfl[j] = *(const bf16x8*)(Wl_s + r * LDSK + kq * 8);
        }
#pragma unroll
        for (int i = 0; i < MF; ++i)
#pragma unroll
            for (int j = 0; j < 2; ++j) {
                acc[i][j] = __builtin_amdgcn_mfma_f32_16x16x32_bf16(Afh[i], Wfh[j], acc[i][j], 0, 0, 0);
                acc[i][j] = __builtin_amdgcn_mfma_f32_16x16x32_bf16(Afh[i], Wfl[j], acc[i][j], 0, 0, 0);
                acc[i][j] = __builtin_amdgcn_mfma_f32_16x16x32_bf16(Afl[i], Wfh[j], acc[i][j], 0, 0, 0);
            }
        __syncthreads();
    }
#pragma unroll
    for (int i = 0; i < MF; ++i) {
        int row0 = bm + wm * (BM / 2) + i * 16 + (lane >> 4) * 4;
#pragma unroll
        for (int j = 0; j < 2; ++j) {
            int col = bn + wn * 32 + j * 16 + fr;
            float bj = bias[col];
#pragma unroll
            for (int r = 0; r < 4; ++r) {
                float v = acc[i][j][r] + bj;
                if (ACT == 1) v = 0.5f * v * (1.0f + erff(v * 0.70710678118654752f));
                size_t idx = (size_t)(row0 + r) * N + col;
                if (OUT == 0) Cf[idx] = v;
                else if (OUT == 1) Chi[idx] = (bfr)v;
                else {
                    bfr hh = (bfr)v;
                    Chi[idx] = hh;
                    Clo[idx] = (bfr)(v - (float)hh);
                }
            }
        }
    }
}

// ---- fused flash attention, bf16 inputs; RoPE folded in when CAUSAL ----
template <int TK, int CAUSAL>
__global__ __launch_bounds__(256) void attn_kernel(
    const bfr* __restrict__ Qg, int qstr,
    const bfr* __restrict__ Kg, const bfr* __restrict__ Vg, int kvstr,
    const int* __restrict__ pad,
    const float* __restrict__ cosT, const float* __restrict__ sinT,
    bfr* __restrict__ Ohi, bfr* __restrict__ Olo)
{
    __shared__ bfr Qs[64 * AST];
    __shared__ bfr Ks[64 * AST];
    __shared__ bfr VTs[64 * AST];
    __shared__ bfr Ps[64 * AST];
    const int bidx = blockIdx.x;
    const int qt = bidx & 1, bh = bidx >> 1;
    const int h = bh & 7, b = bh >> 3;
    const int t = threadIdx.x;
    const int w = t >> 6, lane = t & 63;
    const int l4 = lane & 15, hi4 = lane >> 4;
    const int q0 = qt * 64;
    const int srow = t >> 2, ht = t & 3;

    if (CAUSAL) {
        int qrow = q0 + srow;
        const bfr* qp = Qg + (size_t)(b * L_ + qrow) * qstr + h * HD_ + ht * 8;
        bf16x8 a = *(const bf16x8*)qp;
        bf16x8 bb = *(const bf16x8*)(qp + 32);
        bf16x8 o1, o2;
#pragma unroll
        for (int j = 0; j < 8; ++j) {
            float c = cosT[qrow * 32 + ht * 8 + j], s = sinT[qrow * 32 + ht * 8 + j];
            float x1 = (float)a[j], x2 = (float)bb[j];
            o1[j] = (bfr)(x1 * c - x2 * s);
            o2[j] = (bfr)(x2 * c + x1 * s);
        }
        *(bf16x8*)(Qs + srow * AST + ht * 8) = o1;
        *(bf16x8*)(Qs + srow * AST + ht * 8 + 32) = o2;
    } else {
        const bfr* qp = Qg + (size_t)(b * L_ + q0 + srow) * qstr + h * HD_ + ht * 16;
        *(bf16x8*)(Qs + srow * AST + ht * 16) = *(const bf16x8*)qp;
        *(bf16x8*)(Qs + srow * AST + ht * 16 + 8) = *(const bf16x8*)(qp + 8);
    }

    f32x4 o_acc[4] = {};
    float m_run[4], l_run[4];
#pragma unroll
    for (int r = 0; r < 4; ++r) { m_run[r] = -1e30f; l_run[r] = 0.f; }

    const int NT = CAUSAL ? (qt + 1) : (TK / 64);
    for (int kt = 0; kt < NT; ++kt) {
        __syncthreads();
        if (CAUSAL) {
            int krow = kt * 64 + srow;
            const bfr* kp = Kg + (size_t)(b * TK + krow) * kvstr + h * HD_ + ht * 8;
            bf16x8 a = *(const bf16x8*)kp;
            bf16x8 bb = *(const bf16x8*)(kp + 32);
            bf16x8 o1, o2;
#pragma unroll
            for (int j = 0; j < 8; ++j) {
                float c = cosT[krow * 32 + ht * 8 + j], s = sinT[krow * 32 + ht * 8 + j];
                float x1 = (float)a[j], x2 = (float)bb[j];
                o1[j] = (bfr)(x1 * c - x2 * s);
                o2[j] = (bfr)(x2 * c + x1 * s);
            }
            *(bf16x8*)(Ks + srow * AST + ht * 8) = o1;
            *(bf16x8*)(Ks + srow * AST + ht * 8 + 32) = o2;
        } else {
            const bfr* kp = Kg + (size_t)(b * TK + kt * 64 + srow) * kvstr + h * HD_ + ht * 16;
            *(bf16x8*)(Ks + srow * AST + ht * 16) = *(const bf16x8*)kp;
            *(bf16x8*)(Ks + srow * AST + ht * 16 + 8) = *(const bf16x8*)(kp + 8);
        }
        {
            const bfr* vp = Vg + (size_t)(b * TK + kt * 64 + srow) * kvstr + h * HD_ + ht * 16;
            bf16x8 v0 = *(const bf16x8*)vp;
            bf16x8 v1 = *(const bf16x8*)(vp + 8);
#pragma unroll
            for (int i = 0; i < 8; ++i) VTs[(ht * 16 + i) * AST + srow] = v0[i];
#pragma unroll
            for (int i = 0; i < 8; ++i) VTs[(ht * 16 + 8 + i) * AST + srow] = v1[i];
        }
        __syncthreads();

        f32x4 s[4] = {};
#pragma unroll
        for (int kk = 0; kk < 64; kk += 32) {
            bf16x8 a = *(const bf16x8*)(Qs + (w * 16 + l4) * AST + kk + hi4 * 8);
#pragma unroll
            for (int n = 0; n < 4; ++n) {
                bf16x8 bb = *(const bf16x8*)(Ks + (n * 16 + l4) * AST + kk + hi4 * 8);
                s[n] = __builtin_amdgcn_mfma_f32_16x16x32_bf16(a, bb, s[n], 0, 0, 0);
            }
        }
        float madd[4];
        if (!CAUSAL) {
#pragma unroll
            for (int n = 0; n < 4; ++n)
                madd[n] = pad[b * TK + kt * 64 + n * 16 + l4] ? -1e30f : 0.f;
        }
#pragma unroll
        for (int r = 0; r < 4; ++r) {
            int qrow = q0 + w * 16 + hi4 * 4 + r;
            float sv[4];
#pragma unroll
            for (int n = 0; n < 4; ++n) {
                float x = s[n][r] * 0.125f;
                if (CAUSAL) {
                    int col = kt * 64 + n * 16 + l4;
                    if (col > qrow) x = -1e30f;
                } else x += madd[n];
                sv[n] = x;
            }
            float mx = fmaxf(fmaxf(sv[0], sv[1]), fmaxf(sv[2], sv[3]));
#pragma unroll
            for (int off = 1; off < 16; off <<= 1) mx = fmaxf(mx, __shfl_xor(mx, off));
            float mnew = fmaxf(m_run[r], mx);
            float alpha = expf(m_run[r] - mnew);
            float pv[4], psum = 0.f;
#pragma unroll
            for (int n = 0; n < 4; ++n) { pv[n] = expf(sv[n] - mnew); psum += pv[n]; }
#pragma unroll
            for (int off = 1; off < 16; off <<= 1) psum += __shfl_xor(psum, off);
            l_run[r] = l_run[r] * alpha + psum;
            m_run[r] = mnew;
#pragma unroll
            for (int n = 0; n < 4; ++n) o_acc[n][r] *= alpha;
#pragma unroll
            for (int n = 0; n < 4; ++n)
                Ps[(w * 16 + hi4 * 4 + r) * AST + n * 16 + l4] = (bfr)pv[n];
        }
#pragma unroll
        for (int kk = 0; kk < 64; kk += 32) {
            bf16x8 pa = *(const bf16x8*)(Ps + (w * 16 + l4) * AST + kk + hi4 * 8);
#pragma unroll
            for (int n = 0; n < 4; ++n) {
                bf16x8 vb = *(const bf16x8*)(VTs + (n * 16 + l4) * AST + kk + hi4 * 8);
                o_acc[n] = __builtin_amdgcn_mfma_f32_16x16x32_bf16(pa, vb, o_acc[n], 0, 0, 0);
            }
        }
    }
#pragma unroll
    for (int r = 0; r < 4; ++r) {
        float inv = 1.0f / l_run[r];
        int qrow = q0 + w * 16 + hi4 * 4 + r;
#pragma unroll
        for (int n = 0; n < 4; ++n) {
            float v = o_acc[n][r] * inv;
            size_t idx = (size_t)(b * L_ + qrow) * D_ + h * HD_ + n * 16 + l4;
            bfr hh = (bfr)v;
            Ohi[idx] = hh;
            Olo[idx] = (bfr)(v - (float)hh);
        }
    }
}

__global__ void rope_tables_kernel(float* __restrict__ cosT, float* __restrict__ sinT)
{
    int gid = blockIdx.x * blockDim.x + threadIdx.x;
    if (gid >= L_ * 32) return;
    int l = gid >> 5, i = gid & 31;
    float inv = powf(10000.0f, -(float)(2 * i) / (float)HD_);
    float ang = (float)l * inv;
    cosT[gid] = cosf(ang);
    sinT[gid] = sinf(ang);
}

__global__ void embed_kernel(const int* __restrict__ targets, const float* __restrict__ emb,
                             float* __restrict__ tgt, bfr* __restrict__ thi, bfr* __restrict__ tlo)
{
    int gid = blockIdx.x * blockDim.x + threadIdx.x;
    if (gid >= B_ * L_ * D_) return;
    int d = gid & (D_ - 1);
    int r = gid >> 9;
    int tok = targets[r];
    float x = emb[(size_t)tok * D_ + d] * 22.62741699796952f;
    tgt[gid] = x;
    bfr hh = (bfr)x;
    thi[gid] = hh;
    tlo[gid] = (bfr)(x - (float)hh);
}

__global__ void pad_kernel(const float* __restrict__ mem, int* __restrict__ pad)
{
    int gid = blockIdx.x * blockDim.x + threadIdx.x;
    if (gid >= B_ * T_) return;
    const float* p = mem + (size_t)gid * D_;
    float s = 0.f;
    for (int d = 0; d < D_; ++d) s += fabsf(p[d]);
    pad[gid] = (s == 0.0f) ? 1 : 0;
}

// tgt = LN(tgt + delta); writes f32 + split planes
__global__ __launch_bounds__(128) void ln_residual_kernel(
    float* __restrict__ tgt, const float* __restrict__ delta,
    const float* __restrict__ g, const float* __restrict__ bb,
    bfr* __restrict__ thi, bfr* __restrict__ tlo)
{
    const int row = blockIdx.x;
    const int t = threadIdx.x;
    __shared__ float xs[D_];
    __shared__ float rbuf[128];
    size_t base = (size_t)row * D_;
    float lsum = 0.f;
    for (int d = t; d < D_; d += 128) {
        float x = tgt[base + d] + delta[base + d];
        xs[d] = x;
        lsum += x;
    }
    rbuf[t] = lsum;
    __syncthreads();
    for (int off = 64; off > 0; off >>= 1) { if (t < off) rbuf[t] += rbuf[t + off]; __syncthreads(); }
    float mean = rbuf[0] * (1.0f / D_);
    __syncthreads();
    float lv = 0.f;
    for (int d = t; d < D_; d += 128) { float dd = xs[d] - mean; lv += dd * dd; }
    rbuf[t] = lv;
    __syncthreads();
    for (int off = 64; off > 0; off >>= 1) { if (t < off) rbuf[t] += rbuf[t + off]; __syncthreads(); }
    float inv = 1.0f / sqrtf(rbuf[0] * (1.0f / D_) + 1e-5f);
    for (int d = t; d < D_; d += 128) {
        float y = (xs[d] - mean) * inv * g[d] + bb[d];
        tgt[base + d] = y;
        bfr hh = (bfr)y;
        thi[base + d] = hh;
        tlo[base + d] = (bfr)(y - (float)hh);
    }
}

__global__ void copyf_kernel(const float* __restrict__ in, float* __restrict__ out, int n)
{
    int gid = blockIdx.x * blockDim.x + threadIdx.x;
    if (gid < n) out[gid] = in[gid];
}

__global__ void fillf_kernel(float* p, float v, size_t n)
{
    size_t gid = (size_t)blockIdx.x * 256 + threadIdx.x;
    if (gid < n) p[gid] = v;
}

extern "C" void kernel_launch(void* const* d_in, const int* in_sizes, int n_in,
                              void* d_out, int out_size, void* d_ws, size_t ws_size,
                              hipStream_t stream)
{
    const float* enc    = (const float*)d_in[0];
    const int*   tg     = (const int*)d_in[1];
    const float* emb    = (const float*)d_in[2];
    const float* inp_w  = (const float*)d_in[3];
    const float* inp_b  = (const float*)d_in[4];
    const float* out_w  = (const float*)d_in[5];
    const float* out_b  = (const float*)d_in[6];
    const float* qw     = (const float*)d_in[7];
    const float* qb     = (const float*)d_in[8];
    const float* kw     = (const float*)d_in[9];
    const float* kb     = (const float*)d_in[10];
    const float* vw     = (const float*)d_in[11];
    const float* vb     = (const float*)d_in[12];
    const float* ow     = (const float*)d_in[13];
    const float* ob     = (const float*)d_in[14];
    const float* mha_w  = (const float*)d_in[15];
    const float* mha_b  = (const float*)d_in[16];
    const float* mha_ow = (const float*)d_in[17];
    const float* mha_ob = (const float*)d_in[18];
    const float* w1     = (const float*)d_in[19];
    const float* b1     = (const float*)d_in[20];
    const float* w2     = (const float*)d_in[21];
    const float* b2     = (const float*)d_in[22];
    const float* ln1g   = (const float*)d_in[23];
    const float* ln1b   = (const float*)d_in[24];
    const float* ln2g   = (const float*)d_in[25];
    const float* ln2b   = (const float*)d_in[26];
    const float* ln3g   = (const float*)d_in[27];
    const float* ln3b   = (const float*)d_in[28];

    const int BL = B_ * L_;        // 4096
    const int BT = B_ * T_;        // 16384
    const size_t N_LOGITS = (size_t)BL * V_;
    const int D2 = D_ * D_;        // 262144

    const size_t WS_NEEDED =
        (size_t)2 * BT * D_ * sizeof(bfr) + (size_t)BL * D_ * sizeof(float)
        + (size_t)2 * BL * D_ * sizeof(bfr)
        + (size_t)2 * L_ * 32 * sizeof(float) + (size_t)BT * sizeof(int)
        + (size_t)2 * V_ * D_ * sizeof(bfr);
    if (ws_size < WS_NEEDED) {
        fillf_kernel<<<((size_t)out_size + 255) / 256, 256, 0, stream>>>((float*)d_out, 0.f, (size_t)out_size);
        return;
    }
    bfr*   f_K2b = (bfr*)d_ws;
    bfr*   f_V2b = f_K2b + (size_t)BT * D_;
    float* f_tgt = (float*)(f_V2b + (size_t)BT * D_);
    bfr*   tgt_hi = (bfr*)(f_tgt + (size_t)BL * D_);
    bfr*   tgt_lo = tgt_hi + (size_t)BL * D_;
    float* f_cos = (float*)(tgt_lo + (size_t)BL * D_);
    float* f_sin = f_cos + (size_t)L_ * 32;
    int*   f_pad = (int*)(f_sin + (size_t)L_ * 32);
    bfr*   ow_hi = (bfr*)(f_pad + BT);
    bfr*   ow_lo = ow_hi + (size_t)V_ * D_;

    bfr* wp = (bfr*)d_out;
    bfr* qkvw_hi = wp;  wp += 3 * D2;
    bfr* qkvw_lo = wp;  wp += 3 * D2;
    bfr* inp_hi  = wp;  wp += D2;
    bfr* inp_lo  = wp;  wp += D2;
    bfr* mha_hi  = wp;  wp += 3 * D2;
    bfr* mha_lo  = wp;  wp += 3 * D2;
    bfr* o_hi    = wp;  wp += D2;
    bfr* o_lo    = wp;  wp += D2;
    bfr* mo_hi   = wp;  wp += D2;
    bfr* mo_lo   = wp;  wp += D2;
    bfr* w1_hi   = wp;  wp += DFF_ * D_;
    bfr* w1_lo   = wp;  wp += DFF_ * D_;
    bfr* w2_hi   = wp;  wp += D_ * DFF_;
    bfr* w2_lo   = wp;  wp += D_ * DFF_;
    float* f_qkvb = (float*)wp;                 // [1536]
    float* lr    = f_qkvb + 3 * D_;
    float* f_t2  = lr;
    bfr*   qkv   = (bfr*)(f_t2 + (size_t)BL * D_);
    bfr*   qcr   = qkv + (size_t)BL * 3 * D_;
    bfr*   t1_hi = qcr + (size_t)BL * D_;
    bfr*   t1_lo = t1_hi + (size_t)BL * D_;
    bfr*   ffh_hi = t1_lo + (size_t)BL * D_;
    bfr*   ffh_lo = ffh_hi + (size_t)BL * DFF_;
    float* f_mem = lr;  // prologue-only alias

    split_convert_kernel<<<(D2 + 255) / 256, 256, 0, stream>>>(qw, qkvw_hi, qkvw_lo, D2);
    split_convert_kernel<<<(D2 + 255) / 256, 256, 0, stream>>>(kw, qkvw_hi + D2, qkvw_lo + D2, D2);
    split_convert_kernel<<<(D2 + 255) / 256, 256, 0, stream>>>(vw, qkvw_hi + 2 * D2, qkvw_lo + 2 * D2, D2);
    split_convert_kernel<<<(D2 + 255) / 256, 256, 0, stream>>>(inp_w, inp_hi, inp_lo, D2);
    split_convert_kernel<<<(3 * D2 + 255) / 256, 256, 0, stream>>>(mha_w, mha_hi, mha_lo, 3 * D2);
    split_convert_kernel<<<(D2 + 255) / 256, 256, 0, stream>>>(ow, o_hi, o_lo, D2);
    split_convert_kernel<<<(D2 + 255) / 256, 256, 0, stream>>>(mha_ow, mo_hi, mo_lo, D2);
    split_convert_kernel<<<(DFF_ * D_ + 255) / 256, 256, 0, stream>>>(w1, w1_hi, w1_lo, DFF_ * D_);
    split_convert_kernel<<<(D_ * DFF_ + 255) / 256, 256, 0, stream>>>(w2, w2_hi, w2_lo, D_ * DFF_);
    split_convert_kernel<<<(V_ * D_ + 255) / 256, 256, 0, stream>>>(out_w, ow_hi, ow_lo, V_ * D_);
    copyf_kernel<<<2, 256, 0, stream>>>(qb, f_qkvb, D_);
    copyf_kernel<<<2, 256, 0, stream>>>(kb, f_qkvb + D_, D_);
    copyf_kernel<<<2, 256, 0, stream>>>(vb, f_qkvb + 2 * D_, D_);

    rope_tables_kernel<<<(L_ * 32 + 255) / 256, 256, 0, stream>>>(f_cos, f_sin);
    embed_kernel<<<(BL * D_ + 255) / 256, 256, 0, stream>>>(tg, emb, f_tgt, tgt_hi, tgt_lo);

    gemm_split<0><<<dim3(D_ / 64, BT / 128), 256, 0, stream>>>(enc, inp_hi, inp_lo, inp_b, f_mem, nullptr, BT, D_, INC_);
    pad_kernel<<<(BT + 255) / 256, 256, 0, stream>>>(f_mem, f_pad);
    gemm_split<1><<<dim3(D_ / 64, BT / 128), 256, 0, stream>>>(f_mem, mha_hi + (size_t)D2, mha_lo + (size_t)D2, mha_b + D_, nullptr, f_K2b, BT, D_, D_);
    gemm_split<1><<<dim3(D_ / 64, BT / 128), 256, 0, stream>>>(f_mem, mha_hi + (size_t)2 * D2, mha_lo + (size_t)2 * D2, mha_b + 2 * D_, nullptr, f_V2b, BT, D_, D_);

    for (int layer = 0; layer < NL_; ++layer) {
        // self attention: fused QKV gemm (BM=64) -> bf16 [BL,1536]; rope inside attn
        gemm_ps<0, 1, 64><<<(BL / 64) * (3 * D_ / 64), 256, 0, stream>>>(tgt_hi, tgt_lo, qkvw_hi, qkvw_lo, f_qkvb, nullptr, qkv, nullptr, BL, 3 * D_, D_);
        attn_kernel<L_, 1><<<B_ * H_ * 2, 256, 0, stream>>>(qkv, 3 * D_, qkv + D_, qkv + 2 * D_, 3 * D_, nullptr, f_cos, f_sin, t1_hi, t1_lo);
        gemm_ps<0, 0, 64><<<(BL / 64) * (D_ / 64), 256, 0, stream>>>(t1_hi, t1_lo, o_hi, o_lo, ob, f_t2, nullptr, nullptr, BL, D_, D_);
        ln_residual_kernel<<<BL, 128, 0, stream>>>(f_tgt, f_t2, ln1g, ln1b, tgt_hi, tgt_lo);
        // cross attention
        gemm_ps<0, 1, 64><<<(BL / 64) * (D_ / 64), 256, 0, stream>>>(tgt_hi, tgt_lo, mha_hi, mha_lo, mha_b, nullptr, qcr, nullptr, BL, D_, D_);
        attn_kernel<T_, 0><<<B_ * H_ * 2, 256, 0, stream>>>(qcr, D_, f_K2b, f_V2b, D_, f_pad, nullptr, nullptr, t1_hi, t1_lo);
        gemm_ps<0, 0, 64><<<(BL / 64) * (D_ / 64), 256, 0, stream>>>(t1_hi, t1_lo, mo_hi, mo_lo, mha_ob, f_t2, nullptr, nullptr, BL, D_, D_);
        ln_residual_kernel<<<BL, 128, 0, stream>>>(f_tgt, f_t2, ln2g, ln2b, tgt_hi, tgt_lo);
        // FFN
        gemm_ps<1, 2, 64><<<(BL / 64) * (DFF_ / 64), 256, 0, stream>>>(tgt_hi, tgt_lo, w1_hi, w1_lo, b1, nullptr, ffh_hi, ffh_lo, BL, DFF_, D_);
        gemm_ps<0, 0, 64><<<(BL / 64) * (D_ / 64), 256, 0, stream>>>(ffh_hi, ffh_lo, w2_hi, w2_lo, b2, f_t2, nullptr, nullptr, BL, D_, DFF_);
        ln_residual_kernel<<<BL, 128, 0, stream>>>(f_tgt, f_t2, ln3g, ln3b, tgt_hi, tgt_lo);
    }

    // all d_out scratch dead; outputs f32
    float* o_logits = (float*)d_out;
    float* o_tgt = o_logits + N_LOGITS;
    gemm_ps<0, 0, 128><<<(BL / 128) * (V_ / 64), 256, 0, stream>>>(tgt_hi, tgt_lo, ow_hi, ow_lo, out_b, o_logits, nullptr, nullptr, BL, V_, D_);
    copyf_kernel<<<(BL * D_ + 255) / 256, 256, 0, stream>>>(f_tgt, o_tgt, BL * D_);
}

// Round 12
// 1386.213 us; speedup vs baseline: 6.2244x; 1.0810x over previous
//
#include <hip/hip_runtime.h>
#include <hip/hip_bf16.h>

#define B_ 32
#define T_ 512
#define L_ 128
#define INC_ 512
#define D_ 512
#define H_ 8
#define HD_ 64
#define NL_ 6
#define DFF_ 1024
#define V_ 8000
#define LDSK 40  // gemm LDS row stride (bf16)
#define AST 72   // attn LDS row stride (bf16)

typedef __bf16 bfr;
typedef __attribute__((ext_vector_type(8))) __bf16 bf16x8;
typedef __attribute__((ext_vector_type(4))) __bf16 bf16x4;
typedef __attribute__((ext_vector_type(4))) float f32x4;

// ---- batched f32 -> (hi,lo) bf16 plane split ----
struct SplitDesc { const float* src; bfr* hi; bfr* lo; int n; int blk0; };
struct SplitTable { SplitDesc e[12]; int ne; };

__global__ void split_many_kernel(SplitTable tab)
{
    int b = blockIdx.x;
    for (int i = 0; i < tab.ne; ++i) {
        const SplitDesc d = tab.e[i];
        int nb = (d.n + 255) >> 8;
        if (b >= d.blk0 && b < d.blk0 + nb) {
            int g = (b - d.blk0) * 256 + threadIdx.x;
            if (g < d.n) {
                float x = d.src[g];
                bfr h = (bfr)x;
                d.hi[g] = h;
                d.lo[g] = (bfr)(x - (float)h);
            }
            return;
        }
    }
}

// bijective XCD-chunk remap (m204) + GROUP_M tile raster -> (pm, pn)
__device__ __forceinline__ void tile_map(int bid, int nbm, int nbn, int& pm, int& pn)
{
    int nwg = nbm * nbn;
    int q = nwg >> 3, r = nwg & 7;
    int xcd = bid & 7, idx = bid >> 3;
    int wgid = (xcd < r ? xcd * (q + 1) : r * (q + 1) + (xcd - r) * q) + idx;
    const int GROUP = 8;
    int per_group = GROUP * nbn;
    int gid = wgid / per_group;
    int first = gid * GROUP;
    int gsz = min(nbm - first, GROUP);
    int rem = wgid - gid * per_group;
    pm = first + rem % gsz;
    pn = rem / gsz;
}

// ---- GEMM, A = f32 (in-kernel split). Prologue only. OUT: 0=f32, 1=bf16 ----
// TERMS: 3 = Ah*Wh+Ah*Wl+Al*Wh, 2 = Ah*Wh+Ah*Wl
template <int OUT, int TERMS>
__global__ __launch_bounds__(256) void gemm_split(
    const float* __restrict__ A, const bfr* __restrict__ Whi, const bfr* __restrict__ Wlo,
    const float* __restrict__ bias, float* __restrict__ Cf, bfr* __restrict__ Cb,
    int M, int N, int K)
{
    __shared__ bfr Ah_s[128 * LDSK];
    __shared__ bfr Al_s[TERMS == 3 ? 128 * LDSK : 16];
    __shared__ bfr Wh_s[64 * LDSK];
    __shared__ bfr Wl_s[64 * LDSK];
    const int t = threadIdx.x;
    const int bm = blockIdx.y * 128, bn = blockIdx.x * 64;
    const int w = t >> 6, lane = t & 63;
    const int wm = w >> 1, wn = w & 1;
    const int fr = lane & 15, kq = lane >> 4;
    const int ar = t >> 1, ah = (t & 1) * 16;
    const int wr = t >> 2, wk = (t & 3) * 8;

    f32x4 acc[4][2] = {};

    for (int k0 = 0; k0 < K; k0 += 32) {
        {
            const float* ap = A + (size_t)(bm + ar) * K + (k0 + ah);
            float4 v0 = ((const float4*)ap)[0];
            float4 v1 = ((const float4*)ap)[1];
            float4 v2 = ((const float4*)ap)[2];
            float4 v3 = ((const float4*)ap)[3];
            float xs[16] = {v0.x, v0.y, v0.z, v0.w, v1.x, v1.y, v1.z, v1.w,
                            v2.x, v2.y, v2.z, v2.w, v3.x, v3.y, v3.z, v3.w};
            bf16x8 h0, h1;
#pragma unroll
            for (int i = 0; i < 8; ++i) h0[i] = (bfr)xs[i];
#pragma unroll
            for (int i = 0; i < 8; ++i) h1[i] = (bfr)xs[8 + i];
            *(bf16x8*)(Ah_s + ar * LDSK + ah) = h0;
            *(bf16x8*)(Ah_s + ar * LDSK + ah + 8) = h1;
            if constexpr (TERMS == 3) {
                bf16x8 l0, l1;
#pragma unroll
                for (int i = 0; i < 8; ++i) l0[i] = (bfr)(xs[i] - (float)h0[i]);
#pragma unroll
                for (int i = 0; i < 8; ++i) l1[i] = (bfr)(xs[8 + i] - (float)h1[i]);
                *(bf16x8*)(Al_s + ar * LDSK + ah) = l0;
                *(bf16x8*)(Al_s + ar * LDSK + ah + 8) = l1;
            }
        }
        {
            *(bf16x8*)(Wh_s + wr * LDSK + wk) = *(const bf16x8*)(Whi + (size_t)(bn + wr) * K + (k0 + wk));
            *(bf16x8*)(Wl_s + wr * LDSK + wk) = *(const bf16x8*)(Wlo + (size_t)(bn + wr) * K + (k0 + wk));
        }
        __syncthreads();
        bf16x8 Afh[4], Afl[4], Wfh[2], Wfl[2];
#pragma unroll
        for (int i = 0; i < 4; ++i) {
            int r = wm * 64 + i * 16 + fr;
            Afh[i] = *(const bf16x8*)(Ah_s + r * LDSK + kq * 8);
            if constexpr (TERMS == 3) Afl[i] = *(const bf16x8*)(Al_s + r * LDSK + kq * 8);
        }
#pragma unroll
        for (int j = 0; j < 2; ++j) {
            int r = wn * 32 + j * 16 + fr;
            Wfh[j] = *(const bf16x8*)(Wh_s + r * LDSK + kq * 8);
            Wfl[j] = *(const bf16x8*)(Wl_s + r * LDSK + kq * 8);
        }
#pragma unroll
        for (int i = 0; i < 4; ++i)
#pragma unroll
            for (int j = 0; j < 2; ++j) {
                acc[i][j] = __builtin_amdgcn_mfma_f32_16x16x32_bf16(Afh[i], Wfh[j], acc[i][j], 0, 0, 0);
                acc[i][j] = __builtin_amdgcn_mfma_f32_16x16x32_bf16(Afh[i], Wfl[j], acc[i][j], 0, 0, 0);
                if constexpr (TERMS == 3)
                    acc[i][j] = __builtin_amdgcn_mfma_f32_16x16x32_bf16(Afl[i], Wfh[j], acc[i][j], 0, 0, 0);
            }
        __syncthreads();
    }
#pragma unroll
    for (int i = 0; i < 4; ++i) {
        int row0 = bm + wm * 64 + i * 16 + (lane >> 4) * 4;
#pragma unroll
        for (int j = 0; j < 2; ++j) {
            int col = bn + wn * 32 + j * 16 + fr;
            float bj = bias[col];
#pragma unroll
            for (int r = 0; r < 4; ++r) {
                float v = acc[i][j][r] + bj;
                if (OUT == 0) Cf[(size_t)(row0 + r) * N + col] = v;
                else Cb[(size_t)(row0 + r) * N + col] = (bfr)v;
            }
        }
    }
}

// ---- GEMM, A pre-split planes. BM in {64,128}; 1D grid + swizzle ----
// OUT: 0=f32, 1=bf16, 2=split planes.  TERMS: 2 drops Al*Wh (Alo unused)
template <int ACT, int OUT, int BM, int TERMS>
__global__ __launch_bounds__(256, 2) void gemm_ps(
    const bfr* __restrict__ Ahi, const bfr* __restrict__ Alo,
    const bfr* __restrict__ Whi, const bfr* __restrict__ Wlo,
    const float* __restrict__ bias, float* __restrict__ Cf,
    bfr* __restrict__ Chi, bfr* __restrict__ Clo, int M, int N, int K)
{
    constexpr int MF = BM / 32;
    __shared__ bfr Ah_s[BM * LDSK];
    __shared__ bfr Al_s[TERMS == 3 ? BM * LDSK : 16];
    __shared__ bfr Wh_s[64 * LDSK];
    __shared__ bfr Wl_s[64 * LDSK];
    const int t = threadIdx.x;
    int pm, pn;
    tile_map(blockIdx.x, M / BM, N / 64, pm, pn);
    const int bm = pm * BM, bn = pn * 64;
    const int w = t >> 6, lane = t & 63;
    const int wm = w >> 1, wn = w & 1;
    const int fr = lane & 15, kq = lane >> 4;
    const int wr = t >> 2, wk = (t & 3) * 8;

    f32x4 acc[MF][2] = {};

    for (int k0 = 0; k0 < K; k0 += 32) {
        if constexpr (BM == 128) {
            const int ar = t >> 1, ah = (t & 1) * 16;
            const bfr* ap = Ahi + (size_t)(bm + ar) * K + (k0 + ah);
            *(bf16x8*)(Ah_s + ar * LDSK + ah) = *(const bf16x8*)ap;
            *(bf16x8*)(Ah_s + ar * LDSK + ah + 8) = *(const bf16x8*)(ap + 8);
            if constexpr (TERMS == 3) {
                const bfr* al = Alo + (size_t)(bm + ar) * K + (k0 + ah);
                *(bf16x8*)(Al_s + ar * LDSK + ah) = *(const bf16x8*)al;
                *(bf16x8*)(Al_s + ar * LDSK + ah + 8) = *(const bf16x8*)(al + 8);
            }
        } else {
            const int ar = t >> 2, ah = (t & 3) * 8;
            *(bf16x8*)(Ah_s + ar * LDSK + ah) = *(const bf16x8*)(Ahi + (size_t)(bm + ar) * K + (k0 + ah));
            if constexpr (TERMS == 3)
                *(bf16x8*)(Al_s + ar * LDSK + ah) = *(const bf16x8*)(Alo + (size_t)(bm + ar) * K + (k0 + ah));
        }
        {
            *(bf16x8*)(Wh_s + wr * LDSK + wk) = *(const bf16x8*)(Whi + (size_t)(bn + wr) * K + (k0 + wk));
            *(bf16x8*)(Wl_s + wr * LDSK + wk) = *(const bf16x8*)(Wlo + (size_t)(bn + wr) * K + (k0 + wk));
        }
        __syncthreads();
        bf16x8 Afh[MF], Afl[MF], Wfh[2], Wfl[2];
#pragma unroll
        for (int i = 0; i < MF; ++i) {
            int r = wm * (BM / 2) + i * 16 + fr;
            Afh[i] = *(const bf16x8*)(Ah_s + r * LDSK + kq * 8);
            if constexpr (TERMS == 3) Afl[i] = *(const bf16x8*)(Al_s + r * LDSK + kq * 8);
        }
#pragma unroll
        for (int j = 0; j < 2; ++j) {
            int r = wn * 32 + j * 16 + fr;
            Wfh[j] = *(const bf16x8*)(Wh_s + r * LDSK + kq * 8);
            Wfl[j] = *(const bf16x8*)(Wl_s + r * LDSK + kq * 8);
        }
#pragma unroll
        for (int i = 0; i < MF; ++i)
#pragma unroll
            for (int j = 0; j < 2; ++j) {
                acc[i][j] = __builtin_amdgcn_mfma_f32_16x16x32_bf16(Afh[i], Wfh[j], acc[i][j], 0, 0, 0);
                acc[i][j] = __builtin_amdgcn_mfma_f32_16x16x32_bf16(Afh[i], Wfl[j], acc[i][j], 0, 0, 0);
                if constexpr (TERMS == 3)
                    acc[i][j] = __builtin_amdgcn_mfma_f32_16x16x32_bf16(Afl[i], Wfh[j], acc[i][j], 0, 0, 0);
            }
        __syncthreads();
    }
#pragma unroll
    for (int i = 0; i < MF; ++i) {
        int row0 = bm + wm * (BM / 2) + i * 16 + (lane >> 4) * 4;
#pragma unroll
        for (int j = 0; j < 2; ++j) {
            int col = bn + wn * 32 + j * 16 + fr;
            float bj = bias[col];
#pragma unroll
            for (int r = 0; r < 4; ++r) {
                float v = acc[i][j][r] + bj;
                if (ACT == 1) v = 0.5f * v * (1.0f + erff(v * 0.70710678118654752f));
                size_t idx = (size_t)(row0 + r) * N + col;
                if (OUT == 0) Cf[idx] = v;
                else if (OUT == 1) Chi[idx] = (bfr)v;
                else {
                    bfr hh = (bfr)v;
                    Chi[idx] = hh;
                    Clo[idx] = (bfr)(v - (float)hh);
                }
            }
        }
    }
}

// ---- fused flash attention, bf16 inputs; RoPE folded in when CAUSAL ----
template <int TK, int CAUSAL>
__global__ __launch_bounds__(256) void attn_kernel(
    const bfr* __restrict__ Qg, int qstr,
    const bfr* __restrict__ Kg, const bfr* __restrict__ Vg, int kvstr,
    const int* __restrict__ pad,
    const float* __restrict__ cosT, const float* __restrict__ sinT,
    bfr* __restrict__ Ohi, bfr* __restrict__ Olo)
{
    __shared__ bfr Qs[64 * AST];
    __shared__ bfr Ks[64 * AST];
    __shared__ bfr VTs[64 * AST];
    __shared__ bfr Ps[64 * AST];
    const int bidx = blockIdx.x;
    const int qt = bidx & 1, bh = bidx >> 1;
    const int h = bh & 7, b = bh >> 3;
    const int t = threadIdx.x;
    const int w = t >> 6, lane = t & 63;
    const int l4 = lane & 15, hi4 = lane >> 4;
    const int q0 = qt * 64;
    const int srow = t >> 2, ht = t & 3;

    if (CAUSAL) {
        int qrow = q0 + srow;
        const bfr* qp = Qg + (size_t)(b * L_ + qrow) * qstr + h * HD_ + ht * 8;
        bf16x8 a = *(const bf16x8*)qp;
        bf16x8 bb = *(const bf16x8*)(qp + 32);
        bf16x8 o1, o2;
#pragma unroll
        for (int j = 0; j < 8; ++j) {
            float c = cosT[qrow * 32 + ht * 8 + j], s = sinT[qrow * 32 + ht * 8 + j];
            float x1 = (float)a[j], x2 = (float)bb[j];
            o1[j] = (bfr)(x1 * c - x2 * s);
            o2[j] = (bfr)(x2 * c + x1 * s);
        }
        *(bf16x8*)(Qs + srow * AST + ht * 8) = o1;
        *(bf16x8*)(Qs + srow * AST + ht * 8 + 32) = o2;
    } else {
        const bfr* qp = Qg + (size_t)(b * L_ + q0 + srow) * qstr + h * HD_ + ht * 16;
        *(bf16x8*)(Qs + srow * AST + ht * 16) = *(const bf16x8*)qp;
        *(bf16x8*)(Qs + srow * AST + ht * 16 + 8) = *(const bf16x8*)(qp + 8);
    }

    f32x4 o_acc[4] = {};
    float m_run[4], l_run[4];
#pragma unroll
    for (int r = 0; r < 4; ++r) { m_run[r] = -1e30f; l_run[r] = 0.f; }

    const int NT = CAUSAL ? (qt + 1) : (TK / 64);
    for (int kt = 0; kt < NT; ++kt) {
        __syncthreads();
        if (CAUSAL) {
            int krow = kt * 64 + srow;
            const bfr* kp = Kg + (size_t)(b * TK + krow) * kvstr + h * HD_ + ht * 8;
            bf16x8 a = *(const bf16x8*)kp;
            bf16x8 bb = *(const bf16x8*)(kp + 32);
            bf16x8 o1, o2;
#pragma unroll
            for (int j = 0; j < 8; ++j) {
                float c = cosT[krow * 32 + ht * 8 + j], s = sinT[krow * 32 + ht * 8 + j];
                float x1 = (float)a[j], x2 = (float)bb[j];
                o1[j] = (bfr)(x1 * c - x2 * s);
                o2[j] = (bfr)(x2 * c + x1 * s);
            }
            *(bf16x8*)(Ks + srow * AST + ht * 8) = o1;
            *(bf16x8*)(Ks + srow * AST + ht * 8 + 32) = o2;
        } else {
            const bfr* kp = Kg + (size_t)(b * TK + kt * 64 + srow) * kvstr + h * HD_ + ht * 16;
            *(bf16x8*)(Ks + srow * AST + ht * 16) = *(const bf16x8*)kp;
            *(bf16x8*)(Ks + srow * AST + ht * 16 + 8) = *(const bf16x8*)(kp + 8);
        }
        {
            const bfr* vp = Vg + (size_t)(b * TK + kt * 64 + srow) * kvstr + h * HD_ + ht * 16;
            bf16x8 v0 = *(const bf16x8*)vp;
            bf16x8 v1 = *(const bf16x8*)(vp + 8);
#pragma unroll
            for (int i = 0; i < 8; ++i) VTs[(ht * 16 + i) * AST + srow] = v0[i];
#pragma unroll
            for (int i = 0; i < 8; ++i) VTs[(ht * 16 + 8 + i) * AST + srow] = v1[i];
        }
        __syncthreads();

        f32x4 s[4] = {};
#pragma unroll
        for (int kk = 0; kk < 64; kk += 32) {
            bf16x8 a = *(const bf16x8*)(Qs + (w * 16 + l4) * AST + kk + hi4 * 8);
#pragma unroll
            for (int n = 0; n < 4; ++n) {
                bf16x8 bb = *(const bf16x8*)(Ks + (n * 16 + l4) * AST + kk + hi4 * 8);
                s[n] = __builtin_amdgcn_mfma_f32_16x16x32_bf16(a, bb, s[n], 0, 0, 0);
            }
        }
        float madd[4];
        if (!CAUSAL) {
#pragma unroll
            for (int n = 0; n < 4; ++n)
                madd[n] = pad[b * TK + kt * 64 + n * 16 + l4] ? -1e30f : 0.f;
        }
#pragma unroll
        for (int r = 0; r < 4; ++r) {
            int qrow = q0 + w * 16 + hi4 * 4 + r;
            float sv[4];
#pragma unroll
            for (int n = 0; n < 4; ++n) {
                float x = s[n][r] * 0.125f;
                if (CAUSAL) {
                    int col = kt * 64 + n * 16 + l4;
                    if (col > qrow) x = -1e30f;
                } else x += madd[n];
                sv[n] = x;
            }
            float mx = fmaxf(fmaxf(sv[0], sv[1]), fmaxf(sv[2], sv[3]));
#pragma unroll
            for (int off = 1; off < 16; off <<= 1) mx = fmaxf(mx, __shfl_xor(mx, off));
            float mnew = fmaxf(m_run[r], mx);
            float alpha = expf(m_run[r] - mnew);
            float pv[4], psum = 0.f;
#pragma unroll
            for (int n = 0; n < 4; ++n) { pv[n] = expf(sv[n] - mnew); psum += pv[n]; }
#pragma unroll
            for (int off = 1; off < 16; off <<= 1) psum += __shfl_xor(psum, off);
            l_run[r] = l_run[r] * alpha + psum;
            m_run[r] = mnew;
#pragma unroll
            for (int n = 0; n < 4; ++n) o_acc[n][r] *= alpha;
#pragma unroll
            for (int n = 0; n < 4; ++n)
                Ps[(w * 16 + hi4 * 4 + r) * AST + n * 16 + l4] = (bfr)pv[n];
        }
#pragma unroll
        for (int kk = 0; kk < 64; kk += 32) {
            bf16x8 pa = *(const bf16x8*)(Ps + (w * 16 + l4) * AST + kk + hi4 * 8);
#pragma unroll
            for (int n = 0; n < 4; ++n) {
                bf16x8 vb = *(const bf16x8*)(VTs + (n * 16 + l4) * AST + kk + hi4 * 8);
                o_acc[n] = __builtin_amdgcn_mfma_f32_16x16x32_bf16(pa, vb, o_acc[n], 0, 0, 0);
            }
        }
    }
#pragma unroll
    for (int r = 0; r < 4; ++r) {
        float inv = 1.0f / l_run[r];
        int qrow = q0 + w * 16 + hi4 * 4 + r;
#pragma unroll
        for (int n = 0; n < 4; ++n) {
            float v = o_acc[n][r] * inv;
            size_t idx = (size_t)(b * L_ + qrow) * D_ + h * HD_ + n * 16 + l4;
            bfr hh = (bfr)v;
            Ohi[idx] = hh;
            Olo[idx] = (bfr)(v - (float)hh);
        }
    }
}

__global__ void rope_tables_kernel(float* __restrict__ cosT, float* __restrict__ sinT)
{
    int gid = blockIdx.x * blockDim.x + threadIdx.x;
    if (gid >= L_ * 32) return;
    int l = gid >> 5, i = gid & 31;
    float inv = powf(10000.0f, -(float)(2 * i) / (float)HD_);
    float ang = (float)l * inv;
    cosT[gid] = cosf(ang);
    sinT[gid] = sinf(ang);
}

__global__ void embed_kernel(const int* __restrict__ targets, const float* __restrict__ emb,
                             float* __restrict__ tgt, bfr* __restrict__ thi, bfr* __restrict__ tlo)
{
    int gid = blockIdx.x * blockDim.x + threadIdx.x;
    if (gid >= B_ * L_ * D_) return;
    int d = gid & (D_ - 1);
    int r = gid >> 9;
    int tok = targets[r];
    float x = emb[(size_t)tok * D_ + d] * 22.62741699796952f;
    tgt[gid] = x;
    bfr hh = (bfr)x;
    thi[gid] = hh;
    tlo[gid] = (bfr)(x - (float)hh);
}

__global__ void pad_kernel(const float* __restrict__ mem, int* __restrict__ pad)
{
    int gid = blockIdx.x * blockDim.x + threadIdx.x;
    if (gid >= B_ * T_) return;
    const float* p = mem + (size_t)gid * D_;
    float s = 0.f;
    for (int d = 0; d < D_; ++d) s += fabsf(p[d]);
    pad[gid] = (s == 0.0f) ? 1 : 0;
}

// tgt = LN(tgt + delta); f32 + planes, register-resident rows, float4 I/O
__global__ __launch_bounds__(128) void ln_residual_kernel(
    float* __restrict__ tgt, const float* __restrict__ delta,
    const float* __restrict__ g, const float* __restrict__ bb,
    bfr* __restrict__ thi, bfr* __restrict__ tlo)
{
    const int row = blockIdx.x;
    const int t = threadIdx.x;
    __shared__ float rbuf[128];
    size_t base = (size_t)row * D_ + t * 4;
    float4 x = *(float4*)(tgt + base);
    float4 dl = *(const float4*)(delta + base);
    x.x += dl.x; x.y += dl.y; x.z += dl.z; x.w += dl.w;
    rbuf[t] = x.x + x.y + x.z + x.w;
    __syncthreads();
    for (int off = 64; off > 0; off >>= 1) { if (t < off) rbuf[t] += rbuf[t + off]; __syncthreads(); }
    float mean = rbuf[0] * (1.0f / D_);
    __syncthreads();
    float4 d4 = {x.x - mean, x.y - mean, x.z - mean, x.w - mean};
    rbuf[t] = d4.x * d4.x + d4.y * d4.y + d4.z * d4.z + d4.w * d4.w;
    __syncthreads();
    for (int off = 64; off > 0; off >>= 1) { if (t < off) rbuf[t] += rbuf[t + off]; __syncthreads(); }
    float inv = 1.0f / sqrtf(rbuf[0] * (1.0f / D_) + 1e-5f);
    float4 g4 = *(const float4*)(g + t * 4);
    float4 b4 = *(const float4*)(bb + t * 4);
    float4 y = {d4.x * inv * g4.x + b4.x, d4.y * inv * g4.y + b4.y,
                d4.z * inv * g4.z + b4.z, d4.w * inv * g4.w + b4.w};
    *(float4*)(tgt + base) = y;
    bf16x4 h4, l4;
    float yy[4] = {y.x, y.y, y.z, y.w};
#pragma unroll
    for (int i = 0; i < 4; ++i) {
        bfr hh = (bfr)yy[i];
        h4[i] = hh;
        l4[i] = (bfr)(yy[i] - (float)hh);
    }
    *(bf16x4*)(thi + base) = h4;
    *(bf16x4*)(tlo + base) = l4;
}

__global__ void copyf_kernel(const float* __restrict__ in, float* __restrict__ out, int n)
{
    int gid = blockIdx.x * blockDim.x + threadIdx.x;
    if (gid < n) out[gid] = in[gid];
}

__global__ void fillf_kernel(float* p, float v, size_t n)
{
    size_t gid = (size_t)blockIdx.x * 256 + threadIdx.x;
    if (gid < n) p[gid] = v;
}

extern "C" void kernel_launch(void* const* d_in, const int* in_sizes, int n_in,
                              void* d_out, int out_size, void* d_ws, size_t ws_size,
                              hipStream_t stream)
{
    const float* enc    = (const float*)d_in[0];
    const int*   tg     = (const int*)d_in[1];
    const float* emb    = (const float*)d_in[2];
    const float* inp_w  = (const float*)d_in[3];
    const float* inp_b  = (const float*)d_in[4];
    const float* out_w  = (const float*)d_in[5];
    const float* out_b  = (const float*)d_in[6];
    const float* qw     = (const float*)d_in[7];
    const float* qb     = (const float*)d_in[8];
    const float* kw     = (const float*)d_in[9];
    const float* kb     = (const float*)d_in[10];
    const float* vw     = (const float*)d_in[11];
    const float* vb     = (const float*)d_in[12];
    const float* ow     = (const float*)d_in[13];
    const float* ob     = (const float*)d_in[14];
    const float* mha_w  = (const float*)d_in[15];
    const float* mha_b  = (const float*)d_in[16];
    const float* mha_ow = (const float*)d_in[17];
    const float* mha_ob = (const float*)d_in[18];
    const float* w1     = (const float*)d_in[19];
    const float* b1     = (const float*)d_in[20];
    const float* w2     = (const float*)d_in[21];
    const float* b2     = (const float*)d_in[22];
    const float* ln1g   = (const float*)d_in[23];
    const float* ln1b   = (const float*)d_in[24];
    const float* ln2g   = (const float*)d_in[25];
    const float* ln2b   = (const float*)d_in[26];
    const float* ln3g   = (const float*)d_in[27];
    const float* ln3b   = (const float*)d_in[28];

    const int BL = B_ * L_;        // 4096
    const int BT = B_ * T_;        // 16384
    const size_t N_LOGITS = (size_t)BL * V_;
    const int D2 = D_ * D_;        // 262144

    const size_t WS_NEEDED =
        (size_t)2 * BT * D_ * sizeof(bfr) + (size_t)BL * D_ * sizeof(float)
        + (size_t)2 * BL * D_ * sizeof(bfr)
        + (size_t)2 * L_ * 32 * sizeof(float) + (size_t)BT * sizeof(int)
        + (size_t)2 * V_ * D_ * sizeof(bfr);
    if (ws_size < WS_NEEDED) {
        fillf_kernel<<<((size_t)out_size + 255) / 256, 256, 0, stream>>>((float*)d_out, 0.f, (size_t)out_size);
        return;
    }
    bfr*   f_K2b = (bfr*)d_ws;
    bfr*   f_V2b = f_K2b + (size_t)BT * D_;
    float* f_tgt = (float*)(f_V2b + (size_t)BT * D_);
    bfr*   tgt_hi = (bfr*)(f_tgt + (size_t)BL * D_);
    bfr*   tgt_lo = tgt_hi + (size_t)BL * D_;
    float* f_cos = (float*)(tgt_lo + (size_t)BL * D_);
    float* f_sin = f_cos + (size_t)L_ * 32;
    int*   f_pad = (int*)(f_sin + (size_t)L_ * 32);
    bfr*   ow_hi = (bfr*)(f_pad + BT);
    bfr*   ow_lo = ow_hi + (size_t)V_ * D_;

    bfr* wp = (bfr*)d_out;
    bfr* qkvw_hi = wp;  wp += 3 * D2;
    bfr* qkvw_lo = wp;  wp += 3 * D2;
    bfr* inp_hi  = wp;  wp += D2;
    bfr* inp_lo  = wp;  wp += D2;
    bfr* mha_hi  = wp;  wp += 3 * D2;
    bfr* mha_lo  = wp;  wp += 3 * D2;
    bfr* o_hi    = wp;  wp += D2;
    bfr* o_lo    = wp;  wp += D2;
    bfr* mo_hi   = wp;  wp += D2;
    bfr* mo_lo   = wp;  wp += D2;
    bfr* w1_hi   = wp;  wp += DFF_ * D_;
    bfr* w1_lo   = wp;  wp += DFF_ * D_;
    bfr* w2_hi   = wp;  wp += D_ * DFF_;
    bfr* w2_lo   = wp;  wp += D_ * DFF_;
    float* f_qkvb = (float*)wp;                 // [1536]
    float* lr    = f_qkvb + 3 * D_;
    float* f_t2  = lr;
    bfr*   qkv   = (bfr*)(f_t2 + (size_t)BL * D_);
    bfr*   qcr   = qkv + (size_t)BL * 3 * D_;
    bfr*   t1_hi = qcr + (size_t)BL * D_;
    bfr*   t1_lo = t1_hi + (size_t)BL * D_;
    bfr*   ffh_hi = t1_lo + (size_t)BL * D_;
    bfr*   ffh_lo = ffh_hi + (size_t)BL * DFF_;
    float* f_mem = lr;  // prologue-only alias

    // single batched weight split
    {
        SplitTable tab{};
        int blk = 0, ne = 0;
        auto add = [&](const float* s, bfr* h, bfr* l, int n) {
            tab.e[ne] = {s, h, l, n, blk};
            blk += (n + 255) >> 8;
            ++ne;
        };
        add(qw, qkvw_hi, qkvw_lo, D2);
        add(kw, qkvw_hi + D2, qkvw_lo + D2, D2);
        add(vw, qkvw_hi + 2 * D2, qkvw_lo + 2 * D2, D2);
        add(inp_w, inp_hi, inp_lo, D2);
        add(mha_w, mha_hi, mha_lo, 3 * D2);
        add(ow, o_hi, o_lo, D2);
        add(mha_ow, mo_hi, mo_lo, D2);
        add(w1, w1_hi, w1_lo, DFF_ * D_);
        add(w2, w2_hi, w2_lo, D_ * DFF_);
        add(out_w, ow_hi, ow_lo, V_ * D_);
        tab.ne = ne;
        split_many_kernel<<<blk, 256, 0, stream>>>(tab);
    }
    copyf_kernel<<<2, 256, 0, stream>>>(qb, f_qkvb, D_);
    copyf_kernel<<<2, 256, 0, stream>>>(kb, f_qkvb + D_, D_);
    copyf_kernel<<<2, 256, 0, stream>>>(vb, f_qkvb + 2 * D_, D_);

    rope_tables_kernel<<<(L_ * 32 + 255) / 256, 256, 0, stream>>>(f_cos, f_sin);
    embed_kernel<<<(BL * D_ + 255) / 256, 256, 0, stream>>>(tg, emb, f_tgt, tgt_hi, tgt_lo);

    // prologue: memory exact (3-term), K2/V2 bf16-out (2-term)
    gemm_split<0, 3><<<dim3(D_ / 64, BT / 128), 256, 0, stream>>>(enc, inp_hi, inp_lo, inp_b, f_mem, nullptr, BT, D_, INC_);
    pad_kernel<<<(BT + 255) / 256, 256, 0, stream>>>(f_mem, f_pad);
    gemm_split<1, 2><<<dim3(D_ / 64, BT / 128), 256, 0, stream>>>(f_mem, mha_hi + (size_t)D2, mha_lo + (size_t)D2, mha_b + D_, nullptr, f_K2b, BT, D_, D_);
    gemm_split<1, 2><<<dim3(D_ / 64, BT / 128), 256, 0, stream>>>(f_mem, mha_hi + (size_t)2 * D2, mha_lo + (size_t)2 * D2, mha_b + 2 * D_, nullptr, f_V2b, BT, D_, D_);

    for (int layer = 0; layer < NL_; ++layer) {
        // self attention: fused QKV (bf16 out, 2-term); rope inside attn
        gemm_ps<0, 1, 64, 2><<<(BL / 64) * (3 * D_ / 64), 256, 0, stream>>>(tgt_hi, nullptr, qkvw_hi, qkvw_lo, f_qkvb, nullptr, qkv, nullptr, BL, 3 * D_, D_);
        attn_kernel<L_, 1><<<B_ * H_ * 2, 256, 0, stream>>>(qkv, 3 * D_, qkv + D_, qkv + 2 * D_, 3 * D_, nullptr, f_cos, f_sin, t1_hi, t1_lo);
        gemm_ps<0, 0, 64, 3><<<(BL / 64) * (D_ / 64), 256, 0, stream>>>(t1_hi, t1_lo, o_hi, o_lo, ob, f_t2, nullptr, nullptr, BL, D_, D_);
        ln_residual_kernel<<<BL, 128, 0, stream>>>(f_tgt, f_t2, ln1g, ln1b, tgt_hi, tgt_lo);
        // cross attention (Q bf16 out, 2-term)
        gemm_ps<0, 1, 64, 2><<<(BL / 64) * (D_ / 64), 256, 0, stream>>>(tgt_hi, nullptr, mha_hi, mha_lo, mha_b, nullptr, qcr, nullptr, BL, D_, D_);
        attn_kernel<T_, 0><<<B_ * H_ * 2, 256, 0, stream>>>(qcr, D_, f_K2b, f_V2b, D_, f_pad, nullptr, nullptr, t1_hi, t1_lo);
        gemm_ps<0, 0, 64, 3><<<(BL / 64) * (D_ / 64), 256, 0, stream>>>(t1_hi, t1_lo, mo_hi, mo_lo, mha_ob, f_t2, nullptr, nullptr, BL, D_, D_);
        ln_residual_kernel<<<BL, 128, 0, stream>>>(f_tgt, f_t2, ln2g, ln2b, tgt_hi, tgt_lo);
        // FFN (residual path: 3-term)
        gemm_ps<1, 2, 64, 3><<<(BL / 64) * (DFF_ / 64), 256, 0, stream>>>(tgt_hi, tgt_lo, w1_hi, w1_lo, b1, nullptr, ffh_hi, ffh_lo, BL, DFF_, D_);
        gemm_ps<0, 0, 64, 3><<<(BL / 64) * (D_ / 64), 256, 0, stream>>>(ffh_hi, ffh_lo, w2_hi, w2_lo, b2, f_t2, nullptr, nullptr, BL, D_, DFF_);
        ln_residual_kernel<<<BL, 128, 0, stream>>>(f_tgt, f_t2, ln3g, ln3b, tgt_hi, tgt_lo);
    }

    // all d_out scratch dead; outputs f32 (logits: 2-term, final output)
    float* o_logits = (float*)d_out;
    float* o_tgt = o_logits + N_LOGITS;
    gemm_ps<0, 0, 128, 2><<<(BL / 128) * (V_ / 64), 256, 0, stream>>>(tgt_hi, nullptr, ow_hi, ow_lo, out_b, o_logits, nullptr, nullptr, BL, V_, D_);
    copyf_kernel<<<(BL * D_ + 255) / 256, 256, 0, stream>>>(f_tgt, o_tgt, BL * D_);
}

// Round 13
// 1259.484 us; speedup vs baseline: 6.8507x; 1.1006x over previous
//
#include <hip/hip_runtime.h>
#include <hip/hip_bf16.h>

#define B_ 32
#define T_ 512
#define L_ 128
#define INC_ 512
#define D_ 512
#define H_ 8
#define HD_ 64
#define NL_ 6
#define DFF_ 1024
#define V_ 8000
#define LDSK 40  // gemm LDS row stride (bf16)
#define AST 72   // attn LDS row stride (bf16)

typedef __bf16 bfr;
typedef __attribute__((ext_vector_type(8))) __bf16 bf16x8;
typedef __attribute__((ext_vector_type(4))) __bf16 bf16x4;
typedef __attribute__((ext_vector_type(4))) float f32x4;

// ---- batched f32 -> (hi,lo) bf16 plane split (weights only) ----
struct SplitDesc { const float* src; bfr* hi; bfr* lo; int n; int blk0; };
struct SplitTable { SplitDesc e[12]; int ne; };

__global__ void split_many_kernel(SplitTable tab)
{
    int b = blockIdx.x;
    for (int i = 0; i < tab.ne; ++i) {
        const SplitDesc d = tab.e[i];
        int nb = (d.n + 255) >> 8;
        if (b >= d.blk0 && b < d.blk0 + nb) {
            int g = (b - d.blk0) * 256 + threadIdx.x;
            if (g < d.n) {
                float x = d.src[g];
                bfr h = (bfr)x;
                d.hi[g] = h;
                d.lo[g] = (bfr)(x - (float)h);
            }
            return;
        }
    }
}

// bijective XCD-chunk remap (m204) + GROUP_M tile raster -> (pm, pn)
__device__ __forceinline__ void tile_map(int bid, int nbm, int nbn, int& pm, int& pn)
{
    int nwg = nbm * nbn;
    int q = nwg >> 3, r = nwg & 7;
    int xcd = bid & 7, idx = bid >> 3;
    int wgid = (xcd < r ? xcd * (q + 1) : r * (q + 1) + (xcd - r) * q) + idx;
    const int GROUP = 8;
    int per_group = GROUP * nbn;
    int gid = wgid / per_group;
    int first = gid * GROUP;
    int gsz = min(nbm - first, GROUP);
    int rem = wgid - gid * per_group;
    pm = first + rem % gsz;
    pn = rem / gsz;
}

// ---- GEMM, A = f32 (converted to bf16 in-kernel). Prologue only.
// 2-term: Ah*Wh + Ah*Wl. OUT: 0=f32, 1=bf16
template <int OUT>
__global__ __launch_bounds__(256) void gemm_split(
    const float* __restrict__ A, const bfr* __restrict__ Whi, const bfr* __restrict__ Wlo,
    const float* __restrict__ bias, float* __restrict__ Cf, bfr* __restrict__ Cb,
    int M, int N, int K)
{
    __shared__ bfr Ah_s[128 * LDSK];
    __shared__ bfr Wh_s[64 * LDSK];
    __shared__ bfr Wl_s[64 * LDSK];
    const int t = threadIdx.x;
    const int bm = blockIdx.y * 128, bn = blockIdx.x * 64;
    const int w = t >> 6, lane = t & 63;
    const int wm = w >> 1, wn = w & 1;
    const int fr = lane & 15, kq = lane >> 4;
    const int ar = t >> 1, ah = (t & 1) * 16;
    const int wr = t >> 2, wk = (t & 3) * 8;

    f32x4 acc[4][2] = {};

    for (int k0 = 0; k0 < K; k0 += 32) {
        {
            const float* ap = A + (size_t)(bm + ar) * K + (k0 + ah);
            float4 v0 = ((const float4*)ap)[0];
            float4 v1 = ((const float4*)ap)[1];
            float4 v2 = ((const float4*)ap)[2];
            float4 v3 = ((const float4*)ap)[3];
            float xs[16] = {v0.x, v0.y, v0.z, v0.w, v1.x, v1.y, v1.z, v1.w,
                            v2.x, v2.y, v2.z, v2.w, v3.x, v3.y, v3.z, v3.w};
            bf16x8 h0, h1;
#pragma unroll
            for (int i = 0; i < 8; ++i) h0[i] = (bfr)xs[i];
#pragma unroll
            for (int i = 0; i < 8; ++i) h1[i] = (bfr)xs[8 + i];
            *(bf16x8*)(Ah_s + ar * LDSK + ah) = h0;
            *(bf16x8*)(Ah_s + ar * LDSK + ah + 8) = h1;
        }
        {
            *(bf16x8*)(Wh_s + wr * LDSK + wk) = *(const bf16x8*)(Whi + (size_t)(bn + wr) * K + (k0 + wk));
            *(bf16x8*)(Wl_s + wr * LDSK + wk) = *(const bf16x8*)(Wlo + (size_t)(bn + wr) * K + (k0 + wk));
        }
        __syncthreads();
        bf16x8 Afh[4], Wfh[2], Wfl[2];
#pragma unroll
        for (int i = 0; i < 4; ++i)
            Afh[i] = *(const bf16x8*)(Ah_s + (wm * 64 + i * 16 + fr) * LDSK + kq * 8);
#pragma unroll
        for (int j = 0; j < 2; ++j) {
            int r = wn * 32 + j * 16 + fr;
            Wfh[j] = *(const bf16x8*)(Wh_s + r * LDSK + kq * 8);
            Wfl[j] = *(const bf16x8*)(Wl_s + r * LDSK + kq * 8);
        }
#pragma unroll
        for (int i = 0; i < 4; ++i)
#pragma unroll
            for (int j = 0; j < 2; ++j) {
                acc[i][j] = __builtin_amdgcn_mfma_f32_16x16x32_bf16(Afh[i], Wfh[j], acc[i][j], 0, 0, 0);
                acc[i][j] = __builtin_amdgcn_mfma_f32_16x16x32_bf16(Afh[i], Wfl[j], acc[i][j], 0, 0, 0);
            }
        __syncthreads();
    }
#pragma unroll
    for (int i = 0; i < 4; ++i) {
        int row0 = bm + wm * 64 + i * 16 + (lane >> 4) * 4;
#pragma unroll
        for (int j = 0; j < 2; ++j) {
            int col = bn + wn * 32 + j * 16 + fr;
            float bj = bias[col];
#pragma unroll
            for (int r = 0; r < 4; ++r) {
                float v = acc[i][j][r] + bj;
                if (OUT == 0) Cf[(size_t)(row0 + r) * N + col] = v;
                else Cb[(size_t)(row0 + r) * N + col] = (bfr)v;
            }
        }
    }
}

// ---- GEMM, A bf16. 2-term (Ah*Wh + Ah*Wl). BM in {64,128}; 1D grid + swizzle ----
// OUT: 0=f32, 1=bf16
template <int ACT, int OUT, int BM>
__global__ __launch_bounds__(256, 2) void gemm_ps(
    const bfr* __restrict__ Ahi,
    const bfr* __restrict__ Whi, const bfr* __restrict__ Wlo,
    const float* __restrict__ bias, float* __restrict__ Cf,
    bfr* __restrict__ Chi, int M, int N, int K)
{
    constexpr int MF = BM / 32;
    __shared__ bfr Ah_s[BM * LDSK];
    __shared__ bfr Wh_s[64 * LDSK];
    __shared__ bfr Wl_s[64 * LDSK];
    const int t = threadIdx.x;
    int pm, pn;
    tile_map(blockIdx.x, M / BM, N / 64, pm, pn);
    const int bm = pm * BM, bn = pn * 64;
    const int w = t >> 6, lane = t & 63;
    const int wm = w >> 1, wn = w & 1;
    const int fr = lane & 15, kq = lane >> 4;
    const int wr = t >> 2, wk = (t & 3) * 8;

    f32x4 acc[MF][2] = {};

    for (int k0 = 0; k0 < K; k0 += 32) {
        if constexpr (BM == 128) {
            const int ar = t >> 1, ah = (t & 1) * 16;
            const bfr* ap = Ahi + (size_t)(bm + ar) * K + (k0 + ah);
            *(bf16x8*)(Ah_s + ar * LDSK + ah) = *(const bf16x8*)ap;
            *(bf16x8*)(Ah_s + ar * LDSK + ah + 8) = *(const bf16x8*)(ap + 8);
        } else {
            const int ar = t >> 2, ah = (t & 3) * 8;
            *(bf16x8*)(Ah_s + ar * LDSK + ah) = *(const bf16x8*)(Ahi + (size_t)(bm + ar) * K + (k0 + ah));
        }
        {
            *(bf16x8*)(Wh_s + wr * LDSK + wk) = *(const bf16x8*)(Whi + (size_t)(bn + wr) * K + (k0 + wk));
            *(bf16x8*)(Wl_s + wr * LDSK + wk) = *(const bf16x8*)(Wlo + (size_t)(bn + wr) * K + (k0 + wk));
        }
        __syncthreads();
        bf16x8 Afh[MF], Wfh[2], Wfl[2];
#pragma unroll
        for (int i = 0; i < MF; ++i)
            Afh[i] = *(const bf16x8*)(Ah_s + (wm * (BM / 2) + i * 16 + fr) * LDSK + kq * 8);
#pragma unroll
        for (int j = 0; j < 2; ++j) {
            int r = wn * 32 + j * 16 + fr;
            Wfh[j] = *(const bf16x8*)(Wh_s + r * LDSK + kq * 8);
            Wfl[j] = *(const bf16x8*)(Wl_s + r * LDSK + kq * 8);
        }
#pragma unroll
        for (int i = 0; i < MF; ++i)
#pragma unroll
            for (int j = 0; j < 2; ++j) {
                acc[i][j] = __builtin_amdgcn_mfma_f32_16x16x32_bf16(Afh[i], Wfh[j], acc[i][j], 0, 0, 0);
                acc[i][j] = __builtin_amdgcn_mfma_f32_16x16x32_bf16(Afh[i], Wfl[j], acc[i][j], 0, 0, 0);
            }
        __syncthreads();
    }
#pragma unroll
    for (int i = 0; i < MF; ++i) {
        int row0 = bm + wm * (BM / 2) + i * 16 + (lane >> 4) * 4;
#pragma unroll
        for (int j = 0; j < 2; ++j) {
            int col = bn + wn * 32 + j * 16 + fr;
            float bj = bias[col];
#pragma unroll
            for (int r = 0; r < 4; ++r) {
                float v = acc[i][j][r] + bj;
                if (ACT == 1) v = 0.5f * v * (1.0f + erff(v * 0.70710678118654752f));
                size_t idx = (size_t)(row0 + r) * N + col;
                if (OUT == 0) Cf[idx] = v;
                else Chi[idx] = (bfr)v;
            }
        }
    }
}

// ---- fused flash attention, bf16 inputs; RoPE folded in when CAUSAL ----
template <int TK, int CAUSAL>
__global__ __launch_bounds__(256) void attn_kernel(
    const bfr* __restrict__ Qg, int qstr,
    const bfr* __restrict__ Kg, const bfr* __restrict__ Vg, int kvstr,
    const int* __restrict__ pad,
    const float* __restrict__ cosT, const float* __restrict__ sinT,
    bfr* __restrict__ Ohi)
{
    __shared__ bfr Qs[64 * AST];
    __shared__ bfr Ks[64 * AST];
    __shared__ bfr VTs[64 * AST];
    __shared__ bfr Ps[64 * AST];
    const int bidx = blockIdx.x;
    const int qt = bidx & 1, bh = bidx >> 1;
    const int h = bh & 7, b = bh >> 3;
    const int t = threadIdx.x;
    const int w = t >> 6, lane = t & 63;
    const int l4 = lane & 15, hi4 = lane >> 4;
    const int q0 = qt * 64;
    const int srow = t >> 2, ht = t & 3;

    if (CAUSAL) {
        int qrow = q0 + srow;
        const bfr* qp = Qg + (size_t)(b * L_ + qrow) * qstr + h * HD_ + ht * 8;
        bf16x8 a = *(const bf16x8*)qp;
        bf16x8 bb = *(const bf16x8*)(qp + 32);
        bf16x8 o1, o2;
#pragma unroll
        for (int j = 0; j < 8; ++j) {
            float c = cosT[qrow * 32 + ht * 8 + j], s = sinT[qrow * 32 + ht * 8 + j];
            float x1 = (float)a[j], x2 = (float)bb[j];
            o1[j] = (bfr)(x1 * c - x2 * s);
            o2[j] = (bfr)(x2 * c + x1 * s);
        }
        *(bf16x8*)(Qs + srow * AST + ht * 8) = o1;
        *(bf16x8*)(Qs + srow * AST + ht * 8 + 32) = o2;
    } else {
        const bfr* qp = Qg + (size_t)(b * L_ + q0 + srow) * qstr + h * HD_ + ht * 16;
        *(bf16x8*)(Qs + srow * AST + ht * 16) = *(const bf16x8*)qp;
        *(bf16x8*)(Qs + srow * AST + ht * 16 + 8) = *(const bf16x8*)(qp + 8);
    }

    f32x4 o_acc[4] = {};
    float m_run[4], l_run[4];
#pragma unroll
    for (int r = 0; r < 4; ++r) { m_run[r] = -1e30f; l_run[r] = 0.f; }

    const int NT = CAUSAL ? (qt + 1) : (TK / 64);
    for (int kt = 0; kt < NT; ++kt) {
        __syncthreads();
        if (CAUSAL) {
            int krow = kt * 64 + srow;
            const bfr* kp = Kg + (size_t)(b * TK + krow) * kvstr + h * HD_ + ht * 8;
            bf16x8 a = *(const bf16x8*)kp;
            bf16x8 bb = *(const bf16x8*)(kp + 32);
            bf16x8 o1, o2;
#pragma unroll
            for (int j = 0; j < 8; ++j) {
                float c = cosT[krow * 32 + ht * 8 + j], s = sinT[krow * 32 + ht * 8 + j];
                float x1 = (float)a[j], x2 = (float)bb[j];
                o1[j] = (bfr)(x1 * c - x2 * s);
                o2[j] = (bfr)(x2 * c + x1 * s);
            }
            *(bf16x8*)(Ks + srow * AST + ht * 8) = o1;
            *(bf16x8*)(Ks + srow * AST + ht * 8 + 32) = o2;
        } else {
            const bfr* kp = Kg + (size_t)(b * TK + kt * 64 + srow) * kvstr + h * HD_ + ht * 16;
            *(bf16x8*)(Ks + srow * AST + ht * 16) = *(const bf16x8*)kp;
            *(bf16x8*)(Ks + srow * AST + ht * 16 + 8) = *(const bf16x8*)(kp + 8);
        }
        {
            const bfr* vp = Vg + (size_t)(b * TK + kt * 64 + srow) * kvstr + h * HD_ + ht * 16;
            bf16x8 v0 = *(const bf16x8*)vp;
            bf16x8 v1 = *(const bf16x8*)(vp + 8);
#pragma unroll
            for (int i = 0; i < 8; ++i) VTs[(ht * 16 + i) * AST + srow] = v0[i];
#pragma unroll
            for (int i = 0; i < 8; ++i) VTs[(ht * 16 + 8 + i) * AST + srow] = v1[i];
        }
        __syncthreads();

        f32x4 s[4] = {};
#pragma unroll
        for (int kk = 0; kk < 64; kk += 32) {
            bf16x8 a = *(const bf16x8*)(Qs + (w * 16 + l4) * AST + kk + hi4 * 8);
#pragma unroll
            for (int n = 0; n < 4; ++n) {
                bf16x8 bb = *(const bf16x8*)(Ks + (n * 16 + l4) * AST + kk + hi4 * 8);
                s[n] = __builtin_amdgcn_mfma_f32_16x16x32_bf16(a, bb, s[n], 0, 0, 0);
            }
        }
        float madd[4];
        if (!CAUSAL) {
#pragma unroll
            for (int n = 0; n < 4; ++n)
                madd[n] = pad[b * TK + kt * 64 + n * 16 + l4] ? -1e30f : 0.f;
        }
#pragma unroll
        for (int r = 0; r < 4; ++r) {
            int qrow = q0 + w * 16 + hi4 * 4 + r;
            float sv[4];
#pragma unroll
            for (int n = 0; n < 4; ++n) {
                float x = s[n][r] * 0.125f;
                if (CAUSAL) {
                    int col = kt * 64 + n * 16 + l4;
                    if (col > qrow) x = -1e30f;
                } else x += madd[n];
                sv[n] = x;
            }
            float mx = fmaxf(fmaxf(sv[0], sv[1]), fmaxf(sv[2], sv[3]));
#pragma unroll
            for (int off = 1; off < 16; off <<= 1) mx = fmaxf(mx, __shfl_xor(mx, off));
            float mnew = fmaxf(m_run[r], mx);
            float alpha = expf(m_run[r] - mnew);
            float pv[4], psum = 0.f;
#pragma unroll
            for (int n = 0; n < 4; ++n) { pv[n] = expf(sv[n] - mnew); psum += pv[n]; }
#pragma unroll
            for (int off = 1; off < 16; off <<= 1) psum += __shfl_xor(psum, off);
            l_run[r] = l_run[r] * alpha + psum;
            m_run[r] = mnew;
#pragma unroll
            for (int n = 0; n < 4; ++n) o_acc[n][r] *= alpha;
#pragma unroll
            for (int n = 0; n < 4; ++n)
                Ps[(w * 16 + hi4 * 4 + r) * AST + n * 16 + l4] = (bfr)pv[n];
        }
#pragma unroll
        for (int kk = 0; kk < 64; kk += 32) {
            bf16x8 pa = *(const bf16x8*)(Ps + (w * 16 + l4) * AST + kk + hi4 * 8);
#pragma unroll
            for (int n = 0; n < 4; ++n) {
                bf16x8 vb = *(const bf16x8*)(VTs + (n * 16 + l4) * AST + kk + hi4 * 8);
                o_acc[n] = __builtin_amdgcn_mfma_f32_16x16x32_bf16(pa, vb, o_acc[n], 0, 0, 0);
            }
        }
    }
#pragma unroll
    for (int r = 0; r < 4; ++r) {
        float inv = 1.0f / l_run[r];
        int qrow = q0 + w * 16 + hi4 * 4 + r;
#pragma unroll
        for (int n = 0; n < 4; ++n)
            Ohi[(size_t)(b * L_ + qrow) * D_ + h * HD_ + n * 16 + l4] = (bfr)(o_acc[n][r] * inv);
    }
}

__global__ void rope_tables_kernel(float* __restrict__ cosT, float* __restrict__ sinT)
{
    int gid = blockIdx.x * blockDim.x + threadIdx.x;
    if (gid >= L_ * 32) return;
    int l = gid >> 5, i = gid & 31;
    float inv = powf(10000.0f, -(float)(2 * i) / (float)HD_);
    float ang = (float)l * inv;
    cosT[gid] = cosf(ang);
    sinT[gid] = sinf(ang);
}

__global__ void embed_kernel(const int* __restrict__ targets, const float* __restrict__ emb,
                             float* __restrict__ tgt, bfr* __restrict__ thi)
{
    int gid = blockIdx.x * blockDim.x + threadIdx.x;
    if (gid >= B_ * L_ * D_) return;
    int d = gid & (D_ - 1);
    int r = gid >> 9;
    int tok = targets[r];
    float x = emb[(size_t)tok * D_ + d] * 22.62741699796952f;
    tgt[gid] = x;
    thi[gid] = (bfr)x;
}

__global__ void pad_kernel(const float* __restrict__ mem, int* __restrict__ pad)
{
    int gid = blockIdx.x * blockDim.x + threadIdx.x;
    if (gid >= B_ * T_) return;
    const float* p = mem + (size_t)gid * D_;
    float s = 0.f;
    for (int d = 0; d < D_; ++d) s += fabsf(p[d]);
    pad[gid] = (s == 0.0f) ? 1 : 0;
}

// tgt = LN(tgt + delta); writes f32 + bf16 image, float4 I/O
__global__ __launch_bounds__(128) void ln_residual_kernel(
    float* __restrict__ tgt, const float* __restrict__ delta,
    const float* __restrict__ g, const float* __restrict__ bb,
    bfr* __restrict__ thi)
{
    const int row = blockIdx.x;
    const int t = threadIdx.x;
    __shared__ float rbuf[128];
    size_t base = (size_t)row * D_ + t * 4;
    float4 x = *(float4*)(tgt + base);
    float4 dl = *(const float4*)(delta + base);
    x.x += dl.x; x.y += dl.y; x.z += dl.z; x.w += dl.w;
    rbuf[t] = x.x + x.y + x.z + x.w;
    __syncthreads();
    for (int off = 64; off > 0; off >>= 1) { if (t < off) rbuf[t] += rbuf[t + off]; __syncthreads(); }
    float mean = rbuf[0] * (1.0f / D_);
    __syncthreads();
    float4 d4 = {x.x - mean, x.y - mean, x.z - mean, x.w - mean};
    rbuf[t] = d4.x * d4.x + d4.y * d4.y + d4.z * d4.z + d4.w * d4.w;
    __syncthreads();
    for (int off = 64; off > 0; off >>= 1) { if (t < off) rbuf[t] += rbuf[t + off]; __syncthreads(); }
    float inv = 1.0f / sqrtf(rbuf[0] * (1.0f / D_) + 1e-5f);
    float4 g4 = *(const float4*)(g + t * 4);
    float4 b4 = *(const float4*)(bb + t * 4);
    float4 y = {d4.x * inv * g4.x + b4.x, d4.y * inv * g4.y + b4.y,
                d4.z * inv * g4.z + b4.z, d4.w * inv * g4.w + b4.w};
    *(float4*)(tgt + base) = y;
    bf16x4 h4 = {(bfr)y.x, (bfr)y.y, (bfr)y.z, (bfr)y.w};
    *(bf16x4*)(thi + base) = h4;
}

__global__ void copyf_kernel(const float* __restrict__ in, float* __restrict__ out, int n)
{
    int gid = blockIdx.x * blockDim.x + threadIdx.x;
    if (gid < n) out[gid] = in[gid];
}

__global__ void fillf_kernel(float* p, float v, size_t n)
{
    size_t gid = (size_t)blockIdx.x * 256 + threadIdx.x;
    if (gid < n) p[gid] = v;
}

extern "C" void kernel_launch(void* const* d_in, const int* in_sizes, int n_in,
                              void* d_out, int out_size, void* d_ws, size_t ws_size,
                              hipStream_t stream)
{
    const float* enc    = (const float*)d_in[0];
    const int*   tg     = (const int*)d_in[1];
    const float* emb    = (const float*)d_in[2];
    const float* inp_w  = (const float*)d_in[3];
    const float* inp_b  = (const float*)d_in[4];
    const float* out_w  = (const float*)d_in[5];
    const float* out_b  = (const float*)d_in[6];
    const float* qw     = (const float*)d_in[7];
    const float* qb     = (const float*)d_in[8];
    const float* kw     = (const float*)d_in[9];
    const float* kb     = (const float*)d_in[10];
    const float* vw     = (const float*)d_in[11];
    const float* vb     = (const float*)d_in[12];
    const float* ow     = (const float*)d_in[13];
    const float* ob     = (const float*)d_in[14];
    const float* mha_w  = (const float*)d_in[15];
    const float* mha_b  = (const float*)d_in[16];
    const float* mha_ow = (const float*)d_in[17];
    const float* mha_ob = (const float*)d_in[18];
    const float* w1     = (const float*)d_in[19];
    const float* b1     = (const float*)d_in[20];
    const float* w2     = (const float*)d_in[21];
    const float* b2     = (const float*)d_in[22];
    const float* ln1g   = (const float*)d_in[23];
    const float* ln1b   = (const float*)d_in[24];
    const float* ln2g   = (const float*)d_in[25];
    const float* ln2b   = (const float*)d_in[26];
    const float* ln3g   = (const float*)d_in[27];
    const float* ln3b   = (const float*)d_in[28];

    const int BL = B_ * L_;        // 4096
    const int BT = B_ * T_;        // 16384
    const size_t N_LOGITS = (size_t)BL * V_;
    const int D2 = D_ * D_;        // 262144

    const size_t WS_NEEDED =
        (size_t)BT * 1024 * sizeof(bfr)                 // fused K2|V2
        + (size_t)BL * D_ * sizeof(float)               // tgt f32
        + (size_t)BL * D_ * sizeof(bfr)                 // tgt_hi
        + (size_t)2 * L_ * 32 * sizeof(float) + (size_t)BT * sizeof(int)
        + (size_t)2 * V_ * D_ * sizeof(bfr);            // out_w planes
    if (ws_size < WS_NEEDED) {
        fillf_kernel<<<((size_t)out_size + 255) / 256, 256, 0, stream>>>((float*)d_out, 0.f, (size_t)out_size);
        return;
    }
    bfr*   f_KVb = (bfr*)d_ws;                          // [BT,1024]: K2 cols 0..511, V2 512..1023
    float* f_tgt = (float*)(f_KVb + (size_t)BT * 1024);
    bfr*   tgt_hi = (bfr*)(f_tgt + (size_t)BL * D_);
    float* f_cos = (float*)(tgt_hi + (size_t)BL * D_);
    float* f_sin = f_cos + (size_t)L_ * 32;
    int*   f_pad = (int*)(f_sin + (size_t)L_ * 32);
    bfr*   ow_hi = (bfr*)(f_pad + BT);
    bfr*   ow_lo = ow_hi + (size_t)V_ * D_;

    bfr* wp = (bfr*)d_out;
    bfr* qkvw_hi = wp;  wp += 3 * D2;
    bfr* qkvw_lo = wp;  wp += 3 * D2;
    bfr* inp_hi  = wp;  wp += D2;
    bfr* inp_lo  = wp;  wp += D2;
    bfr* mha_hi  = wp;  wp += 3 * D2;
    bfr* mha_lo  = wp;  wp += 3 * D2;
    bfr* o_hi    = wp;  wp += D2;
    bfr* o_lo    = wp;  wp += D2;
    bfr* mo_hi   = wp;  wp += D2;
    bfr* mo_lo   = wp;  wp += D2;
    bfr* w1_hi   = wp;  wp += DFF_ * D_;
    bfr* w1_lo   = wp;  wp += DFF_ * D_;
    bfr* w2_hi   = wp;  wp += D_ * DFF_;
    bfr* w2_lo   = wp;  wp += D_ * DFF_;
    float* f_qkvb = (float*)wp;                 // [1536]
    float* lr    = f_qkvb + 3 * D_;
    float* f_t2  = lr;                                   // [BL,512] f32
    bfr*   qkv   = (bfr*)(f_t2 + (size_t)BL * D_);       // [BL,1536]
    bfr*   qcr   = qkv + (size_t)BL * 3 * D_;            // [BL,512]
    bfr*   t1_hi = qcr + (size_t)BL * D_;                // [BL,512]
    bfr*   ffh_hi = t1_hi + (size_t)BL * D_;             // [BL,1024]
    float* f_mem = lr;  // prologue-only alias (BT*D f32 = 33.5MB <= layer region)

    // single batched weight split
    {
        SplitTable tab{};
        int blk = 0, ne = 0;
        auto add = [&](const float* s, bfr* h, bfr* l, int n) {
            tab.e[ne] = {s, h, l, n, blk};
            blk += (n + 255) >> 8;
            ++ne;
        };
        add(qw, qkvw_hi, qkvw_lo, D2);
        add(kw, qkvw_hi + D2, qkvw_lo + D2, D2);
        add(vw, qkvw_hi + 2 * D2, qkvw_lo + 2 * D2, D2);
        add(inp_w, inp_hi, inp_lo, D2);
        add(mha_w, mha_hi, mha_lo, 3 * D2);
        add(ow, o_hi, o_lo, D2);
        add(mha_ow, mo_hi, mo_lo, D2);
        add(w1, w1_hi, w1_lo, DFF_ * D_);
        add(w2, w2_hi, w2_lo, D_ * DFF_);
        add(out_w, ow_hi, ow_lo, V_ * D_);
        tab.ne = ne;
        split_many_kernel<<<blk, 256, 0, stream>>>(tab);
    }
    copyf_kernel<<<2, 256, 0, stream>>>(qb, f_qkvb, D_);
    copyf_kernel<<<2, 256, 0, stream>>>(kb, f_qkvb + D_, D_);
    copyf_kernel<<<2, 256, 0, stream>>>(vb, f_qkvb + 2 * D_, D_);

    rope_tables_kernel<<<(L_ * 32 + 255) / 256, 256, 0, stream>>>(f_cos, f_sin);
    embed_kernel<<<(BL * D_ + 255) / 256, 256, 0, stream>>>(tg, emb, f_tgt, tgt_hi);

    // prologue: memory f32, pad mask, fused K2|V2 (bf16, N=1024; mha_w rows [D,3D) contiguous)
    gemm_split<0><<<dim3(D_ / 64, BT / 128), 256, 0, stream>>>(enc, inp_hi, inp_lo, inp_b, f_mem, nullptr, BT, D_, INC_);
    pad_kernel<<<(BT + 255) / 256, 256, 0, stream>>>(f_mem, f_pad);
    gemm_split<1><<<dim3(1024 / 64, BT / 128), 256, 0, stream>>>(f_mem, mha_hi + (size_t)D2, mha_lo + (size_t)D2, mha_b + D_, nullptr, f_KVb, BT, 1024, D_);

    for (int layer = 0; layer < NL_; ++layer) {
        // self attention: fused QKV -> bf16 [BL,1536]; rope inside attn
        gemm_ps<0, 1, 64><<<(BL / 64) * (3 * D_ / 64), 256, 0, stream>>>(tgt_hi, qkvw_hi, qkvw_lo, f_qkvb, nullptr, qkv, BL, 3 * D_, D_);
        attn_kernel<L_, 1><<<B_ * H_ * 2, 256, 0, stream>>>(qkv, 3 * D_, qkv + D_, qkv + 2 * D_, 3 * D_, nullptr, f_cos, f_sin, t1_hi);
        gemm_ps<0, 0, 64><<<(BL / 64) * (D_ / 64), 256, 0, stream>>>(t1_hi, o_hi, o_lo, ob, f_t2, nullptr, BL, D_, D_);
        ln_residual_kernel<<<BL, 128, 0, stream>>>(f_tgt, f_t2, ln1g, ln1b, tgt_hi);
        // cross attention
        gemm_ps<0, 1, 64><<<(BL / 64) * (D_ / 64), 256, 0, stream>>>(tgt_hi, mha_hi, mha_lo, mha_b, nullptr, qcr, BL, D_, D_);
        attn_kernel<T_, 0><<<B_ * H_ * 2, 256, 0, stream>>>(qcr, D_, f_KVb, f_KVb + D_, 1024, f_pad, nullptr, nullptr, t1_hi);
        gemm_ps<0, 0, 64><<<(BL / 64) * (D_ / 64), 256, 0, stream>>>(t1_hi, mo_hi, mo_lo, mha_ob, f_t2, nullptr, BL, D_, D_);
        ln_residual_kernel<<<BL, 128, 0, stream>>>(f_tgt, f_t2, ln2g, ln2b, tgt_hi);
        // FFN
        gemm_ps<1, 1, 64><<<(BL / 64) * (DFF_ / 64), 256, 0, stream>>>(tgt_hi, w1_hi, w1_lo, b1, nullptr, ffh_hi, BL, DFF_, D_);
        gemm_ps<0, 0, 64><<<(BL / 64) * (D_ / 64), 256, 0, stream>>>(ffh_hi, w2_hi, w2_lo, b2, f_t2, nullptr, BL, D_, DFF_);
        ln_residual_kernel<<<BL, 128, 0, stream>>>(f_tgt, f_t2, ln3g, ln3b, tgt_hi);
    }

    // all d_out scratch dead; outputs f32
    float* o_logits = (float*)d_out;
    float* o_tgt = o_logits + N_LOGITS;
    gemm_ps<0, 0, 128><<<(BL / 128) * (V_ / 64), 256, 0, stream>>>(tgt_hi, ow_hi, ow_lo, out_b, o_logits, nullptr, BL, V_, D_);
    copyf_kernel<<<(BL * D_ + 255) / 256, 256, 0, stream>>>(f_tgt, o_tgt, BL * D_);
}

// Round 14
// 1106.752 us; speedup vs baseline: 7.7961x; 1.1380x over previous
//
#include <hip/hip_runtime.h>
#include <hip/hip_bf16.h>

#define B_ 32
#define T_ 512
#define L_ 128
#define INC_ 512
#define D_ 512
#define H_ 8
#define HD_ 64
#define NL_ 6
#define DFF_ 1024
#define V_ 8000
#define LDSK 40  // gemm LDS row stride (bf16)
#define AST 72   // attn LDS row stride (bf16)

typedef __bf16 bfr;
typedef __attribute__((ext_vector_type(8))) __bf16 bf16x8;
typedef __attribute__((ext_vector_type(4))) __bf16 bf16x4;
typedef __attribute__((ext_vector_type(4))) float f32x4;

// ---- batched f32 -> bf16 convert (weights) ----
struct ConvDesc { const float* src; bfr* dst; int n; int blk0; };
struct ConvTable { ConvDesc e[12]; int ne; };

__global__ void conv_many_kernel(ConvTable tab)
{
    int b = blockIdx.x;
    for (int i = 0; i < tab.ne; ++i) {
        const ConvDesc d = tab.e[i];
        int nb = (d.n + 255) >> 8;
        if (b >= d.blk0 && b < d.blk0 + nb) {
            int g = (b - d.blk0) * 256 + threadIdx.x;
            if (g < d.n) d.dst[g] = (bfr)d.src[g];
            return;
        }
    }
}

// bijective XCD-chunk remap (m204) + GROUP_M tile raster -> (pm, pn)
__device__ __forceinline__ void tile_map(int bid, int nbm, int nbn, int& pm, int& pn)
{
    int nwg = nbm * nbn;
    int q = nwg >> 3, r = nwg & 7;
    int xcd = bid & 7, idx = bid >> 3;
    int wgid = (xcd < r ? xcd * (q + 1) : r * (q + 1) + (xcd - r) * q) + idx;
    const int GROUP = 8;
    int per_group = GROUP * nbn;
    int gid = wgid / per_group;
    int first = gid * GROUP;
    int gsz = min(nbm - first, GROUP);
    int rem = wgid - gid * per_group;
    pm = first + rem % gsz;
    pn = rem / gsz;
}

// ---- GEMM, A = f32 (converted in-kernel), W bf16. Prologue only. OUT: 0=f32, 1=bf16 ----
template <int OUT>
__global__ __launch_bounds__(256) void gemm_split(
    const float* __restrict__ A, const bfr* __restrict__ Whi,
    const float* __restrict__ bias, float* __restrict__ Cf, bfr* __restrict__ Cb,
    int M, int N, int K)
{
    __shared__ bfr Ah_s[128 * LDSK];
    __shared__ bfr Wh_s[64 * LDSK];
    const int t = threadIdx.x;
    const int bm = blockIdx.y * 128, bn = blockIdx.x * 64;
    const int w = t >> 6, lane = t & 63;
    const int wm = w >> 1, wn = w & 1;
    const int fr = lane & 15, kq = lane >> 4;
    const int ar = t >> 1, ah = (t & 1) * 16;
    const int wr = t >> 2, wk = (t & 3) * 8;

    f32x4 acc[4][2] = {};

    for (int k0 = 0; k0 < K; k0 += 32) {
        {
            const float* ap = A + (size_t)(bm + ar) * K + (k0 + ah);
            float4 v0 = ((const float4*)ap)[0];
            float4 v1 = ((const float4*)ap)[1];
            float4 v2 = ((const float4*)ap)[2];
            float4 v3 = ((const float4*)ap)[3];
            float xs[16] = {v0.x, v0.y, v0.z, v0.w, v1.x, v1.y, v1.z, v1.w,
                            v2.x, v2.y, v2.z, v2.w, v3.x, v3.y, v3.z, v3.w};
            bf16x8 h0, h1;
#pragma unroll
            for (int i = 0; i < 8; ++i) h0[i] = (bfr)xs[i];
#pragma unroll
            for (int i = 0; i < 8; ++i) h1[i] = (bfr)xs[8 + i];
            *(bf16x8*)(Ah_s + ar * LDSK + ah) = h0;
            *(bf16x8*)(Ah_s + ar * LDSK + ah + 8) = h1;
        }
        *(bf16x8*)(Wh_s + wr * LDSK + wk) = *(const bf16x8*)(Whi + (size_t)(bn + wr) * K + (k0 + wk));
        __syncthreads();
        bf16x8 Afh[4], Wfh[2];
#pragma unroll
        for (int i = 0; i < 4; ++i)
            Afh[i] = *(const bf16x8*)(Ah_s + (wm * 64 + i * 16 + fr) * LDSK + kq * 8);
#pragma unroll
        for (int j = 0; j < 2; ++j)
            Wfh[j] = *(const bf16x8*)(Wh_s + (wn * 32 + j * 16 + fr) * LDSK + kq * 8);
#pragma unroll
        for (int i = 0; i < 4; ++i)
#pragma unroll
            for (int j = 0; j < 2; ++j)
                acc[i][j] = __builtin_amdgcn_mfma_f32_16x16x32_bf16(Afh[i], Wfh[j], acc[i][j], 0, 0, 0);
        __syncthreads();
    }
#pragma unroll
    for (int i = 0; i < 4; ++i) {
        int row0 = bm + wm * 64 + i * 16 + (lane >> 4) * 4;
#pragma unroll
        for (int j = 0; j < 2; ++j) {
            int col = bn + wn * 32 + j * 16 + fr;
            float bj = bias[col];
#pragma unroll
            for (int r = 0; r < 4; ++r) {
                float v = acc[i][j][r] + bj;
                if (OUT == 0) Cf[(size_t)(row0 + r) * N + col] = v;
                else Cb[(size_t)(row0 + r) * N + col] = (bfr)v;
            }
        }
    }
}

// ---- GEMM, A bf16, W bf16 (1-term). BM in {64,128}; 1D grid + swizzle ----
// OUT: 0=f32, 1=bf16
template <int ACT, int OUT, int BM>
__global__ __launch_bounds__(256, 2) void gemm_ps(
    const bfr* __restrict__ Ahi,
    const bfr* __restrict__ Whi,
    const float* __restrict__ bias, float* __restrict__ Cf,
    bfr* __restrict__ Chi, int M, int N, int K)
{
    constexpr int MF = BM / 32;
    __shared__ bfr Ah_s[BM * LDSK];
    __shared__ bfr Wh_s[64 * LDSK];
    const int t = threadIdx.x;
    int pm, pn;
    tile_map(blockIdx.x, M / BM, N / 64, pm, pn);
    const int bm = pm * BM, bn = pn * 64;
    const int w = t >> 6, lane = t & 63;
    const int wm = w >> 1, wn = w & 1;
    const int fr = lane & 15, kq = lane >> 4;
    const int wr = t >> 2, wk = (t & 3) * 8;

    f32x4 acc[MF][2] = {};

    for (int k0 = 0; k0 < K; k0 += 32) {
        if constexpr (BM == 128) {
            const int ar = t >> 1, ah = (t & 1) * 16;
            const bfr* ap = Ahi + (size_t)(bm + ar) * K + (k0 + ah);
            *(bf16x8*)(Ah_s + ar * LDSK + ah) = *(const bf16x8*)ap;
            *(bf16x8*)(Ah_s + ar * LDSK + ah + 8) = *(const bf16x8*)(ap + 8);
        } else {
            const int ar = t >> 2, ah = (t & 3) * 8;
            *(bf16x8*)(Ah_s + ar * LDSK + ah) = *(const bf16x8*)(Ahi + (size_t)(bm + ar) * K + (k0 + ah));
        }
        *(bf16x8*)(Wh_s + wr * LDSK + wk) = *(const bf16x8*)(Whi + (size_t)(bn + wr) * K + (k0 + wk));
        __syncthreads();
        bf16x8 Afh[MF], Wfh[2];
#pragma unroll
        for (int i = 0; i < MF; ++i)
            Afh[i] = *(const bf16x8*)(Ah_s + (wm * (BM / 2) + i * 16 + fr) * LDSK + kq * 8);
#pragma unroll
        for (int j = 0; j < 2; ++j)
            Wfh[j] = *(const bf16x8*)(Wh_s + (wn * 32 + j * 16 + fr) * LDSK + kq * 8);
#pragma unroll
        for (int i = 0; i < MF; ++i)
#pragma unroll
            for (int j = 0; j < 2; ++j)
                acc[i][j] = __builtin_amdgcn_mfma_f32_16x16x32_bf16(Afh[i], Wfh[j], acc[i][j], 0, 0, 0);
        __syncthreads();
    }
#pragma unroll
    for (int i = 0; i < MF; ++i) {
        int row0 = bm + wm * (BM / 2) + i * 16 + (lane >> 4) * 4;
#pragma unroll
        for (int j = 0; j < 2; ++j) {
            int col = bn + wn * 32 + j * 16 + fr;
            float bj = bias[col];
#pragma unroll
            for (int r = 0; r < 4; ++r) {
                float v = acc[i][j][r] + bj;
                if (ACT == 1) v = 0.5f * v * (1.0f + erff(v * 0.70710678118654752f));
                size_t idx = (size_t)(row0 + r) * N + col;
                if (OUT == 0) Cf[idx] = v;
                else Chi[idx] = (bfr)v;
            }
        }
    }
}

// ---- fused flash attention, bf16 inputs; RoPE folded in when CAUSAL ----
template <int TK, int CAUSAL>
__global__ __launch_bounds__(256) void attn_kernel(
    const bfr* __restrict__ Qg, int qstr,
    const bfr* __restrict__ Kg, const bfr* __restrict__ Vg, int kvstr,
    const int* __restrict__ pad,
    const float* __restrict__ cosT, const float* __restrict__ sinT,
    bfr* __restrict__ Ohi)
{
    __shared__ bfr Qs[64 * AST];
    __shared__ bfr Ks[64 * AST];
    __shared__ bfr VTs[64 * AST];
    __shared__ bfr Ps[64 * AST];
    const int bidx = blockIdx.x;
    const int qt = bidx & 1, bh = bidx >> 1;
    const int h = bh & 7, b = bh >> 3;
    const int t = threadIdx.x;
    const int w = t >> 6, lane = t & 63;
    const int l4 = lane & 15, hi4 = lane >> 4;
    const int q0 = qt * 64;
    const int srow = t >> 2, ht = t & 3;

    if (CAUSAL) {
        int qrow = q0 + srow;
        const bfr* qp = Qg + (size_t)(b * L_ + qrow) * qstr + h * HD_ + ht * 8;
        bf16x8 a = *(const bf16x8*)qp;
        bf16x8 bb = *(const bf16x8*)(qp + 32);
        bf16x8 o1, o2;
#pragma unroll
        for (int j = 0; j < 8; ++j) {
            float c = cosT[qrow * 32 + ht * 8 + j], s = sinT[qrow * 32 + ht * 8 + j];
            float x1 = (float)a[j], x2 = (float)bb[j];
            o1[j] = (bfr)(x1 * c - x2 * s);
            o2[j] = (bfr)(x2 * c + x1 * s);
        }
        *(bf16x8*)(Qs + srow * AST + ht * 8) = o1;
        *(bf16x8*)(Qs + srow * AST + ht * 8 + 32) = o2;
    } else {
        const bfr* qp = Qg + (size_t)(b * L_ + q0 + srow) * qstr + h * HD_ + ht * 16;
        *(bf16x8*)(Qs + srow * AST + ht * 16) = *(const bf16x8*)qp;
        *(bf16x8*)(Qs + srow * AST + ht * 16 + 8) = *(const bf16x8*)(qp + 8);
    }

    f32x4 o_acc[4] = {};
    float m_run[4], l_run[4];
#pragma unroll
    for (int r = 0; r < 4; ++r) { m_run[r] = -1e30f; l_run[r] = 0.f; }

    const int NT = CAUSAL ? (qt + 1) : (TK / 64);
    for (int kt = 0; kt < NT; ++kt) {
        __syncthreads();
        if (CAUSAL) {
            int krow = kt * 64 + srow;
            const bfr* kp = Kg + (size_t)(b * TK + krow) * kvstr + h * HD_ + ht * 8;
            bf16x8 a = *(const bf16x8*)kp;
            bf16x8 bb = *(const bf16x8*)(kp + 32);
            bf16x8 o1, o2;
#pragma unroll
            for (int j = 0; j < 8; ++j) {
                float c = cosT[krow * 32 + ht * 8 + j], s = sinT[krow * 32 + ht * 8 + j];
                float x1 = (float)a[j], x2 = (float)bb[j];
                o1[j] = (bfr)(x1 * c - x2 * s);
                o2[j] = (bfr)(x2 * c + x1 * s);
            }
            *(bf16x8*)(Ks + srow * AST + ht * 8) = o1;
            *(bf16x8*)(Ks + srow * AST + ht * 8 + 32) = o2;
        } else {
            const bfr* kp = Kg + (size_t)(b * TK + kt * 64 + srow) * kvstr + h * HD_ + ht * 16;
            *(bf16x8*)(Ks + srow * AST + ht * 16) = *(const bf16x8*)kp;
            *(bf16x8*)(Ks + srow * AST + ht * 16 + 8) = *(const bf16x8*)(kp + 8);
        }
        {
            const bfr* vp = Vg + (size_t)(b * TK + kt * 64 + srow) * kvstr + h * HD_ + ht * 16;
            bf16x8 v0 = *(const bf16x8*)vp;
            bf16x8 v1 = *(const bf16x8*)(vp + 8);
#pragma unroll
            for (int i = 0; i < 8; ++i) VTs[(ht * 16 + i) * AST + srow] = v0[i];
#pragma unroll
            for (int i = 0; i < 8; ++i) VTs[(ht * 16 + 8 + i) * AST + srow] = v1[i];
        }
        __syncthreads();

        f32x4 s[4] = {};
#pragma unroll
        for (int kk = 0; kk < 64; kk += 32) {
            bf16x8 a = *(const bf16x8*)(Qs + (w * 16 + l4) * AST + kk + hi4 * 8);
#pragma unroll
            for (int n = 0; n < 4; ++n) {
                bf16x8 bb = *(const bf16x8*)(Ks + (n * 16 + l4) * AST + kk + hi4 * 8);
                s[n] = __builtin_amdgcn_mfma_f32_16x16x32_bf16(a, bb, s[n], 0, 0, 0);
            }
        }
        float madd[4];
        if (!CAUSAL) {
#pragma unroll
            for (int n = 0; n < 4; ++n)
                madd[n] = pad[b * TK + kt * 64 + n * 16 + l4] ? -1e30f : 0.f;
        }
#pragma unroll
        for (int r = 0; r < 4; ++r) {
            int qrow = q0 + w * 16 + hi4 * 4 + r;
            float sv[4];
#pragma unroll
            for (int n = 0; n < 4; ++n) {
                float x = s[n][r] * 0.125f;
                if (CAUSAL) {
                    int col = kt * 64 + n * 16 + l4;
                    if (col > qrow) x = -1e30f;
                } else x += madd[n];
                sv[n] = x;
            }
            float mx = fmaxf(fmaxf(sv[0], sv[1]), fmaxf(sv[2], sv[3]));
#pragma unroll
            for (int off = 1; off < 16; off <<= 1) mx = fmaxf(mx, __shfl_xor(mx, off));
            float mnew = fmaxf(m_run[r], mx);
            float alpha = expf(m_run[r] - mnew);
            float pv[4], psum = 0.f;
#pragma unroll
            for (int n = 0; n < 4; ++n) { pv[n] = expf(sv[n] - mnew); psum += pv[n]; }
#pragma unroll
            for (int off = 1; off < 16; off <<= 1) psum += __shfl_xor(psum, off);
            l_run[r] = l_run[r] * alpha + psum;
            m_run[r] = mnew;
#pragma unroll
            for (int n = 0; n < 4; ++n) o_acc[n][r] *= alpha;
#pragma unroll
            for (int n = 0; n < 4; ++n)
                Ps[(w * 16 + hi4 * 4 + r) * AST + n * 16 + l4] = (bfr)pv[n];
        }
#pragma unroll
        for (int kk = 0; kk < 64; kk += 32) {
            bf16x8 pa = *(const bf16x8*)(Ps + (w * 16 + l4) * AST + kk + hi4 * 8);
#pragma unroll
            for (int n = 0; n < 4; ++n) {
                bf16x8 vb = *(const bf16x8*)(VTs + (n * 16 + l4) * AST + kk + hi4 * 8);
                o_acc[n] = __builtin_amdgcn_mfma_f32_16x16x32_bf16(pa, vb, o_acc[n], 0, 0, 0);
            }
        }
    }
#pragma unroll
    for (int r = 0; r < 4; ++r) {
        float inv = 1.0f / l_run[r];
        int qrow = q0 + w * 16 + hi4 * 4 + r;
#pragma unroll
        for (int n = 0; n < 4; ++n)
            Ohi[(size_t)(b * L_ + qrow) * D_ + h * HD_ + n * 16 + l4] = (bfr)(o_acc[n][r] * inv);
    }
}

__global__ void rope_tables_kernel(float* __restrict__ cosT, float* __restrict__ sinT)
{
    int gid = blockIdx.x * blockDim.x + threadIdx.x;
    if (gid >= L_ * 32) return;
    int l = gid >> 5, i = gid & 31;
    float inv = powf(10000.0f, -(float)(2 * i) / (float)HD_);
    float ang = (float)l * inv;
    cosT[gid] = cosf(ang);
    sinT[gid] = sinf(ang);
}

__global__ void embed_kernel(const int* __restrict__ targets, const float* __restrict__ emb,
                             float* __restrict__ tgt, bfr* __restrict__ thi)
{
    int gid = blockIdx.x * blockDim.x + threadIdx.x;
    if (gid >= B_ * L_ * D_) return;
    int d = gid & (D_ - 1);
    int r = gid >> 9;
    int tok = targets[r];
    float x = emb[(size_t)tok * D_ + d] * 22.62741699796952f;
    tgt[gid] = x;
    thi[gid] = (bfr)x;
}

__global__ void pad_kernel(const float* __restrict__ mem, int* __restrict__ pad)
{
    int gid = blockIdx.x * blockDim.x + threadIdx.x;
    if (gid >= B_ * T_) return;
    const float* p = mem + (size_t)gid * D_;
    float s = 0.f;
    for (int d = 0; d < D_; ++d) s += fabsf(p[d]);
    pad[gid] = (s == 0.0f) ? 1 : 0;
}

// tgt = LN(tgt + delta); writes f32 + bf16 image, float4 I/O
__global__ __launch_bounds__(128) void ln_residual_kernel(
    float* __restrict__ tgt, const float* __restrict__ delta,
    const float* __restrict__ g, const float* __restrict__ bb,
    bfr* __restrict__ thi)
{
    const int row = blockIdx.x;
    const int t = threadIdx.x;
    __shared__ float rbuf[128];
    size_t base = (size_t)row * D_ + t * 4;
    float4 x = *(float4*)(tgt + base);
    float4 dl = *(const float4*)(delta + base);
    x.x += dl.x; x.y += dl.y; x.z += dl.z; x.w += dl.w;
    rbuf[t] = x.x + x.y + x.z + x.w;
    __syncthreads();
    for (int off = 64; off > 0; off >>= 1) { if (t < off) rbuf[t] += rbuf[t + off]; __syncthreads(); }
    float mean = rbuf[0] * (1.0f / D_);
    __syncthreads();
    float4 d4 = {x.x - mean, x.y - mean, x.z - mean, x.w - mean};
    rbuf[t] = d4.x * d4.x + d4.y * d4.y + d4.z * d4.z + d4.w * d4.w;
    __syncthreads();
    for (int off = 64; off > 0; off >>= 1) { if (t < off) rbuf[t] += rbuf[t + off]; __syncthreads(); }
    float inv = 1.0f / sqrtf(rbuf[0] * (1.0f / D_) + 1e-5f);
    float4 g4 = *(const float4*)(g + t * 4);
    float4 b4 = *(const float4*)(bb + t * 4);
    float4 y = {d4.x * inv * g4.x + b4.x, d4.y * inv * g4.y + b4.y,
                d4.z * inv * g4.z + b4.z, d4.w * inv * g4.w + b4.w};
    *(float4*)(tgt + base) = y;
    bf16x4 h4 = {(bfr)y.x, (bfr)y.y, (bfr)y.z, (bfr)y.w};
    *(bf16x4*)(thi + base) = h4;
}

__global__ void copyf_kernel(const float* __restrict__ in, float* __restrict__ out, int n)
{
    int gid = blockIdx.x * blockDim.x + threadIdx.x;
    if (gid < n) out[gid] = in[gid];
}

__global__ void fillf_kernel(float* p, float v, size_t n)
{
    size_t gid = (size_t)blockIdx.x * 256 + threadIdx.x;
    if (gid < n) p[gid] = v;
}

extern "C" void kernel_launch(void* const* d_in, const int* in_sizes, int n_in,
                              void* d_out, int out_size, void* d_ws, size_t ws_size,
                              hipStream_t stream)
{
    const float* enc    = (const float*)d_in[0];
    const int*   tg     = (const int*)d_in[1];
    const float* emb    = (const float*)d_in[2];
    const float* inp_w  = (const float*)d_in[3];
    const float* inp_b  = (const float*)d_in[4];
    const float* out_w  = (const float*)d_in[5];
    const float* out_b  = (const float*)d_in[6];
    const float* qw     = (const float*)d_in[7];
    const float* qb     = (const float*)d_in[8];
    const float* kw     = (const float*)d_in[9];
    const float* kb     = (const float*)d_in[10];
    const float* vw     = (const float*)d_in[11];
    const float* vb     = (const float*)d_in[12];
    const float* ow     = (const float*)d_in[13];
    const float* ob     = (const float*)d_in[14];
    const float* mha_w  = (const float*)d_in[15];
    const float* mha_b  = (const float*)d_in[16];
    const float* mha_ow = (const float*)d_in[17];
    const float* mha_ob = (const float*)d_in[18];
    const float* w1     = (const float*)d_in[19];
    const float* b1     = (const float*)d_in[20];
    const float* w2     = (const float*)d_in[21];
    const float* b2     = (const float*)d_in[22];
    const float* ln1g   = (const float*)d_in[23];
    const float* ln1b   = (const float*)d_in[24];
    const float* ln2g   = (const float*)d_in[25];
    const float* ln2b   = (const float*)d_in[26];
    const float* ln3g   = (const float*)d_in[27];
    const float* ln3b   = (const float*)d_in[28];

    const int BL = B_ * L_;        // 4096
    const int BT = B_ * T_;        // 16384
    const size_t N_LOGITS = (size_t)BL * V_;
    const int D2 = D_ * D_;        // 262144

    const size_t WS_NEEDED =
        (size_t)BT * 1024 * sizeof(bfr)                 // fused K2|V2
        + (size_t)BL * D_ * sizeof(float)               // tgt f32
        + (size_t)BL * D_ * sizeof(bfr)                 // tgt_hi
        + (size_t)2 * L_ * 32 * sizeof(float) + (size_t)BT * sizeof(int)
        + (size_t)V_ * D_ * sizeof(bfr);                // out_w bf16
    if (ws_size < WS_NEEDED) {
        fillf_kernel<<<((size_t)out_size + 255) / 256, 256, 0, stream>>>((float*)d_out, 0.f, (size_t)out_size);
        return;
    }
    bfr*   f_KVb = (bfr*)d_ws;                          // [BT,1024]: K2 cols 0..511, V2 512..1023
    float* f_tgt = (float*)(f_KVb + (size_t)BT * 1024);
    bfr*   tgt_hi = (bfr*)(f_tgt + (size_t)BL * D_);
    float* f_cos = (float*)(tgt_hi + (size_t)BL * D_);
    float* f_sin = f_cos + (size_t)L_ * 32;
    int*   f_pad = (int*)(f_sin + (size_t)L_ * 32);
    bfr*   ow_hi = (bfr*)(f_pad + BT);

    bfr* wp = (bfr*)d_out;
    bfr* qkvw_hi = wp;  wp += 3 * D2;
    bfr* inp_hi  = wp;  wp += D2;
    bfr* mha_hi  = wp;  wp += 3 * D2;
    bfr* o_hi    = wp;  wp += D2;
    bfr* mo_hi   = wp;  wp += D2;
    bfr* w1_hi   = wp;  wp += DFF_ * D_;
    bfr* w2_hi   = wp;  wp += D_ * DFF_;
    float* f_qkvb = (float*)wp;                 // [1536]
    float* lr    = f_qkvb + 3 * D_;
    float* f_t2  = lr;                                   // [BL,512] f32
    bfr*   qkv   = (bfr*)(f_t2 + (size_t)BL * D_);       // [BL,1536]
    bfr*   qcr   = qkv + (size_t)BL * 3 * D_;            // [BL,512]
    bfr*   t1_hi = qcr + (size_t)BL * D_;                // [BL,512]
    bfr*   ffh_hi = t1_hi + (size_t)BL * D_;             // [BL,1024]
    float* f_mem = lr;  // prologue-only alias (BT*D f32 = 33.5MB <= layer region)

    // single batched weight convert (bf16)
    {
        ConvTable tab{};
        int blk = 0, ne = 0;
        auto add = [&](const float* s, bfr* d, int n) {
            tab.e[ne] = {s, d, n, blk};
            blk += (n + 255) >> 8;
            ++ne;
        };
        add(qw, qkvw_hi, D2);
        add(kw, qkvw_hi + D2, D2);
        add(vw, qkvw_hi + 2 * D2, D2);
        add(inp_w, inp_hi, D2);
        add(mha_w, mha_hi, 3 * D2);
        add(ow, o_hi, D2);
        add(mha_ow, mo_hi, D2);
        add(w1, w1_hi, DFF_ * D_);
        add(w2, w2_hi, D_ * DFF_);
        add(out_w, ow_hi, V_ * D_);
        tab.ne = ne;
        conv_many_kernel<<<blk, 256, 0, stream>>>(tab);
    }
    copyf_kernel<<<2, 256, 0, stream>>>(qb, f_qkvb, D_);
    copyf_kernel<<<2, 256, 0, stream>>>(kb, f_qkvb + D_, D_);
    copyf_kernel<<<2, 256, 0, stream>>>(vb, f_qkvb + 2 * D_, D_);

    rope_tables_kernel<<<(L_ * 32 + 255) / 256, 256, 0, stream>>>(f_cos, f_sin);
    embed_kernel<<<(BL * D_ + 255) / 256, 256, 0, stream>>>(tg, emb, f_tgt, tgt_hi);

    // prologue: memory f32, pad mask, fused K2|V2 (bf16, N=1024)
    gemm_split<0><<<dim3(D_ / 64, BT / 128), 256, 0, stream>>>(enc, inp_hi, inp_b, f_mem, nullptr, BT, D_, INC_);
    pad_kernel<<<(BT + 255) / 256, 256, 0, stream>>>(f_mem, f_pad);
    gemm_split<1><<<dim3(1024 / 64, BT / 128), 256, 0, stream>>>(f_mem, mha_hi + (size_t)D2, mha_b + D_, nullptr, f_KVb, BT, 1024, D_);

    for (int layer = 0; layer < NL_; ++layer) {
        // self attention: fused QKV -> bf16 [BL,1536]; rope inside attn
        gemm_ps<0, 1, 64><<<(BL / 64) * (3 * D_ / 64), 256, 0, stream>>>(tgt_hi, qkvw_hi, f_qkvb, nullptr, qkv, BL, 3 * D_, D_);
        attn_kernel<L_, 1><<<B_ * H_ * 2, 256, 0, stream>>>(qkv, 3 * D_, qkv + D_, qkv + 2 * D_, 3 * D_, nullptr, f_cos, f_sin, t1_hi);
        gemm_ps<0, 0, 64><<<(BL / 64) * (D_ / 64), 256, 0, stream>>>(t1_hi, o_hi, ob, f_t2, nullptr, BL, D_, D_);
        ln_residual_kernel<<<BL, 128, 0, stream>>>(f_tgt, f_t2, ln1g, ln1b, tgt_hi);
        // cross attention
        gemm_ps<0, 1, 64><<<(BL / 64) * (D_ / 64), 256, 0, stream>>>(tgt_hi, mha_hi, mha_b, nullptr, qcr, BL, D_, D_);
        attn_kernel<T_, 0><<<B_ * H_ * 2, 256, 0, stream>>>(qcr, D_, f_KVb, f_KVb + D_, 1024, f_pad, nullptr, nullptr, t1_hi);
        gemm_ps<0, 0, 64><<<(BL / 64) * (D_ / 64), 256, 0, stream>>>(t1_hi, mo_hi, mha_ob, f_t2, nullptr, BL, D_, D_);
        ln_residual_kernel<<<BL, 128, 0, stream>>>(f_tgt, f_t2, ln2g, ln2b, tgt_hi);
        // FFN
        gemm_ps<1, 1, 64><<<(BL / 64) * (DFF_ / 64), 256, 0, stream>>>(tgt_hi, w1_hi, b1, nullptr, ffh_hi, BL, DFF_, D_);
        gemm_ps<0, 0, 64><<<(BL / 64) * (D_ / 64), 256, 0, stream>>>(ffh_hi, w2_hi, b2, f_t2, nullptr, BL, D_, DFF_);
        ln_residual_kernel<<<BL, 128, 0, stream>>>(f_tgt, f_t2, ln3g, ln3b, tgt_hi);
    }

    // all d_out scratch dead; outputs f32
    float* o_logits = (float*)d_out;
    float* o_tgt = o_logits + N_LOGITS;
    gemm_ps<0, 0, 128><<<(BL / 128) * (V_ / 64), 256, 0, stream>>>(tgt_hi, ow_hi, out_b, o_logits, nullptr, BL, V_, D_);
    copyf_kernel<<<(BL * D_ + 255) / 256, 256, 0, stream>>>(f_tgt, o_tgt, BL * D_);
}